// Round 5
// baseline (23603.950 us; speedup 1.0000x reference)
//
#include <hip/hip_runtime.h>
#include <stdint.h>

// ============================ problem constants ============================
#define C_DIM   768
#define N_TOK   193
#define B_TOT   64
#define ROWS    (B_TOT * N_TOK)       // 12352
#define QKV_DIM 2304
#define N_HEAD  12
#define N_EXP   8
#define MAXPER  ROWS
#define HALF_CT 24704u

enum { MODE_PATCH = 0, MODE_PLAIN = 1, MODE_RESID = 2, MODE_EXPERT = 3 };

// snapshot layout (floats, inside d_ws)
#define SN_H0    0
#define SN_Y1    768
#define SN_O     1536
#define SN_HR    2304
#define SN_Y2    3072
#define SN_HC    3840
#define SN_TW    4608
#define SN_EO    4616
#define SN_QKV   6160
#define SN_TOTAL 460000

// ============================ threefry-2x32 (bit-exact vs JAX) ============================
__device__ __forceinline__ uint32_t rotl32(uint32_t x, int n){ return (x << n) | (x >> (32 - n)); }

__device__ __forceinline__ void tf2x32(uint32_t k0, uint32_t k1, uint32_t x0, uint32_t x1,
                                       uint32_t &r0, uint32_t &r1){
  uint32_t k2 = k0 ^ k1 ^ 0x1BD11BDAu;
#define TF4(a,b,c,d) x0+=x1; x1=rotl32(x1,a); x1^=x0; x0+=x1; x1=rotl32(x1,b); x1^=x0; \
                     x0+=x1; x1=rotl32(x1,c); x1^=x0; x0+=x1; x1=rotl32(x1,d); x1^=x0;
  x0 += k0; x1 += k1;
  TF4(13,15,26, 6)  x0 += k1; x1 += k2 + 1u;
  TF4(17,29,16,24)  x0 += k2; x1 += k0 + 2u;
  TF4(13,15,26, 6)  x0 += k0; x1 += k1 + 3u;
  TF4(17,29,16,24)  x0 += k1; x1 += k2 + 4u;
  TF4(13,15,26, 6)  x0 += k2; x1 += k0 + 5u;
#undef TF4
  r0 = x0; r1 = x1;
}

__device__ __forceinline__ float jax_erfinv(float x){
  float w = -log1pf(-x * x);
  float p;
  if (w < 5.0f){
    w -= 2.5f;
    p =              2.81022636e-08f;
    p = fmaf(p, w,   3.43273939e-07f);
    p = fmaf(p, w,  -3.5233877e-06f);
    p = fmaf(p, w,  -4.39150654e-06f);
    p = fmaf(p, w,   0.00021858087f);
    p = fmaf(p, w,  -0.00125372503f);
    p = fmaf(p, w,  -0.00417768164f);
    p = fmaf(p, w,   0.246640727f);
    p = fmaf(p, w,   1.50140941f);
  } else {
    w = sqrtf(w) - 3.0f;
    p =             -0.000200214257f;
    p = fmaf(p, w,   0.000100950558f);
    p = fmaf(p, w,   0.00134934322f);
    p = fmaf(p, w,  -0.00367342844f);
    p = fmaf(p, w,   0.00573950773f);
    p = fmaf(p, w,  -0.0076224613f);
    p = fmaf(p, w,   0.00943887047f);
    p = fmaf(p, w,   1.00167406f);
    p = fmaf(p, w,   2.83297682f);
  }
  return p * x;
}

// PARTITIONABLE threefry random_bits (JAX >= 0.4.36 default):
// counts = iota(u64, size); bits[i] = o0 ^ o1 where (o0,o1) = tf(key, (i>>32, i&0xffffffff)).
__device__ __forceinline__ float jax_noise(uint32_t c0, uint32_t c1, uint32_t j){
  uint32_t o0, o1;
  tf2x32(c0, c1, 0u, j, o0, o1);
  uint32_t bits = o0 ^ o1;
  float f = __uint_as_float(0x3f800000u | (bits >> 9)) - 1.0f;   // [0,1)
  const float lo = -0.99999994f;                                  // nextafter(-1,0)
  float u = fmaxf(lo, f * 2.0f + lo);                             // (hi-lo) == 2.0f in fp32
  return 1.41421356237f * jax_erfinv(u) * 0.125f;                 // sqrt(2)*erfinv(u)/E
}

// ============================ small kernels ============================
__global__ __launch_bounds__(64) void k_zero8(int* __restrict__ p){
  if ((int)threadIdx.x < N_EXP) p[threadIdx.x] = 0;
}

__global__ __launch_bounds__(64) void k_sentinel(float* __restrict__ out, float v){
  if (threadIdx.x == 0) out[0] = v;
}

__global__ __launch_bounds__(64) void k_save(const float* __restrict__ src, float* __restrict__ dst){
  if (threadIdx.x == 0) dst[0] = src[0];
}

__global__ __launch_bounds__(256) void k_snap(const float* __restrict__ src, float* __restrict__ dst, int n){
  for (int i = blockIdx.x * 256 + threadIdx.x; i < n; i += gridDim.x * 256) dst[i] = src[i];
}

__global__ __launch_bounds__(256) void k_cls(float* __restrict__ h, const float* __restrict__ cls,
                                             const float* __restrict__ pos){
  const int bt = blockIdx.x;
  #pragma unroll
  for (int u = 0; u < 3; ++u){
    int c = threadIdx.x + u * 256;
    h[(size_t)bt * N_TOK * C_DIM + c] = cls[c] + pos[c];
  }
}

__device__ __forceinline__ float blk_sum(float v, float* sb){
  #pragma unroll
  for (int off = 32; off > 0; off >>= 1) v += __shfl_down(v, off, 64);
  const int lane = threadIdx.x & 63, w = threadIdx.x >> 6;
  if (lane == 0) sb[w] = v;
  __syncthreads();
  if (threadIdx.x == 0) sb[4] = sb[0] + sb[1] + sb[2] + sb[3];
  __syncthreads();
  float r = sb[4];
  __syncthreads();
  return r;
}

__global__ __launch_bounds__(256) void k_layernorm(const float* __restrict__ x, float* __restrict__ y,
                                                   const float* __restrict__ w, const float* __restrict__ b){
  __shared__ float sb[8];
  const float* xr = x + (size_t)blockIdx.x * C_DIM;
  float v0 = xr[threadIdx.x], v1 = xr[threadIdx.x + 256], v2 = xr[threadIdx.x + 512];
  float mean = blk_sum(v0 + v1 + v2, sb) * (1.0f / 768.0f);
  float d0 = v0 - mean, d1 = v1 - mean, d2 = v2 - mean;
  float var = blk_sum(d0 * d0 + d1 * d1 + d2 * d2, sb) * (1.0f / 768.0f);
  float inv = 1.0f / sqrtf(var + 1e-5f);
  float* yr = y + (size_t)blockIdx.x * C_DIM;
  yr[threadIdx.x]       = d0 * inv * w[threadIdx.x]       + b[threadIdx.x];
  yr[threadIdx.x + 256] = d1 * inv * w[threadIdx.x + 256] + b[threadIdx.x + 256];
  yr[threadIdx.x + 512] = d2 * inv * w[threadIdx.x + 512] + b[threadIdx.x + 512];
}

__global__ __launch_bounds__(256) void k_final(const float* __restrict__ h, float* __restrict__ out,
                                               const float* __restrict__ w, const float* __restrict__ b){
  __shared__ float sb[8];
  const int bt = blockIdx.x;
  const float* xr = h + (size_t)bt * N_TOK * C_DIM;
  float v0 = xr[threadIdx.x], v1 = xr[threadIdx.x + 256], v2 = xr[threadIdx.x + 512];
  float mean = blk_sum(v0 + v1 + v2, sb) * (1.0f / 768.0f);
  float d0 = v0 - mean, d1 = v1 - mean, d2 = v2 - mean;
  float var = blk_sum(d0 * d0 + d1 * d1 + d2 * d2, sb) * (1.0f / 768.0f);
  float inv = 1.0f / sqrtf(var + 1e-5f);
  float* orow = out + (size_t)(bt & 31) * 1536 + (size_t)(bt >> 5) * C_DIM;
  orow[threadIdx.x]       = d0 * inv * w[threadIdx.x]       + b[threadIdx.x];
  orow[threadIdx.x + 256] = d1 * inv * w[threadIdx.x + 256] + b[threadIdx.x + 256];
  orow[threadIdx.x + 512] = d2 * inv * w[threadIdx.x + 512] + b[threadIdx.x + 512];
}

// ============================ tiled SGEMM: C = A @ W^T (+bias variants) ============================
template<int MODE>
__global__ __launch_bounds__(256) void k_gemm(
    const float* __restrict__ A, const float* __restrict__ W,
    const float* __restrict__ bias, float* __restrict__ C,
    int M, int Nc, int Kc,
    const float* __restrict__ xa, const float* __restrict__ xb,
    const float* __restrict__ pos,
    const int* __restrict__ elist, const int* __restrict__ ecnt)
{
  constexpr int BM = 128, BN = 128, BK = 8;
  __shared__ float As[BK][BM + 4];
  __shared__ float Bs[BK][BN + 4];
  const int tid = threadIdx.x;
  const int tx = tid & 15, ty = tid >> 4;
  const int lm = tid >> 1, kh = (tid & 1) * 4;

  int e = 0;
  int Mloc = M;
  const float* Wp = W;
  const float* bp = bias;
  if constexpr (MODE == MODE_EXPERT){
    e = blockIdx.z;
    Mloc = ecnt[e];
    Wp = W + (size_t)e * C_DIM * C_DIM;
    bp = bias + e * C_DIM;
  }
  const int row0 = blockIdx.x * BM;
  const int col0 = blockIdx.y * BN;
  if (row0 >= Mloc) return;

  const float* arow = A;
  bool avalid = false;
  const float* psrc = nullptr;
  if constexpr (MODE == MODE_PLAIN || MODE == MODE_RESID){
    int r = row0 + lm;
    avalid = r < Mloc;
    arow = A + (size_t)(avalid ? r : 0) * Kc;
  } else if constexpr (MODE == MODE_EXPERT){
    int r = row0 + lm;
    avalid = r < Mloc;
    if (avalid) arow = A + (size_t)(elist[e * MAXPER + r] >> 1) * C_DIM;
  } else {
    int r = row0 + lm;
    int bt = r / 192;
    int n  = r - bt * 192;
    const float* xp = (bt < 32) ? xa : xb;
    psrc = xp + (size_t)(bt & 31) * 3 * 384 * 384 + n * 2;
    avalid = true;
  }

  float acc[8][8] = {};
  const int nkt = Kc / BK;
  for (int kt = 0; kt < nkt; ++kt){
    const int k0 = kt * BK;
    if constexpr (MODE == MODE_PATCH){
      #pragma unroll
      for (int j = 0; j < 4; ++j){
        int k = k0 + kh + j;
        int c = k / 768;
        int rem = k - c * 768;
        int hr = rem >> 1, p = rem & 1;
        As[kh + j][lm] = psrc[((size_t)c * 384 + hr) * 384 + p];
      }
    } else {
      float4 av = make_float4(0.f, 0.f, 0.f, 0.f);
      if (avalid) av = *(const float4*)(arow + k0 + kh);
      As[kh + 0][lm] = av.x; As[kh + 1][lm] = av.y; As[kh + 2][lm] = av.z; As[kh + 3][lm] = av.w;
    }
    {
      float4 bv = *(const float4*)(Wp + (size_t)(col0 + lm) * Kc + k0 + kh);
      Bs[kh + 0][lm] = bv.x; Bs[kh + 1][lm] = bv.y; Bs[kh + 2][lm] = bv.z; Bs[kh + 3][lm] = bv.w;
    }
    __syncthreads();
    #pragma unroll
    for (int k = 0; k < BK; ++k){
      float a[8], b[8];
      *(float4*)&a[0] = *(const float4*)&As[k][ty * 8];
      *(float4*)&a[4] = *(const float4*)&As[k][ty * 8 + 4];
      *(float4*)&b[0] = *(const float4*)&Bs[k][tx * 8];
      *(float4*)&b[4] = *(const float4*)&Bs[k][tx * 8 + 4];
      #pragma unroll
      for (int i = 0; i < 8; ++i)
        #pragma unroll
        for (int j = 0; j < 8; ++j)
          acc[i][j] = fmaf(a[i], b[j], acc[i][j]);
    }
    __syncthreads();
  }

  #pragma unroll
  for (int i = 0; i < 8; ++i){
    int r = row0 + ty * 8 + i;
    if (r >= Mloc) break;
    if constexpr (MODE == MODE_PATCH){
      int bt = r / 192, n = r - (r / 192) * 192;
      size_t orow = ((size_t)bt * N_TOK + n + 1) * C_DIM;
      size_t prow = (size_t)(n + 1) * C_DIM;
      #pragma unroll
      for (int j = 0; j < 8; ++j){
        int cc = col0 + tx * 8 + j;
        C[orow + cc] = acc[i][j] + bp[cc] + pos[prow + cc];
      }
    } else if constexpr (MODE == MODE_PLAIN){
      size_t orow = (size_t)r * Nc;
      #pragma unroll
      for (int j = 0; j < 8; ++j){
        int cc = col0 + tx * 8 + j;
        C[orow + cc] = acc[i][j] + bp[cc];
      }
    } else if constexpr (MODE == MODE_RESID){
      size_t orow = (size_t)r * Nc;
      #pragma unroll
      for (int j = 0; j < 8; ++j){
        int cc = col0 + tx * 8 + j;
        C[orow + cc] += acc[i][j] + bp[cc];
      }
    } else {
      int ts = elist[e * MAXPER + r];
      size_t orow = (size_t)ts * C_DIM;
      #pragma unroll
      for (int j = 0; j < 8; ++j){
        int cc = col0 + tx * 8 + j;
        C[orow + cc] = acc[i][j] + bp[cc];
      }
    }
  }
}

// ============================ attention (naive) ============================
__global__ __launch_bounds__(256) void k_attn2(const float* __restrict__ qkv, float* __restrict__ o_out){
  const int wid = threadIdx.x >> 6, lane = threadIdx.x & 63;
  const int q = blockIdx.x * 4 + wid;
  const int bh = blockIdx.y;
  const int bt = bh / N_HEAD, hh = bh - bt * N_HEAD;
  if (q >= N_TOK) return;
  const size_t base = (size_t)bt * N_TOK * QKV_DIM + (size_t)hh * 64;
  const float qv = qkv[base + (size_t)q * QKV_DIM + lane];
  const float* Kb = qkv + base + 768;
  const float* Vb = qkv + base + 1536;

  float s0, s1, s2, s3;
  for (int kk = 0; kk < 64; ++kk){
    float prod = qv * Kb[(size_t)kk * QKV_DIM + lane];
    #pragma unroll
    for (int off = 32; off; off >>= 1) prod += __shfl_xor(prod, off, 64);
    if (kk == lane) s0 = prod * 0.125f;
  }
  for (int kk = 0; kk < 64; ++kk){
    float prod = qv * Kb[(size_t)(64 + kk) * QKV_DIM + lane];
    #pragma unroll
    for (int off = 32; off; off >>= 1) prod += __shfl_xor(prod, off, 64);
    if (kk == lane) s1 = prod * 0.125f;
  }
  for (int kk = 0; kk < 64; ++kk){
    float prod = qv * Kb[(size_t)(128 + kk) * QKV_DIM + lane];
    #pragma unroll
    for (int off = 32; off; off >>= 1) prod += __shfl_xor(prod, off, 64);
    if (kk == lane) s2 = prod * 0.125f;
  }
  {
    float prod = qv * Kb[(size_t)192 * QKV_DIM + lane];
    #pragma unroll
    for (int off = 32; off; off >>= 1) prod += __shfl_xor(prod, off, 64);
    s3 = prod * 0.125f;
  }
  float m = fmaxf(fmaxf(s0, s1), fmaxf(s2, s3));
  #pragma unroll
  for (int off = 32; off; off >>= 1) m = fmaxf(m, __shfl_xor(m, off, 64));
  float p0 = expf(s0 - m), p1 = expf(s1 - m), p2 = expf(s2 - m);
  float p3 = expf(s3 - m);
  float l = p0 + p1 + p2 + ((lane == 0) ? p3 : 0.f);
  #pragma unroll
  for (int off = 32; off; off >>= 1) l += __shfl_xor(l, off, 64);

  float o = 0.f;
  for (int kk = 0; kk < 64; ++kk){
    float pk = __shfl(p0, kk, 64);
    o = fmaf(pk, Vb[(size_t)kk * QKV_DIM + lane], o);
  }
  for (int kk = 0; kk < 64; ++kk){
    float pk = __shfl(p1, kk, 64);
    o = fmaf(pk, Vb[(size_t)(64 + kk) * QKV_DIM + lane], o);
  }
  for (int kk = 0; kk < 64; ++kk){
    float pk = __shfl(p2, kk, 64);
    o = fmaf(pk, Vb[(size_t)(128 + kk) * QKV_DIM + lane], o);
  }
  o = fmaf(p3, Vb[(size_t)192 * QKV_DIM + lane], o);

  o_out[((size_t)bt * N_TOK + q) * C_DIM + hh * 64 + lane] = o / l;
}

// ============================ router ============================
__global__ __launch_bounds__(256) void k_router(
    const float* __restrict__ y, const float* __restrict__ rw, const float* __restrict__ rb,
    const float* __restrict__ rlw, const float* __restrict__ rlb,
    float* __restrict__ topw, int* __restrict__ elist, int* __restrict__ ecnt, int l)
{
  const int wid = threadIdx.x >> 6, lane = threadIdx.x & 63;
  const int tok = blockIdx.x * 4 + wid;
  const int e = lane & 7, seg = lane >> 3;
  const float* yr = y + (size_t)tok * C_DIM + seg * 96;
  const float* wr = rw + (size_t)e * C_DIM + seg * 96;
  float part = 0.f;
  #pragma unroll 8
  for (int i = 0; i < 96; ++i) part = fmaf(yr[i], wr[i], part);
  part += __shfl_xor(part, 8, 64);
  part += __shfl_xor(part, 16, 64);
  part += __shfl_xor(part, 32, 64);
  float logit = part + rb[e];
  float ssum = logit;
  ssum += __shfl_xor(ssum, 1, 64); ssum += __shfl_xor(ssum, 2, 64); ssum += __shfl_xor(ssum, 4, 64);
  float mean = ssum * 0.125f;
  float d = logit - mean;
  float vs = d * d;
  vs += __shfl_xor(vs, 1, 64); vs += __shfl_xor(vs, 2, 64); vs += __shfl_xor(vs, 4, 64);
  float ln = d * (1.0f / sqrtf(vs * 0.125f + 1e-5f)) * rlw[e] + rlb[e];
  float mx = ln;
  mx = fmaxf(mx, __shfl_xor(mx, 1, 64)); mx = fmaxf(mx, __shfl_xor(mx, 2, 64)); mx = fmaxf(mx, __shfl_xor(mx, 4, 64));
  float ex = expf(ln - mx);
  float es = ex;
  es += __shfl_xor(es, 1, 64); es += __shfl_xor(es, 2, 64); es += __shfl_xor(es, 4, 64);
  float prob = ex / es;
  int t = tok / 6176;
  int rem = tok - t * 6176;
  int b = rem / N_TOK, n = rem - (rem / N_TOK) * N_TOK;
  uint32_t b0, b1, c0, c1;
  tf2x32(0u, 1234u, 0u, (uint32_t)t, b0, b1);
  tf2x32(b0, b1, 0u, (uint32_t)l, c0, c1);
  uint32_t j = (uint32_t)(b * N_TOK + n) * 8u + (uint32_t)e;
  float r = prob + jax_noise(c0, c1, j);
  float v1 = r; int i1 = e;
  #pragma unroll
  for (int off = 1; off <= 4; off <<= 1){
    float ov = __shfl_xor(v1, off, 64); int oi = __shfl_xor(i1, off, 64);
    if (ov > v1 || (ov == v1 && oi < i1)){ v1 = ov; i1 = oi; }
  }
  float rm = (e == i1) ? -3.0e38f : r;
  float v2 = rm; int i2 = e;
  #pragma unroll
  for (int off = 1; off <= 4; off <<= 1){
    float ov = __shfl_xor(v2, off, 64); int oi = __shfl_xor(i2, off, 64);
    if (ov > v2 || (ov == v2 && oi < i2)){ v2 = ov; i2 = oi; }
  }
  float e2 = expf(v2 - v1);
  float sum = 1.0f + e2;
  if (lane == 0){
    topw[tok * 2 + 0] = 1.0f / sum;
    topw[tok * 2 + 1] = e2 / sum;
    int pos = atomicAdd(&ecnt[i1], 1);
    elist[i1 * MAXPER + pos] = tok * 2;
    int pos2 = atomicAdd(&ecnt[i2], 1);
    elist[i2 * MAXPER + pos2] = tok * 2 + 1;
  }
}

__global__ __launch_bounds__(256) void k_combine(float* __restrict__ h, const float* __restrict__ eout,
                                                 const float* __restrict__ topw){
  const int tok = blockIdx.x;
  const float w0 = topw[tok * 2], w1 = topw[tok * 2 + 1];
  const size_t hb = (size_t)tok * C_DIM;
  const size_t e0 = (size_t)(tok * 2) * C_DIM, e1 = e0 + C_DIM;
  #pragma unroll
  for (int u = 0; u < 3; ++u){
    int c = threadIdx.x + u * 256;
    h[hb + c] += w0 * eout[e0 + c] + w1 * eout[e1 + c];
  }
}

// ============================ probe 1 ============================
__global__ __launch_bounds__(64) void k_probe(
    const float* __restrict__ ln1w, const float* __restrict__ pos, const float* __restrict__ normw,
    const float* __restrict__ x1, const float* __restrict__ pw, const float* __restrict__ pb,
    const float* __restrict__ y, const float* __restrict__ ew, const float* __restrict__ ebias,
    const float* __restrict__ eout_, const int* __restrict__ elist_, const int* __restrict__ ecnt_,
    const float* __restrict__ saved, float* __restrict__ out)
{
  if (threadIdx.x != 0 || blockIdx.x != 0) return;
  if (ln1w[0] != 1.0f)            out[0] = 5.0e6f;
  if (pos[768 + 384] != 1.0f)     out[1] = 6.0e6f;
  if (normw[0] != 1.0f)           out[2] = 6.5e6f;
  {
    float acc = 0.f;
    for (int k = 0; k < 2304; ++k){
      int c = k / 768, rem = k - c * 768;
      int hr = rem >> 1, p = rem & 1;
      acc = fmaf(x1[(size_t)c * 147456 + (size_t)hr * 384 + p], pw[k], acc);
    }
    acc += pb[0] + pos[768];
    if (fabsf(acc - saved[0]) > 1e-2f) out[3] = 7.0e6f;
  }
  if (ecnt_[0] > 0){
    int ts = elist_[0];
    int tok = ts >> 1;
    float a2 = 0.f;
    const float* wrow = ew + ((size_t)(5 * 8 + 0) * 768 + 17) * 768;
    const float* yrow = y + (size_t)tok * 768;
    for (int k = 0; k < 768; ++k) a2 = fmaf(yrow[k], wrow[k], a2);
    a2 += ebias[5 * 8 * 768 + 17];
    if (fabsf(a2 - eout_[(size_t)ts * 768 + 17]) > 1e-2f) out[4] = 7.5e6f;
  }
  {
    uint32_t r0, r1; tf2x32(0u, 0u, 0u, 0u, r0, r1);
    if (r0 != 0x6b200159u || r1 != 0x99ba4efeu) out[5] = 8.0e6f;
  }
  if (fabsf(jax_erfinv(0.5f) - 0.47693628f) > 1e-4f) out[6] = 8.5e6f;
}

// ============================ probe 2: serial re-implementation ============================
__device__ __forceinline__ bool p2_bad(float a, float b){
  return fabsf(a - b) > 3e-3f * fmaxf(1.0f, fmaxf(fabsf(a), fabsf(b)));
}

__global__ __launch_bounds__(64) void k_probe2(
    const float* __restrict__ ln1w, const float* __restrict__ ln1b,
    const float* __restrict__ qw,   const float* __restrict__ qb,
    const float* __restrict__ pw,   const float* __restrict__ pb,
    const float* __restrict__ ln2w, const float* __restrict__ ln2b,
    const float* __restrict__ rw,   const float* __restrict__ rb,
    const float* __restrict__ rlw,  const float* __restrict__ rlb,
    const float* __restrict__ ew,   const float* __restrict__ eb,
    const float* __restrict__ sn, float* __restrict__ out)
{
  if (threadIdx.x != 0 || blockIdx.x != 0) return;

  if (ln2w[0] != 1.0f) out[8]  = 2.2e7f;
  if (rlw[0]  != 1.0f) out[9]  = 2.1e7f;
  if (rb[0]   != 0.0f) out[10] = 2.05e7f;

  const float* h0 = sn + SN_H0;
  const float* y1 = sn + SN_Y1;
  const float* oS = sn + SN_O;
  const float* hr = sn + SN_HR;
  const float* y2 = sn + SN_Y2;
  const float* hc = sn + SN_HC;
  const float* tw = sn + SN_TW;
  const float* eo = sn + SN_EO;
  const float* Q  = sn + SN_QKV;

  {
    float m = 0.f; for (int c = 0; c < 768; ++c) m += h0[c]; m /= 768.f;
    float v = 0.f; for (int c = 0; c < 768; ++c){ float d = h0[c] - m; v += d * d; } v /= 768.f;
    float inv = 1.f / sqrtf(v + 1e-5f);
    for (int c = 0; c < 768; c += 37){
      float ys = (h0[c] - m) * inv * ln1w[c] + ln1b[c];
      if (p2_bad(ys, y1[c])){ out[11] = 2.0e7f; break; }
    }
  }
  {
    const int cols[3] = {0, 1000, 2303};
    for (int t = 0; t < 3; ++t){
      int cc = cols[t];
      float a = 0.f;
      for (int k = 0; k < 768; ++k) a = fmaf(y1[k], qw[(size_t)cc * 768 + k], a);
      a += qb[cc];
      if (p2_bad(a, Q[(size_t)7 * 2304 + cc])){ out[12] = 1.9e7f; break; }
    }
  }
  {
    const int hh = 3;
    float s[193];
    float mx = -1e30f;
    for (int k = 0; k < 193; ++k){
      float a = 0.f;
      for (int d = 0; d < 64; ++d)
        a = fmaf(Q[(size_t)7 * 2304 + hh * 64 + d], Q[(size_t)k * 2304 + 768 + hh * 64 + d], a);
      s[k] = a * 0.125f;
      mx = fmaxf(mx, s[k]);
    }
    float l = 0.f;
    for (int k = 0; k < 193; ++k){ s[k] = expf(s[k] - mx); l += s[k]; }
    bool fail = false;
    for (int d = 0; d < 64 && !fail; d += 7){
      float o = 0.f;
      for (int k = 0; k < 193; ++k) o = fmaf(s[k], Q[(size_t)k * 2304 + 1536 + hh * 64 + d], o);
      o /= l;
      if (p2_bad(o, oS[hh * 64 + d])) fail = true;
    }
    if (fail) out[13] = 1.8e7f;
  }
  {
    const int cols[2] = {5, 500};
    for (int t = 0; t < 2; ++t){
      int c = cols[t];
      float a = 0.f;
      for (int i = 0; i < 768; ++i) a = fmaf(oS[i], pw[(size_t)c * 768 + i], a);
      a += pb[c] + h0[c];
      if (p2_bad(a, hr[c])){ out[14] = 1.7e7f; break; }
    }
  }
  {
    float m = 0.f; for (int c = 0; c < 768; ++c) m += hr[c]; m /= 768.f;
    float v = 0.f; for (int c = 0; c < 768; ++c){ float d = hr[c] - m; v += d * d; } v /= 768.f;
    float inv = 1.f / sqrtf(v + 1e-5f);
    for (int c = 0; c < 768; c += 37){
      float ys = (hr[c] - m) * inv * ln2w[c] + ln2b[c];
      if (p2_bad(ys, y2[c])){ out[15] = 1.6e7f; break; }
    }
  }
  int i1s = -1, i2s = -1;
  float w0s = 0.f, w1s = 0.f;
  {
    float logit[8], lnv[8], pr[8], rr[8];
    float sm = 0.f;
    for (int e = 0; e < 8; ++e){
      float a = 0.f;
      for (int k = 0; k < 768; ++k) a = fmaf(y2[k], rw[(size_t)e * 768 + k], a);
      logit[e] = a + rb[e];
      sm += logit[e];
    }
    sm /= 8.f;
    float vv = 0.f;
    for (int e = 0; e < 8; ++e){ float d = logit[e] - sm; vv += d * d; }
    vv /= 8.f;
    float inv = 1.f / sqrtf(vv + 1e-5f);
    float mx = -1e30f;
    for (int e = 0; e < 8; ++e){ lnv[e] = (logit[e] - sm) * inv * rlw[e] + rlb[e]; mx = fmaxf(mx, lnv[e]); }
    float es = 0.f;
    for (int e = 0; e < 8; ++e){ pr[e] = expf(lnv[e] - mx); es += pr[e]; }
    uint32_t b0, b1, c0, c1;
    tf2x32(0u, 1234u, 0u, 0u, b0, b1);
    tf2x32(b0, b1, 0u, 0u, c0, c1);
    for (int e = 0; e < 8; ++e) rr[e] = pr[e] / es + jax_noise(c0, c1, 56u + (uint32_t)e);
    float v1s = -3e38f;
    for (int e = 0; e < 8; ++e) if (rr[e] > v1s){ v1s = rr[e]; i1s = e; }
    float v2s = -3e38f;
    for (int e = 0; e < 8; ++e){ if (e == i1s) continue; if (rr[e] > v2s){ v2s = rr[e]; i2s = e; } }
    float e2 = expf(v2s - v1s);
    w0s = 1.f / (1.f + e2); w1s = e2 / (1.f + e2);
    if (fabsf(w0s - tw[0]) > 1e-3f || fabsf(w1s - tw[1]) > 1e-3f) out[16] = 1.5e7f;
  }
  {
    const int cols[2] = {5, 500};
    bool fail = false;
    for (int slot = 0; slot < 2 && !fail; ++slot){
      int e = (slot == 0) ? i1s : i2s;
      for (int t = 0; t < 2 && !fail; ++t){
        int c = cols[t];
        float a = 0.f;
        for (int k = 0; k < 768; ++k) a = fmaf(y2[k], ew[((size_t)e * 768 + c) * 768 + k], a);
        a += eb[e * 768 + c];
        if (p2_bad(a, eo[slot * 768 + c])) fail = true;
      }
    }
    if (fail) out[17] = 1.4e7f;
  }
  {
    for (int c = 0; c < 768; c += 37){
      float a = hr[c] + tw[0] * eo[c] + tw[1] * eo[768 + c];
      if (p2_bad(a, hc[c])){ out[18] = 1.3e7f; break; }
    }
  }
}

// ============================ host launch ============================
extern "C" void kernel_launch(void* const* d_in, const int* in_sizes, int n_in,
                              void* d_out, int out_size, void* d_ws, size_t ws_size,
                              hipStream_t stream){
  float* out = (float*)d_out;

  static const int kExp[22] = {
    14155776, 14155776, 1769472, 768, 768,
    4608, 4608, 10616832, 13824, 3538944, 4608,
    4608, 4608, 36864, 48, 48, 48,
    28311552, 36864, 768, 768, 148224};
  const size_t need_f = (size_t)ROWS * C_DIM * 2 + (size_t)ROWS * QKV_DIM
                      + (size_t)ROWS * 2 + (size_t)N_EXP * MAXPER + 8 + 4 + SN_TOTAL;
  float bad = 0.f;
  if (n_in != 22) bad = 2.0e6f;
  else {
    for (int i = 0; i < 22; ++i)
      if (in_sizes[i] != kExp[i]){ bad = 4.0e6f + i * 1.0e4f; break; }
  }
  if (bad == 0.f && out_size != 49152) bad = 3.0e6f;
  if (bad == 0.f && ws_size < need_f * 4) bad = 1.0e6f;
  if (bad != 0.f){
    k_sentinel<<<dim3(1), 64, 0, stream>>>(out, bad);
    return;
  }

  const float* x1       = (const float*)d_in[0];
  const float* x2       = (const float*)d_in[1];
  const float* patch_w  = (const float*)d_in[2];
  const float* patch_b  = (const float*)d_in[3];
  const float* cls_tok  = (const float*)d_in[4];
  const float* ln1_w    = (const float*)d_in[5];
  const float* ln1_b    = (const float*)d_in[6];
  const float* qkv_w    = (const float*)d_in[7];
  const float* qkv_b    = (const float*)d_in[8];
  const float* proj_w   = (const float*)d_in[9];
  const float* proj_b   = (const float*)d_in[10];
  const float* ln2_w    = (const float*)d_in[11];
  const float* ln2_b    = (const float*)d_in[12];
  const float* route_w  = (const float*)d_in[13];
  const float* route_b  = (const float*)d_in[14];
  const float* rln_w    = (const float*)d_in[15];
  const float* rln_b    = (const float*)d_in[16];
  const float* expert_w = (const float*)d_in[17];
  const float* expert_b = (const float*)d_in[18];
  const float* norm_w   = (const float*)d_in[19];
  const float* norm_b   = (const float*)d_in[20];
  const float* pos_emb  = (const float*)d_in[21];

  float* ws = (float*)d_ws;
  size_t off = 0;
  float* h    = ws + off; off += (size_t)ROWS * C_DIM;
  float* y    = ws + off; off += (size_t)ROWS * C_DIM;
  float* qkv  = ws + off; off += (size_t)ROWS * QKV_DIM;
  float* eout = qkv;
  float* topw = ws + off; off += (size_t)ROWS * 2;
  int*   elist = (int*)(ws + off); off += (size_t)N_EXP * MAXPER;
  int*   ecnt  = (int*)(ws + off); off += 8;
  float* saved = ws + off; off += 4;
  float* snap  = ws + off; off += SN_TOTAL;

  k_cls<<<dim3(B_TOT), 256, 0, stream>>>(h, cls_tok, pos_emb);
  k_gemm<MODE_PATCH><<<dim3(96, 6), 256, 0, stream>>>(
      nullptr, patch_w, patch_b, h, 12288, C_DIM, 2304, x1, x2, pos_emb, nullptr, nullptr);
  k_save<<<dim3(1), 64, 0, stream>>>(h + C_DIM, saved);
  k_snap<<<dim3(3), 256, 0, stream>>>(h + 7 * C_DIM, snap + SN_H0, 768);

  for (int l = 0; l < 6; ++l){
    k_layernorm<<<dim3(ROWS), 256, 0, stream>>>(h, y, ln1_w + l * C_DIM, ln1_b + l * C_DIM);
    if (l == 0) k_snap<<<dim3(3), 256, 0, stream>>>(y + 7 * C_DIM, snap + SN_Y1, 768);
    k_gemm<MODE_PLAIN><<<dim3(97, 18), 256, 0, stream>>>(
        y, qkv_w + (size_t)l * QKV_DIM * C_DIM, qkv_b + l * QKV_DIM, qkv,
        ROWS, QKV_DIM, C_DIM, nullptr, nullptr, nullptr, nullptr, nullptr);
    if (l == 0) k_snap<<<dim3(512), 256, 0, stream>>>(qkv, snap + SN_QKV, 193 * 2304);
    k_attn2<<<dim3(49, B_TOT * N_HEAD), 256, 0, stream>>>(qkv, y);
    if (l == 0) k_snap<<<dim3(3), 256, 0, stream>>>(y + 7 * C_DIM, snap + SN_O, 768);
    k_gemm<MODE_RESID><<<dim3(97, 6), 256, 0, stream>>>(
        y, proj_w + (size_t)l * C_DIM * C_DIM, proj_b + l * C_DIM, h,
        ROWS, C_DIM, C_DIM, nullptr, nullptr, nullptr, nullptr, nullptr);
    if (l == 0) k_snap<<<dim3(3), 256, 0, stream>>>(h + 7 * C_DIM, snap + SN_HR, 768);
    k_layernorm<<<dim3(ROWS), 256, 0, stream>>>(h, y, ln2_w + l * C_DIM, ln2_b + l * C_DIM);
    if (l == 0) k_snap<<<dim3(3), 256, 0, stream>>>(y + 7 * C_DIM, snap + SN_Y2, 768);
    k_zero8<<<dim3(1), 64, 0, stream>>>(ecnt);
    k_router<<<dim3(ROWS / 4), 256, 0, stream>>>(
        y, route_w + (size_t)l * N_EXP * C_DIM, route_b + l * N_EXP,
        rln_w + l * N_EXP, rln_b + l * N_EXP, topw, elist, ecnt, l);
    if (l == 0) k_snap<<<dim3(1), 256, 0, stream>>>(topw + 14, snap + SN_TW, 2);
    k_gemm<MODE_EXPERT><<<dim3(97, 6, N_EXP), 256, 0, stream>>>(
        y, expert_w + (size_t)l * N_EXP * C_DIM * C_DIM, expert_b + (size_t)l * N_EXP * C_DIM, eout,
        ROWS, C_DIM, C_DIM, nullptr, nullptr, nullptr, elist, ecnt);
    if (l == 0) k_snap<<<dim3(6), 256, 0, stream>>>(eout + 14 * C_DIM, snap + SN_EO, 1536);
    k_combine<<<dim3(ROWS), 256, 0, stream>>>(h, eout, topw);
    if (l == 0) k_snap<<<dim3(3), 256, 0, stream>>>(h + 7 * C_DIM, snap + SN_HC, 768);
  }
  k_final<<<dim3(B_TOT), 256, 0, stream>>>(h, out, norm_w, norm_b);
  k_probe<<<dim3(1), 64, 0, stream>>>(ln1_w, pos_emb, norm_w, x1, patch_w, patch_b,
                                      y, expert_w, expert_b, eout, elist, ecnt, saved, out);
  k_probe2<<<dim3(1), 64, 0, stream>>>(ln1_w, ln1_b, qkv_w, qkv_b, proj_w, proj_b,
                                       ln2_w, ln2_b, route_w, route_b, rln_w, rln_b,
                                       expert_w, expert_b, snap, out);
}

// Round 6
// 11320.589 us; speedup vs baseline: 2.0850x; 2.0850x over previous
//
#include <hip/hip_runtime.h>
#include <stdint.h>

// ============================ problem constants ============================
#define C_DIM   768
#define N_TOK   193
#define B_TOT   64                    // 2 towers x 32 batch
#define ROWS    (B_TOT * N_TOK)       // 12352
#define QKV_DIM 2304
#define N_HEAD  12
#define N_EXP   8
#define MAXPER  ROWS

enum { MODE_PATCH = 0, MODE_PLAIN = 1, MODE_RESID = 2, MODE_EXPERT = 3 };

// ============================ threefry-2x32 (bit-exact vs JAX) ============================
__device__ __forceinline__ uint32_t rotl32(uint32_t x, int n){ return (x << n) | (x >> (32 - n)); }

__device__ __forceinline__ void tf2x32(uint32_t k0, uint32_t k1, uint32_t x0, uint32_t x1,
                                       uint32_t &r0, uint32_t &r1){
  uint32_t k2 = k0 ^ k1 ^ 0x1BD11BDAu;
#define TF4(a,b,c,d) x0+=x1; x1=rotl32(x1,a); x1^=x0; x0+=x1; x1=rotl32(x1,b); x1^=x0; \
                     x0+=x1; x1=rotl32(x1,c); x1^=x0; x0+=x1; x1=rotl32(x1,d); x1^=x0;
  x0 += k0; x1 += k1;
  TF4(13,15,26, 6)  x0 += k1; x1 += k2 + 1u;
  TF4(17,29,16,24)  x0 += k2; x1 += k0 + 2u;
  TF4(13,15,26, 6)  x0 += k0; x1 += k1 + 3u;
  TF4(17,29,16,24)  x0 += k1; x1 += k2 + 4u;
  TF4(13,15,26, 6)  x0 += k2; x1 += k0 + 5u;
#undef TF4
  r0 = x0; r1 = x1;
}

__device__ __forceinline__ float jax_erfinv(float x){
  float w = -log1pf(-x * x);
  float p;
  if (w < 5.0f){
    w -= 2.5f;
    p =              2.81022636e-08f;
    p = fmaf(p, w,   3.43273939e-07f);
    p = fmaf(p, w,  -3.5233877e-06f);
    p = fmaf(p, w,  -4.39150654e-06f);
    p = fmaf(p, w,   0.00021858087f);
    p = fmaf(p, w,  -0.00125372503f);
    p = fmaf(p, w,  -0.00417768164f);
    p = fmaf(p, w,   0.246640727f);
    p = fmaf(p, w,   1.50140941f);
  } else {
    w = sqrtf(w) - 3.0f;
    p =             -0.000200214257f;
    p = fmaf(p, w,   0.000100950558f);
    p = fmaf(p, w,   0.00134934322f);
    p = fmaf(p, w,  -0.00367342844f);
    p = fmaf(p, w,   0.00573950773f);
    p = fmaf(p, w,  -0.0076224613f);
    p = fmaf(p, w,   0.00943887047f);
    p = fmaf(p, w,   1.00167406f);
    p = fmaf(p, w,   2.83297682f);
  }
  return p * x;
}

// PARTITIONABLE threefry random_bits (JAX >= 0.4.36 default):
// counts = iota(u64); bits[j] = o0 ^ o1, (o0,o1) = tf(key, (hi=0, lo=j)).  [verified round 5]
__device__ __forceinline__ float jax_noise(uint32_t c0, uint32_t c1, uint32_t j){
  uint32_t o0, o1;
  tf2x32(c0, c1, 0u, j, o0, o1);
  uint32_t bits = o0 ^ o1;
  float f = __uint_as_float(0x3f800000u | (bits >> 9)) - 1.0f;   // [0,1)
  const float lo = -0.99999994f;                                  // nextafter(-1,0)
  float u = fmaxf(lo, f * 2.0f + lo);
  return 1.41421356237f * jax_erfinv(u) * 0.125f;                 // sqrt(2)*erfinv(u)/E
}

// ============================ small kernels ============================
__global__ __launch_bounds__(64) void k_zero8(int* __restrict__ p){
  if ((int)threadIdx.x < N_EXP) p[threadIdx.x] = 0;
}

__global__ __launch_bounds__(64) void k_sentinel(float* __restrict__ out, float v){
  if (threadIdx.x == 0) out[0] = v;
}

__global__ __launch_bounds__(256) void k_cls(float* __restrict__ h, const float* __restrict__ cls,
                                             const float* __restrict__ pos){
  const int bt = blockIdx.x;
  #pragma unroll
  for (int u = 0; u < 3; ++u){
    int c = threadIdx.x + u * 256;
    h[(size_t)bt * N_TOK * C_DIM + c] = cls[c] + pos[c];
  }
}

__device__ __forceinline__ float blk_sum(float v, float* sb){
  #pragma unroll
  for (int off = 32; off > 0; off >>= 1) v += __shfl_down(v, off, 64);
  const int lane = threadIdx.x & 63, w = threadIdx.x >> 6;
  if (lane == 0) sb[w] = v;
  __syncthreads();
  if (threadIdx.x == 0) sb[4] = sb[0] + sb[1] + sb[2] + sb[3];
  __syncthreads();
  float r = sb[4];
  __syncthreads();
  return r;
}

__global__ __launch_bounds__(256) void k_layernorm(const float* __restrict__ x, float* __restrict__ y,
                                                   const float* __restrict__ w, const float* __restrict__ b){
  __shared__ float sb[8];
  const float* xr = x + (size_t)blockIdx.x * C_DIM;
  float v0 = xr[threadIdx.x], v1 = xr[threadIdx.x + 256], v2 = xr[threadIdx.x + 512];
  float mean = blk_sum(v0 + v1 + v2, sb) * (1.0f / 768.0f);
  float d0 = v0 - mean, d1 = v1 - mean, d2 = v2 - mean;
  float var = blk_sum(d0 * d0 + d1 * d1 + d2 * d2, sb) * (1.0f / 768.0f);
  float inv = 1.0f / sqrtf(var + 1e-5f);
  float* yr = y + (size_t)blockIdx.x * C_DIM;
  yr[threadIdx.x]       = d0 * inv * w[threadIdx.x]       + b[threadIdx.x];
  yr[threadIdx.x + 256] = d1 * inv * w[threadIdx.x + 256] + b[threadIdx.x + 256];
  yr[threadIdx.x + 512] = d2 * inv * w[threadIdx.x + 512] + b[threadIdx.x + 512];
}

__global__ __launch_bounds__(256) void k_final(const float* __restrict__ h, float* __restrict__ out,
                                               const float* __restrict__ w, const float* __restrict__ b){
  __shared__ float sb[8];
  const int bt = blockIdx.x;
  const float* xr = h + (size_t)bt * N_TOK * C_DIM;
  float v0 = xr[threadIdx.x], v1 = xr[threadIdx.x + 256], v2 = xr[threadIdx.x + 512];
  float mean = blk_sum(v0 + v1 + v2, sb) * (1.0f / 768.0f);
  float d0 = v0 - mean, d1 = v1 - mean, d2 = v2 - mean;
  float var = blk_sum(d0 * d0 + d1 * d1 + d2 * d2, sb) * (1.0f / 768.0f);
  float inv = 1.0f / sqrtf(var + 1e-5f);
  float* orow = out + (size_t)(bt & 31) * 1536 + (size_t)(bt >> 5) * C_DIM;
  orow[threadIdx.x]       = d0 * inv * w[threadIdx.x]       + b[threadIdx.x];
  orow[threadIdx.x + 256] = d1 * inv * w[threadIdx.x + 256] + b[threadIdx.x + 256];
  orow[threadIdx.x + 512] = d2 * inv * w[threadIdx.x + 512] + b[threadIdx.x + 512];
}

// ============================ tiled SGEMM: C = A @ W^T (+bias variants) ============================
template<int MODE>
__global__ __launch_bounds__(256) void k_gemm(
    const float* __restrict__ A, const float* __restrict__ W,
    const float* __restrict__ bias, float* __restrict__ C,
    int M, int Nc, int Kc,
    const float* __restrict__ xa, const float* __restrict__ xb,
    const float* __restrict__ pos,
    const int* __restrict__ elist, const int* __restrict__ ecnt)
{
  constexpr int BM = 128, BN = 128, BK = 8;
  __shared__ float As[BK][BM + 4];
  __shared__ float Bs[BK][BN + 4];
  const int tid = threadIdx.x;
  const int tx = tid & 15, ty = tid >> 4;
  const int lm = tid >> 1, kh = (tid & 1) * 4;

  int e = 0;
  int Mloc = M;
  const float* Wp = W;
  const float* bp = bias;
  if constexpr (MODE == MODE_EXPERT){
    e = blockIdx.z;
    Mloc = ecnt[e];
    Wp = W + (size_t)e * C_DIM * C_DIM;
    bp = bias + e * C_DIM;
  }
  const int row0 = blockIdx.x * BM;
  const int col0 = blockIdx.y * BN;
  if (row0 >= Mloc) return;

  const float* arow = A;
  bool avalid = false;
  const float* psrc = nullptr;
  if constexpr (MODE == MODE_PLAIN || MODE == MODE_RESID){
    int r = row0 + lm;
    avalid = r < Mloc;
    arow = A + (size_t)(avalid ? r : 0) * Kc;
  } else if constexpr (MODE == MODE_EXPERT){
    int r = row0 + lm;
    avalid = r < Mloc;
    if (avalid) arow = A + (size_t)(elist[e * MAXPER + r] >> 1) * C_DIM;
  } else {
    int r = row0 + lm;
    int bt = r / 192;
    int n  = r - bt * 192;
    const float* xp = (bt < 32) ? xa : xb;
    psrc = xp + (size_t)(bt & 31) * 3 * 384 * 384 + n * 2;
    avalid = true;
  }

  float acc[8][8] = {};
  const int nkt = Kc / BK;
  for (int kt = 0; kt < nkt; ++kt){
    const int k0 = kt * BK;
    if constexpr (MODE == MODE_PATCH){
      #pragma unroll
      for (int j = 0; j < 4; ++j){
        int k = k0 + kh + j;
        int c = k / 768;
        int rem = k - c * 768;
        int hr = rem >> 1, p = rem & 1;
        As[kh + j][lm] = psrc[((size_t)c * 384 + hr) * 384 + p];
      }
    } else {
      float4 av = make_float4(0.f, 0.f, 0.f, 0.f);
      if (avalid) av = *(const float4*)(arow + k0 + kh);
      As[kh + 0][lm] = av.x; As[kh + 1][lm] = av.y; As[kh + 2][lm] = av.z; As[kh + 3][lm] = av.w;
    }
    {
      float4 bv = *(const float4*)(Wp + (size_t)(col0 + lm) * Kc + k0 + kh);
      Bs[kh + 0][lm] = bv.x; Bs[kh + 1][lm] = bv.y; Bs[kh + 2][lm] = bv.z; Bs[kh + 3][lm] = bv.w;
    }
    __syncthreads();
    #pragma unroll
    for (int k = 0; k < BK; ++k){
      float a[8], b[8];
      *(float4*)&a[0] = *(const float4*)&As[k][ty * 8];
      *(float4*)&a[4] = *(const float4*)&As[k][ty * 8 + 4];
      *(float4*)&b[0] = *(const float4*)&Bs[k][tx * 8];
      *(float4*)&b[4] = *(const float4*)&Bs[k][tx * 8 + 4];
      #pragma unroll
      for (int i = 0; i < 8; ++i)
        #pragma unroll
        for (int j = 0; j < 8; ++j)
          acc[i][j] = fmaf(a[i], b[j], acc[i][j]);
    }
    __syncthreads();
  }

  #pragma unroll
  for (int i = 0; i < 8; ++i){
    int r = row0 + ty * 8 + i;
    if (r >= Mloc) break;
    if constexpr (MODE == MODE_PATCH){
      int bt = r / 192, n = r - (r / 192) * 192;
      size_t orow = ((size_t)bt * N_TOK + n + 1) * C_DIM;
      size_t prow = (size_t)(n + 1) * C_DIM;
      #pragma unroll
      for (int j = 0; j < 8; ++j){
        int cc = col0 + tx * 8 + j;
        C[orow + cc] = acc[i][j] + bp[cc] + pos[prow + cc];
      }
    } else if constexpr (MODE == MODE_PLAIN){
      size_t orow = (size_t)r * Nc;
      #pragma unroll
      for (int j = 0; j < 8; ++j){
        int cc = col0 + tx * 8 + j;
        C[orow + cc] = acc[i][j] + bp[cc];
      }
    } else if constexpr (MODE == MODE_RESID){
      size_t orow = (size_t)r * Nc;
      #pragma unroll
      for (int j = 0; j < 8; ++j){
        int cc = col0 + tx * 8 + j;
        C[orow + cc] += acc[i][j] + bp[cc];
      }
    } else {
      int ts = elist[e * MAXPER + r];
      size_t orow = (size_t)ts * C_DIM;
      #pragma unroll
      for (int j = 0; j < 8; ++j){
        int cc = col0 + tx * 8 + j;
        C[orow + cc] = acc[i][j] + bp[cc];
      }
    }
  }
}

// ============================ attention (flash-style, fp32, 64x64 tiles) ============================
// grid (4 q-tiles, 64*12 bh). K and P share one LDS buffer (48 KB total).
// Numerically verified equivalent to the naive two-pass version (rounds 1/2: identical absmax).
__global__ __launch_bounds__(256) void k_attn(const float* __restrict__ qkv, float* __restrict__ o_out){
  __shared__ float Qs[64][64];   // [d][m]
  __shared__ float KPs[64][64];  // K as [d][n], later P as [m][n]
  __shared__ float Vs[64][64];   // [n][d]
  const int q0 = blockIdx.x * 64;
  const int bh = blockIdx.y;
  const int bt = bh / N_HEAD, hh = bh - bt * N_HEAD;
  const int tid = threadIdx.x;
  const int tx = tid & 15, ty = tid >> 4;
  const size_t base = (size_t)bt * N_TOK * QKV_DIM + (size_t)hh * 64;

  { // stage Q transposed
    int m = tid & 63, g = tid >> 6;
    int q = q0 + m;
    bool valid = q < N_TOK;
    const float* src = qkv + base + (size_t)(valid ? q : 0) * QKV_DIM;
    #pragma unroll
    for (int u = 0; u < 4; ++u){
      int cb = (g * 4 + u) * 4;
      float4 v = valid ? *(const float4*)(src + cb) : make_float4(0.f,0.f,0.f,0.f);
      Qs[cb + 0][m] = v.x; Qs[cb + 1][m] = v.y; Qs[cb + 2][m] = v.z; Qs[cb + 3][m] = v.w;
    }
  }

  float Oa[4][4] = {};
  float mrun[4] = {-1e30f, -1e30f, -1e30f, -1e30f};
  float lrun[4] = {};

  for (int kt = 0; kt < 4; ++kt){
    const int n0 = kt * 64;
    __syncthreads();                       // prev iter done with KPs/Vs (also orders Q staging)
    { // stage K transposed
      int m = tid & 63, g = tid >> 6;
      int kk = n0 + m;
      bool valid = kk < N_TOK;
      const float* src = qkv + base + 768 + (size_t)(valid ? kk : 0) * QKV_DIM;
      #pragma unroll
      for (int u = 0; u < 4; ++u){
        int cb = (g * 4 + u) * 4;
        float4 v = valid ? *(const float4*)(src + cb) : make_float4(0.f,0.f,0.f,0.f);
        KPs[cb + 0][m] = v.x; KPs[cb + 1][m] = v.y; KPs[cb + 2][m] = v.z; KPs[cb + 3][m] = v.w;
      }
    }
    { // stage V direct
      int c4 = tid & 15, nr = tid >> 4;
      #pragma unroll
      for (int r = 0; r < 4; ++r){
        int n = nr + r * 16;
        int kk = n0 + n;
        float4 v = (kk < N_TOK) ? *(const float4*)(qkv + base + 1536 + (size_t)kk * QKV_DIM + c4 * 4)
                                : make_float4(0.f,0.f,0.f,0.f);
        *(float4*)&Vs[n][c4 * 4] = v;
      }
    }
    __syncthreads();
    // S = Q K^T * scale
    float s[4][4] = {};
    #pragma unroll 8
    for (int d = 0; d < 64; ++d){
      float4 a4 = *(const float4*)&Qs[d][ty * 4];
      float4 b4 = *(const float4*)&KPs[d][tx * 4];
      float av[4] = {a4.x, a4.y, a4.z, a4.w};
      float bv[4] = {b4.x, b4.y, b4.z, b4.w};
      #pragma unroll
      for (int i = 0; i < 4; ++i)
        #pragma unroll
        for (int j = 0; j < 4; ++j)
          s[i][j] = fmaf(av[i], bv[j], s[i][j]);
    }
    #pragma unroll
    for (int i = 0; i < 4; ++i)
      #pragma unroll
      for (int j = 0; j < 4; ++j){
        s[i][j] *= 0.125f;
        if (n0 + tx * 4 + j >= N_TOK) s[i][j] = -1e30f;
      }
    __syncthreads();                       // all threads done reading KPs as K
    // online softmax, write P into KPs
    #pragma unroll
    for (int i = 0; i < 4; ++i){
      float rm = fmaxf(fmaxf(s[i][0], s[i][1]), fmaxf(s[i][2], s[i][3]));
      rm = fmaxf(rm, __shfl_xor(rm, 1, 64));
      rm = fmaxf(rm, __shfl_xor(rm, 2, 64));
      rm = fmaxf(rm, __shfl_xor(rm, 4, 64));
      rm = fmaxf(rm, __shfl_xor(rm, 8, 64));
      float mn = fmaxf(mrun[i], rm);
      float fac = expf(mrun[i] - mn);
      mrun[i] = mn;
      lrun[i] *= fac;
      float p[4], rs = 0.f;
      #pragma unroll
      for (int j = 0; j < 4; ++j){ p[j] = expf(s[i][j] - mn); rs += p[j]; }
      rs += __shfl_xor(rs, 1, 64);
      rs += __shfl_xor(rs, 2, 64);
      rs += __shfl_xor(rs, 4, 64);
      rs += __shfl_xor(rs, 8, 64);
      lrun[i] += rs;
      #pragma unroll
      for (int j = 0; j < 4; ++j){ Oa[i][j] *= fac; KPs[ty * 4 + i][tx * 4 + j] = p[j]; }
    }
    __syncthreads();
    // O += P V
    #pragma unroll 4
    for (int n = 0; n < 64; ++n){
      float4 v4 = *(const float4*)&Vs[n][tx * 4];
      float vv[4] = {v4.x, v4.y, v4.z, v4.w};
      #pragma unroll
      for (int i = 0; i < 4; ++i){
        float pv = KPs[ty * 4 + i][n];
        #pragma unroll
        for (int j = 0; j < 4; ++j)
          Oa[i][j] = fmaf(pv, vv[j], Oa[i][j]);
      }
    }
  }
  // write O (o layout: [bt][q][h*64+d])
  #pragma unroll
  for (int i = 0; i < 4; ++i){
    int q = q0 + ty * 4 + i;
    if (q < N_TOK){
      float inv = 1.0f / lrun[i];
      #pragma unroll
      for (int j = 0; j < 4; ++j)
        o_out[((size_t)bt * N_TOK + q) * C_DIM + hh * 64 + tx * 4 + j] = Oa[i][j] * inv;
    }
  }
}

// ============================ router (exact JAX partitionable noise + top2) ============================
__global__ __launch_bounds__(256) void k_router(
    const float* __restrict__ y, const float* __restrict__ rw, const float* __restrict__ rb,
    const float* __restrict__ rlw, const float* __restrict__ rlb,
    float* __restrict__ topw, int* __restrict__ elist, int* __restrict__ ecnt, int l)
{
  const int wid = threadIdx.x >> 6, lane = threadIdx.x & 63;
  const int tok = blockIdx.x * 4 + wid;
  const int e = lane & 7, seg = lane >> 3;
  const float* yr = y + (size_t)tok * C_DIM + seg * 96;
  const float* wr = rw + (size_t)e * C_DIM + seg * 96;
  float part = 0.f;
  #pragma unroll 8
  for (int i = 0; i < 96; ++i) part = fmaf(yr[i], wr[i], part);
  part += __shfl_xor(part, 8, 64);
  part += __shfl_xor(part, 16, 64);
  part += __shfl_xor(part, 32, 64);
  float logit = part + rb[e];
  float ssum = logit;
  ssum += __shfl_xor(ssum, 1, 64); ssum += __shfl_xor(ssum, 2, 64); ssum += __shfl_xor(ssum, 4, 64);
  float mean = ssum * 0.125f;
  float d = logit - mean;
  float vs = d * d;
  vs += __shfl_xor(vs, 1, 64); vs += __shfl_xor(vs, 2, 64); vs += __shfl_xor(vs, 4, 64);
  float ln = d * (1.0f / sqrtf(vs * 0.125f + 1e-5f)) * rlw[e] + rlb[e];
  float mx = ln;
  mx = fmaxf(mx, __shfl_xor(mx, 1, 64)); mx = fmaxf(mx, __shfl_xor(mx, 2, 64)); mx = fmaxf(mx, __shfl_xor(mx, 4, 64));
  float ex = expf(ln - mx);
  float es = ex;
  es += __shfl_xor(es, 1, 64); es += __shfl_xor(es, 2, 64); es += __shfl_xor(es, 4, 64);
  float prob = ex / es;
  int t = tok / 6176;
  int rem = tok - t * 6176;
  int b = rem / N_TOK, n = rem - (rem / N_TOK) * N_TOK;
  uint32_t b0, b1, c0, c1;
  tf2x32(0u, 1234u, 0u, (uint32_t)t, b0, b1);
  tf2x32(b0, b1, 0u, (uint32_t)l, c0, c1);
  uint32_t j = (uint32_t)(b * N_TOK + n) * 8u + (uint32_t)e;
  float r = prob + jax_noise(c0, c1, j);
  float v1 = r; int i1 = e;
  #pragma unroll
  for (int off = 1; off <= 4; off <<= 1){
    float ov = __shfl_xor(v1, off, 64); int oi = __shfl_xor(i1, off, 64);
    if (ov > v1 || (ov == v1 && oi < i1)){ v1 = ov; i1 = oi; }
  }
  float rm = (e == i1) ? -3.0e38f : r;
  float v2 = rm; int i2 = e;
  #pragma unroll
  for (int off = 1; off <= 4; off <<= 1){
    float ov = __shfl_xor(v2, off, 64); int oi = __shfl_xor(i2, off, 64);
    if (ov > v2 || (ov == v2 && oi < i2)){ v2 = ov; i2 = oi; }
  }
  float e2 = expf(v2 - v1);
  float sum = 1.0f + e2;
  if (lane == 0){
    topw[tok * 2 + 0] = 1.0f / sum;
    topw[tok * 2 + 1] = e2 / sum;
    int pos = atomicAdd(&ecnt[i1], 1);
    elist[i1 * MAXPER + pos] = tok * 2;
    int pos2 = atomicAdd(&ecnt[i2], 1);
    elist[i2 * MAXPER + pos2] = tok * 2 + 1;
  }
}

__global__ __launch_bounds__(256) void k_combine(float* __restrict__ h, const float* __restrict__ eout,
                                                 const float* __restrict__ topw){
  const int tok = blockIdx.x;
  const float w0 = topw[tok * 2], w1 = topw[tok * 2 + 1];
  const size_t hb = (size_t)tok * C_DIM;
  const size_t e0 = (size_t)(tok * 2) * C_DIM, e1 = e0 + C_DIM;
  #pragma unroll
  for (int u = 0; u < 3; ++u){
    int c = threadIdx.x + u * 256;
    h[hb + c] += w0 * eout[e0 + c] + w1 * eout[e1 + c];
  }
}

// ============================ host launch ============================
extern "C" void kernel_launch(void* const* d_in, const int* in_sizes, int n_in,
                              void* d_out, int out_size, void* d_ws, size_t ws_size,
                              hipStream_t stream){
  float* out = (float*)d_out;

  // interface tripwires (host-side only; all verified passing in rounds 2-5)
  static const int kExp[22] = {
    14155776, 14155776, 1769472, 768, 768,
    4608, 4608, 10616832, 13824, 3538944, 4608,
    4608, 4608, 36864, 48, 48, 48,
    28311552, 36864, 768, 768, 148224};
  const size_t need_f = (size_t)ROWS * C_DIM * 2 + (size_t)ROWS * QKV_DIM
                      + (size_t)ROWS * 2 + (size_t)N_EXP * MAXPER + 8;
  float bad = 0.f;
  if (n_in != 22) bad = 2.0e6f;
  else {
    for (int i = 0; i < 22; ++i)
      if (in_sizes[i] != kExp[i]){ bad = 4.0e6f + i * 1.0e4f; break; }
  }
  if (bad == 0.f && out_size != 49152) bad = 3.0e6f;
  if (bad == 0.f && ws_size < need_f * 4) bad = 1.0e6f;
  if (bad != 0.f){
    k_sentinel<<<dim3(1), 64, 0, stream>>>(out, bad);
    return;
  }

  const float* x1       = (const float*)d_in[0];
  const float* x2       = (const float*)d_in[1];
  const float* patch_w  = (const float*)d_in[2];
  const float* patch_b  = (const float*)d_in[3];
  const float* cls_tok  = (const float*)d_in[4];
  const float* ln1_w    = (const float*)d_in[5];
  const float* ln1_b    = (const float*)d_in[6];
  const float* qkv_w    = (const float*)d_in[7];
  const float* qkv_b    = (const float*)d_in[8];
  const float* proj_w   = (const float*)d_in[9];
  const float* proj_b   = (const float*)d_in[10];
  const float* ln2_w    = (const float*)d_in[11];
  const float* ln2_b    = (const float*)d_in[12];
  const float* route_w  = (const float*)d_in[13];
  const float* route_b  = (const float*)d_in[14];
  const float* rln_w    = (const float*)d_in[15];
  const float* rln_b    = (const float*)d_in[16];
  const float* expert_w = (const float*)d_in[17];
  const float* expert_b = (const float*)d_in[18];
  const float* norm_w   = (const float*)d_in[19];
  const float* norm_b   = (const float*)d_in[20];
  const float* pos_emb  = (const float*)d_in[21];

  // workspace layout (fp32): h | y | qkv (eout aliases qkv) | topw | elist | ecnt
  float* ws = (float*)d_ws;
  size_t off = 0;
  float* h    = ws + off; off += (size_t)ROWS * C_DIM;
  float* y    = ws + off; off += (size_t)ROWS * C_DIM;
  float* qkv  = ws + off; off += (size_t)ROWS * QKV_DIM;
  float* eout = qkv;                         // expert outputs reuse qkv region (dead after attention)
  float* topw = ws + off; off += (size_t)ROWS * 2;
  int*   elist = (int*)(ws + off); off += (size_t)N_EXP * MAXPER;
  int*   ecnt  = (int*)(ws + off); off += 8;

  // patch embed + cls + pos
  k_cls<<<dim3(B_TOT), 256, 0, stream>>>(h, cls_tok, pos_emb);
  k_gemm<MODE_PATCH><<<dim3(96, 6), 256, 0, stream>>>(
      nullptr, patch_w, patch_b, h, 12288, C_DIM, 2304, x1, x2, pos_emb, nullptr, nullptr);

  for (int l = 0; l < 6; ++l){
    k_layernorm<<<dim3(ROWS), 256, 0, stream>>>(h, y, ln1_w + l * C_DIM, ln1_b + l * C_DIM);
    k_gemm<MODE_PLAIN><<<dim3(97, 18), 256, 0, stream>>>(
        y, qkv_w + (size_t)l * QKV_DIM * C_DIM, qkv_b + l * QKV_DIM, qkv,
        ROWS, QKV_DIM, C_DIM, nullptr, nullptr, nullptr, nullptr, nullptr);
    k_attn<<<dim3(4, B_TOT * N_HEAD), 256, 0, stream>>>(qkv, y);   // o -> y
    k_gemm<MODE_RESID><<<dim3(97, 6), 256, 0, stream>>>(
        y, proj_w + (size_t)l * C_DIM * C_DIM, proj_b + l * C_DIM, h,
        ROWS, C_DIM, C_DIM, nullptr, nullptr, nullptr, nullptr, nullptr);
    k_layernorm<<<dim3(ROWS), 256, 0, stream>>>(h, y, ln2_w + l * C_DIM, ln2_b + l * C_DIM);
    k_zero8<<<dim3(1), 64, 0, stream>>>(ecnt);
    k_router<<<dim3(ROWS / 4), 256, 0, stream>>>(
        y, route_w + (size_t)l * N_EXP * C_DIM, route_b + l * N_EXP,
        rln_w + l * N_EXP, rln_b + l * N_EXP, topw, elist, ecnt, l);
    k_gemm<MODE_EXPERT><<<dim3(97, 6, N_EXP), 256, 0, stream>>>(
        y, expert_w + (size_t)l * N_EXP * C_DIM * C_DIM, expert_b + (size_t)l * N_EXP * C_DIM, eout,
        ROWS, C_DIM, C_DIM, nullptr, nullptr, nullptr, elist, ecnt);
    k_combine<<<dim3(ROWS), 256, 0, stream>>>(h, eout, topw);
  }
  k_final<<<dim3(B_TOT), 256, 0, stream>>>(h, out, norm_w, norm_b);
}

// Round 7
// 6001.486 us; speedup vs baseline: 3.9330x; 1.8863x over previous
//
#include <hip/hip_runtime.h>
#include <stdint.h>

// ============================ problem constants ============================
#define C_DIM   768
#define N_TOK   193
#define B_TOT   64                    // 2 towers x 32 batch
#define ROWS    (B_TOT * N_TOK)       // 12352
#define QKV_DIM 2304
#define N_HEAD  12
#define N_EXP   8
#define MAXPER  ROWS

enum { MODE_PATCH = 0, MODE_PLAIN = 1, MODE_RESID = 2, MODE_EXPERT = 3 };

typedef __attribute__((ext_vector_type(8))) short bf16x8;
typedef __attribute__((ext_vector_type(4))) float f32x4;

// ============================ threefry-2x32 (bit-exact vs JAX) ============================
__device__ __forceinline__ uint32_t rotl32(uint32_t x, int n){ return (x << n) | (x >> (32 - n)); }

__device__ __forceinline__ void tf2x32(uint32_t k0, uint32_t k1, uint32_t x0, uint32_t x1,
                                       uint32_t &r0, uint32_t &r1){
  uint32_t k2 = k0 ^ k1 ^ 0x1BD11BDAu;
#define TF4(a,b,c,d) x0+=x1; x1=rotl32(x1,a); x1^=x0; x0+=x1; x1=rotl32(x1,b); x1^=x0; \
                     x0+=x1; x1=rotl32(x1,c); x1^=x0; x0+=x1; x1=rotl32(x1,d); x1^=x0;
  x0 += k0; x1 += k1;
  TF4(13,15,26, 6)  x0 += k1; x1 += k2 + 1u;
  TF4(17,29,16,24)  x0 += k2; x1 += k0 + 2u;
  TF4(13,15,26, 6)  x0 += k0; x1 += k1 + 3u;
  TF4(17,29,16,24)  x0 += k1; x1 += k2 + 4u;
  TF4(13,15,26, 6)  x0 += k2; x1 += k0 + 5u;
#undef TF4
  r0 = x0; r1 = x1;
}

__device__ __forceinline__ float jax_erfinv(float x){
  float w = -log1pf(-x * x);
  float p;
  if (w < 5.0f){
    w -= 2.5f;
    p =              2.81022636e-08f;
    p = fmaf(p, w,   3.43273939e-07f);
    p = fmaf(p, w,  -3.5233877e-06f);
    p = fmaf(p, w,  -4.39150654e-06f);
    p = fmaf(p, w,   0.00021858087f);
    p = fmaf(p, w,  -0.00125372503f);
    p = fmaf(p, w,  -0.00417768164f);
    p = fmaf(p, w,   0.246640727f);
    p = fmaf(p, w,   1.50140941f);
  } else {
    w = sqrtf(w) - 3.0f;
    p =             -0.000200214257f;
    p = fmaf(p, w,   0.000100950558f);
    p = fmaf(p, w,   0.00134934322f);
    p = fmaf(p, w,  -0.00367342844f);
    p = fmaf(p, w,   0.00573950773f);
    p = fmaf(p, w,  -0.0076224613f);
    p = fmaf(p, w,   0.00943887047f);
    p = fmaf(p, w,   1.00167406f);
    p = fmaf(p, w,   2.83297682f);
  }
  return p * x;
}

// PARTITIONABLE threefry random_bits (JAX >= 0.4.36 default) [verified round 5]
__device__ __forceinline__ float jax_noise(uint32_t c0, uint32_t c1, uint32_t j){
  uint32_t o0, o1;
  tf2x32(c0, c1, 0u, j, o0, o1);
  uint32_t bits = o0 ^ o1;
  float f = __uint_as_float(0x3f800000u | (bits >> 9)) - 1.0f;   // [0,1)
  const float lo = -0.99999994f;                                  // nextafter(-1,0)
  float u = fmaxf(lo, f * 2.0f + lo);
  return 1.41421356237f * jax_erfinv(u) * 0.125f;                 // sqrt(2)*erfinv(u)/E
}

// ============================ bf16 split helpers ============================
__device__ __forceinline__ unsigned short f2bf(float x){
  union { float f; uint32_t u; } v; v.f = x;
  uint32_t u = v.u;
  uint32_t r = (u + 0x7FFFu + ((u >> 16) & 1u)) >> 16;   // RNE
  return (unsigned short)r;
}
__device__ __forceinline__ float bf2f(unsigned short h){
  union { uint32_t u; float f; } v; v.u = ((uint32_t)h) << 16;
  return v.f;
}

// ============================ small kernels ============================
__global__ __launch_bounds__(64) void k_zero8(int* __restrict__ p){
  if ((int)threadIdx.x < N_EXP) p[threadIdx.x] = 0;
}

__global__ __launch_bounds__(64) void k_sentinel(float* __restrict__ out, float v){
  if (threadIdx.x == 0) out[0] = v;
}

__global__ __launch_bounds__(256) void k_cls(float* __restrict__ h, const float* __restrict__ cls,
                                             const float* __restrict__ pos){
  const int bt = blockIdx.x;
  #pragma unroll
  for (int u = 0; u < 3; ++u){
    int c = threadIdx.x + u * 256;
    h[(size_t)bt * N_TOK * C_DIM + c] = cls[c] + pos[c];
  }
}

__device__ __forceinline__ float blk_sum(float v, float* sb){
  #pragma unroll
  for (int off = 32; off > 0; off >>= 1) v += __shfl_down(v, off, 64);
  const int lane = threadIdx.x & 63, w = threadIdx.x >> 6;
  if (lane == 0) sb[w] = v;
  __syncthreads();
  if (threadIdx.x == 0) sb[4] = sb[0] + sb[1] + sb[2] + sb[3];
  __syncthreads();
  float r = sb[4];
  __syncthreads();
  return r;
}

__global__ __launch_bounds__(256) void k_layernorm(const float* __restrict__ x, float* __restrict__ y,
                                                   const float* __restrict__ w, const float* __restrict__ b){
  __shared__ float sb[8];
  const float* xr = x + (size_t)blockIdx.x * C_DIM;
  float v0 = xr[threadIdx.x], v1 = xr[threadIdx.x + 256], v2 = xr[threadIdx.x + 512];
  float mean = blk_sum(v0 + v1 + v2, sb) * (1.0f / 768.0f);
  float d0 = v0 - mean, d1 = v1 - mean, d2 = v2 - mean;
  float var = blk_sum(d0 * d0 + d1 * d1 + d2 * d2, sb) * (1.0f / 768.0f);
  float inv = 1.0f / sqrtf(var + 1e-5f);
  float* yr = y + (size_t)blockIdx.x * C_DIM;
  yr[threadIdx.x]       = d0 * inv * w[threadIdx.x]       + b[threadIdx.x];
  yr[threadIdx.x + 256] = d1 * inv * w[threadIdx.x + 256] + b[threadIdx.x + 256];
  yr[threadIdx.x + 512] = d2 * inv * w[threadIdx.x + 512] + b[threadIdx.x + 512];
}

__global__ __launch_bounds__(256) void k_final(const float* __restrict__ h, float* __restrict__ out,
                                               const float* __restrict__ w, const float* __restrict__ b){
  __shared__ float sb[8];
  const int bt = blockIdx.x;
  const float* xr = h + (size_t)bt * N_TOK * C_DIM;
  float v0 = xr[threadIdx.x], v1 = xr[threadIdx.x + 256], v2 = xr[threadIdx.x + 512];
  float mean = blk_sum(v0 + v1 + v2, sb) * (1.0f / 768.0f);
  float d0 = v0 - mean, d1 = v1 - mean, d2 = v2 - mean;
  float var = blk_sum(d0 * d0 + d1 * d1 + d2 * d2, sb) * (1.0f / 768.0f);
  float inv = 1.0f / sqrtf(var + 1e-5f);
  float* orow = out + (size_t)(bt & 31) * 1536 + (size_t)(bt >> 5) * C_DIM;
  orow[threadIdx.x]       = d0 * inv * w[threadIdx.x]       + b[threadIdx.x];
  orow[threadIdx.x + 256] = d1 * inv * w[threadIdx.x + 256] + b[threadIdx.x + 256];
  orow[threadIdx.x + 512] = d2 * inv * w[threadIdx.x + 512] + b[threadIdx.x + 512];
}

// ============================ MFMA GEMM (bf16x2 split): C = A @ W^T (+variants) ============================
// 128x128 tile, BK=32, 4 waves each computing 64x64 via 16x16x32 bf16 MFMA.
// Split: a = hi + lo (bf16 each); a*b ~= hiA*hiB + hiA*loB + loA*hiB  (err ~2^-16 rel).
template<int MODE>
__global__ __launch_bounds__(256) void k_mgemm(
    const float* __restrict__ A, const float* __restrict__ W,
    const float* __restrict__ bias, float* __restrict__ C,
    int M, int Nc, int Kc,
    const float* __restrict__ xa, const float* __restrict__ xb,   // MODE_PATCH: x1/x2
    const float* __restrict__ pos,                                 // MODE_PATCH: pos_emb
    const int* __restrict__ elist, const int* __restrict__ ecnt)  // MODE_EXPERT
{
  __shared__ short sAhi[128][40];
  __shared__ short sAlo[128][40];
  __shared__ short sBhi[128][40];
  __shared__ short sBlo[128][40];

  const int tid = threadIdx.x;

  int e = 0;
  int Mloc = M;
  const float* Wp = W;
  const float* bp = bias;
  if constexpr (MODE == MODE_EXPERT){
    e = blockIdx.z;
    Mloc = ecnt[e];
    Wp = W + (size_t)e * C_DIM * C_DIM;
    bp = bias + e * C_DIM;
  }
  const int row0 = blockIdx.x * 128;
  const int col0 = blockIdx.y * 128;
  if (row0 >= Mloc) return;

  // staging assignment: thread t stages row srow, k-half skh (16 k's)
  const int srow = tid >> 1;
  const int skh  = (tid & 1) * 16;

  const float* arow = A;
  bool avalid = false;
  const float* psrc = nullptr;
  if constexpr (MODE == MODE_PLAIN || MODE == MODE_RESID){
    int r = row0 + srow;
    avalid = r < Mloc;
    arow = A + (size_t)(avalid ? r : 0) * Kc;
  } else if constexpr (MODE == MODE_EXPERT){
    int r = row0 + srow;
    avalid = r < Mloc;
    if (avalid) arow = A + (size_t)(elist[e * MAXPER + r] >> 1) * C_DIM;
  } else { // MODE_PATCH: xp[row][k] = x[b][c][hh][2n+p], k = c*768 + 2*hh + p ; M=12288 exact
    int r = row0 + srow;
    int bt = r / 192;
    int n  = r - bt * 192;
    const float* xp = (bt < 32) ? xa : xb;
    psrc = xp + (size_t)(bt & 31) * 3 * 384 * 384 + n * 2;
    avalid = true;
  }
  const float* brow = Wp + (size_t)(col0 + srow) * Kc;

  // wave -> 64x64 sub-tile
  const int wv = tid >> 6;
  const int wr = (wv >> 1) * 64;
  const int wc = (wv & 1) * 64;
  const int lane = tid & 63;
  const int lrow = lane & 15;
  const int lkh  = (lane >> 4) * 8;

  f32x4 acc[4][4] = {};

  const int nkt = Kc / 32;
  for (int kt = 0; kt < nkt; ++kt){
    const int k0 = kt * 32 + skh;
    // ---- stage A ----
    {
      float va[16] = {};
      if constexpr (MODE == MODE_PATCH){
        int c   = k0 / 768;
        int rem = k0 - c * 768;
        const float* pc = psrc + ((size_t)c * 384 + (rem >> 1)) * 384;
        #pragma unroll
        for (int m = 0; m < 8; ++m){
          va[m * 2 + 0] = pc[(size_t)m * 384 + 0];
          va[m * 2 + 1] = pc[(size_t)m * 384 + 1];
        }
      } else {
        if (avalid){
          *(float4*)&va[0]  = *(const float4*)(arow + k0);
          *(float4*)&va[4]  = *(const float4*)(arow + k0 + 4);
          *(float4*)&va[8]  = *(const float4*)(arow + k0 + 8);
          *(float4*)&va[12] = *(const float4*)(arow + k0 + 12);
        }
      }
      short hi[16], lo[16];
      #pragma unroll
      for (int j = 0; j < 16; ++j){
        unsigned short hb = f2bf(va[j]);
        hi[j] = (short)hb;
        lo[j] = (short)f2bf(va[j] - bf2f(hb));
      }
      *(bf16x8*)&sAhi[srow][skh]     = *(bf16x8*)&hi[0];
      *(bf16x8*)&sAhi[srow][skh + 8] = *(bf16x8*)&hi[8];
      *(bf16x8*)&sAlo[srow][skh]     = *(bf16x8*)&lo[0];
      *(bf16x8*)&sAlo[srow][skh + 8] = *(bf16x8*)&lo[8];
    }
    // ---- stage B ----
    {
      float vb[16];
      *(float4*)&vb[0]  = *(const float4*)(brow + k0);
      *(float4*)&vb[4]  = *(const float4*)(brow + k0 + 4);
      *(float4*)&vb[8]  = *(const float4*)(brow + k0 + 8);
      *(float4*)&vb[12] = *(const float4*)(brow + k0 + 12);
      short hi[16], lo[16];
      #pragma unroll
      for (int j = 0; j < 16; ++j){
        unsigned short hb = f2bf(vb[j]);
        hi[j] = (short)hb;
        lo[j] = (short)f2bf(vb[j] - bf2f(hb));
      }
      *(bf16x8*)&sBhi[srow][skh]     = *(bf16x8*)&hi[0];
      *(bf16x8*)&sBhi[srow][skh + 8] = *(bf16x8*)&hi[8];
      *(bf16x8*)&sBlo[srow][skh]     = *(bf16x8*)&lo[0];
      *(bf16x8*)&sBlo[srow][skh + 8] = *(bf16x8*)&lo[8];
    }
    __syncthreads();
    // ---- MFMA ----
    bf16x8 ahi[4], alo[4], bhi[4], blo[4];
    #pragma unroll
    for (int i = 0; i < 4; ++i){
      ahi[i] = *(const bf16x8*)&sAhi[wr + i * 16 + lrow][lkh];
      alo[i] = *(const bf16x8*)&sAlo[wr + i * 16 + lrow][lkh];
    }
    #pragma unroll
    for (int j = 0; j < 4; ++j){
      bhi[j] = *(const bf16x8*)&sBhi[wc + j * 16 + lrow][lkh];
      blo[j] = *(const bf16x8*)&sBlo[wc + j * 16 + lrow][lkh];
    }
    #pragma unroll
    for (int i = 0; i < 4; ++i)
      #pragma unroll
      for (int j = 0; j < 4; ++j){
        acc[i][j] = __builtin_amdgcn_mfma_f32_16x16x32_bf16(ahi[i], bhi[j], acc[i][j], 0, 0, 0);
        acc[i][j] = __builtin_amdgcn_mfma_f32_16x16x32_bf16(ahi[i], blo[j], acc[i][j], 0, 0, 0);
        acc[i][j] = __builtin_amdgcn_mfma_f32_16x16x32_bf16(alo[i], bhi[j], acc[i][j], 0, 0, 0);
      }
    __syncthreads();
  }

  // ---- epilogue: C/D layout col = lane&15, row = (lane>>4)*4 + reg ----
  #pragma unroll
  for (int i = 0; i < 4; ++i){
    const int rbase = row0 + wr + i * 16 + (lane >> 4) * 4;
    #pragma unroll
    for (int r = 0; r < 4; ++r){
      const int rg = rbase + r;
      if (rg >= Mloc) continue;
      if constexpr (MODE == MODE_PATCH){
        int bt = rg / 192, n = rg - (rg / 192) * 192;
        size_t orow = ((size_t)bt * N_TOK + n + 1) * C_DIM;
        size_t prow = (size_t)(n + 1) * C_DIM;
        #pragma unroll
        for (int j = 0; j < 4; ++j){
          int cg = col0 + wc + j * 16 + (lane & 15);
          C[orow + cg] = acc[i][j][r] + bp[cg] + pos[prow + cg];
        }
      } else if constexpr (MODE == MODE_PLAIN){
        size_t orow = (size_t)rg * Nc;
        #pragma unroll
        for (int j = 0; j < 4; ++j){
          int cg = col0 + wc + j * 16 + (lane & 15);
          C[orow + cg] = acc[i][j][r] + bp[cg];
        }
      } else if constexpr (MODE == MODE_RESID){
        size_t orow = (size_t)rg * Nc;
        #pragma unroll
        for (int j = 0; j < 4; ++j){
          int cg = col0 + wc + j * 16 + (lane & 15);
          C[orow + cg] += acc[i][j][r] + bp[cg];
        }
      } else { // EXPERT: out row = token*2 + slot
        int ts = elist[e * MAXPER + rg];
        size_t orow = (size_t)ts * C_DIM;
        #pragma unroll
        for (int j = 0; j < 4; ++j){
          int cg = col0 + wc + j * 16 + (lane & 15);
          C[orow + cg] = acc[i][j][r] + bp[cg];
        }
      }
    }
  }
}

// ============================ attention (flash-style, fp32, 64x64 tiles) ============================
__global__ __launch_bounds__(256) void k_attn(const float* __restrict__ qkv, float* __restrict__ o_out){
  __shared__ float Qs[64][64];   // [d][m]
  __shared__ float KPs[64][64];  // K as [d][n], later P as [m][n]
  __shared__ float Vs[64][64];   // [n][d]
  const int q0 = blockIdx.x * 64;
  const int bh = blockIdx.y;
  const int bt = bh / N_HEAD, hh = bh - bt * N_HEAD;
  const int tid = threadIdx.x;
  const int tx = tid & 15, ty = tid >> 4;
  const size_t base = (size_t)bt * N_TOK * QKV_DIM + (size_t)hh * 64;

  { // stage Q transposed
    int m = tid & 63, g = tid >> 6;
    int q = q0 + m;
    bool valid = q < N_TOK;
    const float* src = qkv + base + (size_t)(valid ? q : 0) * QKV_DIM;
    #pragma unroll
    for (int u = 0; u < 4; ++u){
      int cb = (g * 4 + u) * 4;
      float4 v = valid ? *(const float4*)(src + cb) : make_float4(0.f,0.f,0.f,0.f);
      Qs[cb + 0][m] = v.x; Qs[cb + 1][m] = v.y; Qs[cb + 2][m] = v.z; Qs[cb + 3][m] = v.w;
    }
  }

  float Oa[4][4] = {};
  float mrun[4] = {-1e30f, -1e30f, -1e30f, -1e30f};
  float lrun[4] = {};

  for (int kt = 0; kt < 4; ++kt){
    const int n0 = kt * 64;
    __syncthreads();
    { // stage K transposed
      int m = tid & 63, g = tid >> 6;
      int kk = n0 + m;
      bool valid = kk < N_TOK;
      const float* src = qkv + base + 768 + (size_t)(valid ? kk : 0) * QKV_DIM;
      #pragma unroll
      for (int u = 0; u < 4; ++u){
        int cb = (g * 4 + u) * 4;
        float4 v = valid ? *(const float4*)(src + cb) : make_float4(0.f,0.f,0.f,0.f);
        KPs[cb + 0][m] = v.x; KPs[cb + 1][m] = v.y; KPs[cb + 2][m] = v.z; KPs[cb + 3][m] = v.w;
      }
    }
    { // stage V direct
      int c4 = tid & 15, nr = tid >> 4;
      #pragma unroll
      for (int r = 0; r < 4; ++r){
        int n = nr + r * 16;
        int kk = n0 + n;
        float4 v = (kk < N_TOK) ? *(const float4*)(qkv + base + 1536 + (size_t)kk * QKV_DIM + c4 * 4)
                                : make_float4(0.f,0.f,0.f,0.f);
        *(float4*)&Vs[n][c4 * 4] = v;
      }
    }
    __syncthreads();
    float s[4][4] = {};
    #pragma unroll 8
    for (int d = 0; d < 64; ++d){
      float4 a4 = *(const float4*)&Qs[d][ty * 4];
      float4 b4 = *(const float4*)&KPs[d][tx * 4];
      float av[4] = {a4.x, a4.y, a4.z, a4.w};
      float bv[4] = {b4.x, b4.y, b4.z, b4.w};
      #pragma unroll
      for (int i = 0; i < 4; ++i)
        #pragma unroll
        for (int j = 0; j < 4; ++j)
          s[i][j] = fmaf(av[i], bv[j], s[i][j]);
    }
    #pragma unroll
    for (int i = 0; i < 4; ++i)
      #pragma unroll
      for (int j = 0; j < 4; ++j){
        s[i][j] *= 0.125f;
        if (n0 + tx * 4 + j >= N_TOK) s[i][j] = -1e30f;
      }
    __syncthreads();
    #pragma unroll
    for (int i = 0; i < 4; ++i){
      float rm = fmaxf(fmaxf(s[i][0], s[i][1]), fmaxf(s[i][2], s[i][3]));
      rm = fmaxf(rm, __shfl_xor(rm, 1, 64));
      rm = fmaxf(rm, __shfl_xor(rm, 2, 64));
      rm = fmaxf(rm, __shfl_xor(rm, 4, 64));
      rm = fmaxf(rm, __shfl_xor(rm, 8, 64));
      float mn = fmaxf(mrun[i], rm);
      float fac = expf(mrun[i] - mn);
      mrun[i] = mn;
      lrun[i] *= fac;
      float p[4], rs = 0.f;
      #pragma unroll
      for (int j = 0; j < 4; ++j){ p[j] = expf(s[i][j] - mn); rs += p[j]; }
      rs += __shfl_xor(rs, 1, 64);
      rs += __shfl_xor(rs, 2, 64);
      rs += __shfl_xor(rs, 4, 64);
      rs += __shfl_xor(rs, 8, 64);
      lrun[i] += rs;
      #pragma unroll
      for (int j = 0; j < 4; ++j){ Oa[i][j] *= fac; KPs[ty * 4 + i][tx * 4 + j] = p[j]; }
    }
    __syncthreads();
    #pragma unroll 4
    for (int n = 0; n < 64; ++n){
      float4 v4 = *(const float4*)&Vs[n][tx * 4];
      float vv[4] = {v4.x, v4.y, v4.z, v4.w};
      #pragma unroll
      for (int i = 0; i < 4; ++i){
        float pv = KPs[ty * 4 + i][n];
        #pragma unroll
        for (int j = 0; j < 4; ++j)
          Oa[i][j] = fmaf(pv, vv[j], Oa[i][j]);
      }
    }
  }
  #pragma unroll
  for (int i = 0; i < 4; ++i){
    int q = q0 + ty * 4 + i;
    if (q < N_TOK){
      float inv = 1.0f / lrun[i];
      #pragma unroll
      for (int j = 0; j < 4; ++j)
        o_out[((size_t)bt * N_TOK + q) * C_DIM + hh * 64 + tx * 4 + j] = Oa[i][j] * inv;
    }
  }
}

// ============================ router (exact JAX partitionable noise + top2) ============================
__global__ __launch_bounds__(256) void k_router(
    const float* __restrict__ y, const float* __restrict__ rw, const float* __restrict__ rb,
    const float* __restrict__ rlw, const float* __restrict__ rlb,
    float* __restrict__ topw, int* __restrict__ elist, int* __restrict__ ecnt, int l)
{
  const int wid = threadIdx.x >> 6, lane = threadIdx.x & 63;
  const int tok = blockIdx.x * 4 + wid;
  const int e = lane & 7, seg = lane >> 3;
  const float* yr = y + (size_t)tok * C_DIM + seg * 96;
  const float* wr = rw + (size_t)e * C_DIM + seg * 96;
  float part = 0.f;
  #pragma unroll 8
  for (int i = 0; i < 96; ++i) part = fmaf(yr[i], wr[i], part);
  part += __shfl_xor(part, 8, 64);
  part += __shfl_xor(part, 16, 64);
  part += __shfl_xor(part, 32, 64);
  float logit = part + rb[e];
  float ssum = logit;
  ssum += __shfl_xor(ssum, 1, 64); ssum += __shfl_xor(ssum, 2, 64); ssum += __shfl_xor(ssum, 4, 64);
  float mean = ssum * 0.125f;
  float d = logit - mean;
  float vs = d * d;
  vs += __shfl_xor(vs, 1, 64); vs += __shfl_xor(vs, 2, 64); vs += __shfl_xor(vs, 4, 64);
  float ln = d * (1.0f / sqrtf(vs * 0.125f + 1e-5f)) * rlw[e] + rlb[e];
  float mx = ln;
  mx = fmaxf(mx, __shfl_xor(mx, 1, 64)); mx = fmaxf(mx, __shfl_xor(mx, 2, 64)); mx = fmaxf(mx, __shfl_xor(mx, 4, 64));
  float ex = expf(ln - mx);
  float es = ex;
  es += __shfl_xor(es, 1, 64); es += __shfl_xor(es, 2, 64); es += __shfl_xor(es, 4, 64);
  float prob = ex / es;
  int t = tok / 6176;
  int rem = tok - t * 6176;
  int b = rem / N_TOK, n = rem - (rem / N_TOK) * N_TOK;
  uint32_t b0, b1, c0, c1;
  tf2x32(0u, 1234u, 0u, (uint32_t)t, b0, b1);
  tf2x32(b0, b1, 0u, (uint32_t)l, c0, c1);
  uint32_t j = (uint32_t)(b * N_TOK + n) * 8u + (uint32_t)e;
  float r = prob + jax_noise(c0, c1, j);
  float v1 = r; int i1 = e;
  #pragma unroll
  for (int off = 1; off <= 4; off <<= 1){
    float ov = __shfl_xor(v1, off, 64); int oi = __shfl_xor(i1, off, 64);
    if (ov > v1 || (ov == v1 && oi < i1)){ v1 = ov; i1 = oi; }
  }
  float rm = (e == i1) ? -3.0e38f : r;
  float v2 = rm; int i2 = e;
  #pragma unroll
  for (int off = 1; off <= 4; off <<= 1){
    float ov = __shfl_xor(v2, off, 64); int oi = __shfl_xor(i2, off, 64);
    if (ov > v2 || (ov == v2 && oi < i2)){ v2 = ov; i2 = oi; }
  }
  float e2 = expf(v2 - v1);
  float sum = 1.0f + e2;
  if (lane == 0){
    topw[tok * 2 + 0] = 1.0f / sum;
    topw[tok * 2 + 1] = e2 / sum;
    int pos = atomicAdd(&ecnt[i1], 1);
    elist[i1 * MAXPER + pos] = tok * 2;
    int pos2 = atomicAdd(&ecnt[i2], 1);
    elist[i2 * MAXPER + pos2] = tok * 2 + 1;
  }
}

__global__ __launch_bounds__(256) void k_combine(float* __restrict__ h, const float* __restrict__ eout,
                                                 const float* __restrict__ topw){
  const int tok = blockIdx.x;
  const float w0 = topw[tok * 2], w1 = topw[tok * 2 + 1];
  const size_t hb = (size_t)tok * C_DIM;
  const size_t e0 = (size_t)(tok * 2) * C_DIM, e1 = e0 + C_DIM;
  #pragma unroll
  for (int u = 0; u < 3; ++u){
    int c = threadIdx.x + u * 256;
    h[hb + c] += w0 * eout[e0 + c] + w1 * eout[e1 + c];
  }
}

// ============================ host launch ============================
extern "C" void kernel_launch(void* const* d_in, const int* in_sizes, int n_in,
                              void* d_out, int out_size, void* d_ws, size_t ws_size,
                              hipStream_t stream){
  float* out = (float*)d_out;

  static const int kExp[22] = {
    14155776, 14155776, 1769472, 768, 768,
    4608, 4608, 10616832, 13824, 3538944, 4608,
    4608, 4608, 36864, 48, 48, 48,
    28311552, 36864, 768, 768, 148224};
  const size_t need_f = (size_t)ROWS * C_DIM * 2 + (size_t)ROWS * QKV_DIM
                      + (size_t)ROWS * 2 + (size_t)N_EXP * MAXPER + 8;
  float bad = 0.f;
  if (n_in != 22) bad = 2.0e6f;
  else {
    for (int i = 0; i < 22; ++i)
      if (in_sizes[i] != kExp[i]){ bad = 4.0e6f + i * 1.0e4f; break; }
  }
  if (bad == 0.f && out_size != 49152) bad = 3.0e6f;
  if (bad == 0.f && ws_size < need_f * 4) bad = 1.0e6f;
  if (bad != 0.f){
    k_sentinel<<<dim3(1), 64, 0, stream>>>(out, bad);
    return;
  }

  const float* x1       = (const float*)d_in[0];
  const float* x2       = (const float*)d_in[1];
  const float* patch_w  = (const float*)d_in[2];
  const float* patch_b  = (const float*)d_in[3];
  const float* cls_tok  = (const float*)d_in[4];
  const float* ln1_w    = (const float*)d_in[5];
  const float* ln1_b    = (const float*)d_in[6];
  const float* qkv_w    = (const float*)d_in[7];
  const float* qkv_b    = (const float*)d_in[8];
  const float* proj_w   = (const float*)d_in[9];
  const float* proj_b   = (const float*)d_in[10];
  const float* ln2_w    = (const float*)d_in[11];
  const float* ln2_b    = (const float*)d_in[12];
  const float* route_w  = (const float*)d_in[13];
  const float* route_b  = (const float*)d_in[14];
  const float* rln_w    = (const float*)d_in[15];
  const float* rln_b    = (const float*)d_in[16];
  const float* expert_w = (const float*)d_in[17];
  const float* expert_b = (const float*)d_in[18];
  const float* norm_w   = (const float*)d_in[19];
  const float* norm_b   = (const float*)d_in[20];
  const float* pos_emb  = (const float*)d_in[21];

  // workspace layout (fp32): h | y | qkv (eout aliases qkv) | topw | elist | ecnt
  float* ws = (float*)d_ws;
  size_t off = 0;
  float* h    = ws + off; off += (size_t)ROWS * C_DIM;
  float* y    = ws + off; off += (size_t)ROWS * C_DIM;
  float* qkv  = ws + off; off += (size_t)ROWS * QKV_DIM;
  float* eout = qkv;
  float* topw = ws + off; off += (size_t)ROWS * 2;
  int*   elist = (int*)(ws + off); off += (size_t)N_EXP * MAXPER;
  int*   ecnt  = (int*)(ws + off); off += 8;

  // patch embed + cls + pos
  k_cls<<<dim3(B_TOT), 256, 0, stream>>>(h, cls_tok, pos_emb);
  k_mgemm<MODE_PATCH><<<dim3(96, 6), 256, 0, stream>>>(
      nullptr, patch_w, patch_b, h, 12288, C_DIM, 2304, x1, x2, pos_emb, nullptr, nullptr);

  for (int l = 0; l < 6; ++l){
    k_layernorm<<<dim3(ROWS), 256, 0, stream>>>(h, y, ln1_w + l * C_DIM, ln1_b + l * C_DIM);
    k_mgemm<MODE_PLAIN><<<dim3(97, 18), 256, 0, stream>>>(
        y, qkv_w + (size_t)l * QKV_DIM * C_DIM, qkv_b + l * QKV_DIM, qkv,
        ROWS, QKV_DIM, C_DIM, nullptr, nullptr, nullptr, nullptr, nullptr);
    k_attn<<<dim3(4, B_TOT * N_HEAD), 256, 0, stream>>>(qkv, y);   // o -> y
    k_mgemm<MODE_RESID><<<dim3(97, 6), 256, 0, stream>>>(
        y, proj_w + (size_t)l * C_DIM * C_DIM, proj_b + l * C_DIM, h,
        ROWS, C_DIM, C_DIM, nullptr, nullptr, nullptr, nullptr, nullptr);
    k_layernorm<<<dim3(ROWS), 256, 0, stream>>>(h, y, ln2_w + l * C_DIM, ln2_b + l * C_DIM);
    k_zero8<<<dim3(1), 64, 0, stream>>>(ecnt);
    k_router<<<dim3(ROWS / 4), 256, 0, stream>>>(
        y, route_w + (size_t)l * N_EXP * C_DIM, route_b + l * N_EXP,
        rln_w + l * N_EXP, rln_b + l * N_EXP, topw, elist, ecnt, l);
    k_mgemm<MODE_EXPERT><<<dim3(97, 6, N_EXP), 256, 0, stream>>>(
        y, expert_w + (size_t)l * N_EXP * C_DIM * C_DIM, expert_b + (size_t)l * N_EXP * C_DIM, eout,
        ROWS, C_DIM, C_DIM, nullptr, nullptr, nullptr, elist, ecnt);
    k_combine<<<dim3(ROWS), 256, 0, stream>>>(h, eout, topw);
  }
  k_final<<<dim3(B_TOT), 256, 0, stream>>>(h, out, norm_w, norm_b);
}

// Round 8
// 5941.147 us; speedup vs baseline: 3.9730x; 1.0102x over previous
//
#include <hip/hip_runtime.h>
#include <stdint.h>

// ============================ problem constants ============================
#define C_DIM   768
#define N_TOK   193
#define B_TOT   64                    // 2 towers x 32 batch
#define ROWS    (B_TOT * N_TOK)       // 12352
#define QKV_DIM 2304
#define N_HEAD  12
#define N_EXP   8
#define MAXPER  ROWS

enum { MODE_PATCH = 0, MODE_PLAIN = 1, MODE_RESID = 2, MODE_EXPERT = 3 };

typedef __attribute__((ext_vector_type(8))) short bf16x8;
typedef __attribute__((ext_vector_type(4))) float f32x4;

// ============================ threefry-2x32 (bit-exact vs JAX) ============================
__device__ __forceinline__ uint32_t rotl32(uint32_t x, int n){ return (x << n) | (x >> (32 - n)); }

__device__ __forceinline__ void tf2x32(uint32_t k0, uint32_t k1, uint32_t x0, uint32_t x1,
                                       uint32_t &r0, uint32_t &r1){
  uint32_t k2 = k0 ^ k1 ^ 0x1BD11BDAu;
#define TF4(a,b,c,d) x0+=x1; x1=rotl32(x1,a); x1^=x0; x0+=x1; x1=rotl32(x1,b); x1^=x0; \
                     x0+=x1; x1=rotl32(x1,c); x1^=x0; x0+=x1; x1=rotl32(x1,d); x1^=x0;
  x0 += k0; x1 += k1;
  TF4(13,15,26, 6)  x0 += k1; x1 += k2 + 1u;
  TF4(17,29,16,24)  x0 += k2; x1 += k0 + 2u;
  TF4(13,15,26, 6)  x0 += k0; x1 += k1 + 3u;
  TF4(17,29,16,24)  x0 += k1; x1 += k2 + 4u;
  TF4(13,15,26, 6)  x0 += k2; x1 += k0 + 5u;
#undef TF4
  r0 = x0; r1 = x1;
}

__device__ __forceinline__ float jax_erfinv(float x){
  float w = -log1pf(-x * x);
  float p;
  if (w < 5.0f){
    w -= 2.5f;
    p =              2.81022636e-08f;
    p = fmaf(p, w,   3.43273939e-07f);
    p = fmaf(p, w,  -3.5233877e-06f);
    p = fmaf(p, w,  -4.39150654e-06f);
    p = fmaf(p, w,   0.00021858087f);
    p = fmaf(p, w,  -0.00125372503f);
    p = fmaf(p, w,  -0.00417768164f);
    p = fmaf(p, w,   0.246640727f);
    p = fmaf(p, w,   1.50140941f);
  } else {
    w = sqrtf(w) - 3.0f;
    p =             -0.000200214257f;
    p = fmaf(p, w,   0.000100950558f);
    p = fmaf(p, w,   0.00134934322f);
    p = fmaf(p, w,  -0.00367342844f);
    p = fmaf(p, w,   0.00573950773f);
    p = fmaf(p, w,  -0.0076224613f);
    p = fmaf(p, w,   0.00943887047f);
    p = fmaf(p, w,   1.00167406f);
    p = fmaf(p, w,   2.83297682f);
  }
  return p * x;
}

// PARTITIONABLE threefry random_bits (JAX >= 0.4.36 default) [verified round 5]
__device__ __forceinline__ float jax_noise(uint32_t c0, uint32_t c1, uint32_t j){
  uint32_t o0, o1;
  tf2x32(c0, c1, 0u, j, o0, o1);
  uint32_t bits = o0 ^ o1;
  float f = __uint_as_float(0x3f800000u | (bits >> 9)) - 1.0f;   // [0,1)
  const float lo = -0.99999994f;                                  // nextafter(-1,0)
  float u = fmaxf(lo, f * 2.0f + lo);
  return 1.41421356237f * jax_erfinv(u) * 0.125f;                 // sqrt(2)*erfinv(u)/E
}

// ============================ bf16 split helpers ============================
__device__ __forceinline__ unsigned short f2bf(float x){
  union { float f; uint32_t u; } v; v.f = x;
  uint32_t u = v.u;
  uint32_t r = (u + 0x7FFFu + ((u >> 16) & 1u)) >> 16;   // RNE
  return (unsigned short)r;
}
__device__ __forceinline__ float bf2f(unsigned short h){
  union { uint32_t u; float f; } v; v.u = ((uint32_t)h) << 16;
  return v.f;
}

// ============================ small kernels ============================
__global__ __launch_bounds__(64) void k_zero8(int* __restrict__ p){
  if ((int)threadIdx.x < N_EXP) p[threadIdx.x] = 0;
}

__global__ __launch_bounds__(64) void k_sentinel(float* __restrict__ out, float v){
  if (threadIdx.x == 0) out[0] = v;
}

__global__ __launch_bounds__(256) void k_cls(float* __restrict__ h, const float* __restrict__ cls,
                                             const float* __restrict__ pos){
  const int bt = blockIdx.x;
  #pragma unroll
  for (int u = 0; u < 3; ++u){
    int c = threadIdx.x + u * 256;
    h[(size_t)bt * N_TOK * C_DIM + c] = cls[c] + pos[c];
  }
}

__device__ __forceinline__ float blk_sum(float v, float* sb){
  #pragma unroll
  for (int off = 32; off > 0; off >>= 1) v += __shfl_down(v, off, 64);
  const int lane = threadIdx.x & 63, w = threadIdx.x >> 6;
  if (lane == 0) sb[w] = v;
  __syncthreads();
  if (threadIdx.x == 0) sb[4] = sb[0] + sb[1] + sb[2] + sb[3];
  __syncthreads();
  float r = sb[4];
  __syncthreads();
  return r;
}

__global__ __launch_bounds__(256) void k_layernorm(const float* __restrict__ x, float* __restrict__ y,
                                                   const float* __restrict__ w, const float* __restrict__ b){
  __shared__ float sb[8];
  const float* xr = x + (size_t)blockIdx.x * C_DIM;
  float v0 = xr[threadIdx.x], v1 = xr[threadIdx.x + 256], v2 = xr[threadIdx.x + 512];
  float mean = blk_sum(v0 + v1 + v2, sb) * (1.0f / 768.0f);
  float d0 = v0 - mean, d1 = v1 - mean, d2 = v2 - mean;
  float var = blk_sum(d0 * d0 + d1 * d1 + d2 * d2, sb) * (1.0f / 768.0f);
  float inv = 1.0f / sqrtf(var + 1e-5f);
  float* yr = y + (size_t)blockIdx.x * C_DIM;
  yr[threadIdx.x]       = d0 * inv * w[threadIdx.x]       + b[threadIdx.x];
  yr[threadIdx.x + 256] = d1 * inv * w[threadIdx.x + 256] + b[threadIdx.x + 256];
  yr[threadIdx.x + 512] = d2 * inv * w[threadIdx.x + 512] + b[threadIdx.x + 512];
}

__global__ __launch_bounds__(256) void k_final(const float* __restrict__ h, float* __restrict__ out,
                                               const float* __restrict__ w, const float* __restrict__ b){
  __shared__ float sb[8];
  const int bt = blockIdx.x;
  const float* xr = h + (size_t)bt * N_TOK * C_DIM;
  float v0 = xr[threadIdx.x], v1 = xr[threadIdx.x + 256], v2 = xr[threadIdx.x + 512];
  float mean = blk_sum(v0 + v1 + v2, sb) * (1.0f / 768.0f);
  float d0 = v0 - mean, d1 = v1 - mean, d2 = v2 - mean;
  float var = blk_sum(d0 * d0 + d1 * d1 + d2 * d2, sb) * (1.0f / 768.0f);
  float inv = 1.0f / sqrtf(var + 1e-5f);
  float* orow = out + (size_t)(bt & 31) * 1536 + (size_t)(bt >> 5) * C_DIM;
  orow[threadIdx.x]       = d0 * inv * w[threadIdx.x]       + b[threadIdx.x];
  orow[threadIdx.x + 256] = d1 * inv * w[threadIdx.x + 256] + b[threadIdx.x + 256];
  orow[threadIdx.x + 512] = d2 * inv * w[threadIdx.x + 512] + b[threadIdx.x + 512];
}

// ============================ MFMA GEMM (bf16x2 split): C = A @ W^T (+variants) ============================
template<int MODE>
__global__ __launch_bounds__(256) void k_mgemm(
    const float* __restrict__ A, const float* __restrict__ W,
    const float* __restrict__ bias, float* __restrict__ C,
    int M, int Nc, int Kc,
    const float* __restrict__ xa, const float* __restrict__ xb,
    const float* __restrict__ pos,
    const int* __restrict__ elist, const int* __restrict__ ecnt)
{
  __shared__ short sAhi[128][40];
  __shared__ short sAlo[128][40];
  __shared__ short sBhi[128][40];
  __shared__ short sBlo[128][40];

  const int tid = threadIdx.x;

  int e = 0;
  int Mloc = M;
  const float* Wp = W;
  const float* bp = bias;
  if constexpr (MODE == MODE_EXPERT){
    e = blockIdx.z;
    Mloc = ecnt[e];
    Wp = W + (size_t)e * C_DIM * C_DIM;
    bp = bias + e * C_DIM;
  }
  const int row0 = blockIdx.x * 128;
  const int col0 = blockIdx.y * 128;
  if (row0 >= Mloc) return;

  const int srow = tid >> 1;
  const int skh  = (tid & 1) * 16;

  const float* arow = A;
  bool avalid = false;
  const float* psrc = nullptr;
  if constexpr (MODE == MODE_PLAIN || MODE == MODE_RESID){
    int r = row0 + srow;
    avalid = r < Mloc;
    arow = A + (size_t)(avalid ? r : 0) * Kc;
  } else if constexpr (MODE == MODE_EXPERT){
    int r = row0 + srow;
    avalid = r < Mloc;
    if (avalid) arow = A + (size_t)(elist[e * MAXPER + r] >> 1) * C_DIM;
  } else {
    int r = row0 + srow;
    int bt = r / 192;
    int n  = r - bt * 192;
    const float* xp = (bt < 32) ? xa : xb;
    psrc = xp + (size_t)(bt & 31) * 3 * 384 * 384 + n * 2;
    avalid = true;
  }
  const float* brow = Wp + (size_t)(col0 + srow) * Kc;

  const int wv = tid >> 6;
  const int wr = (wv >> 1) * 64;
  const int wc = (wv & 1) * 64;
  const int lane = tid & 63;
  const int lrow = lane & 15;
  const int lkh  = (lane >> 4) * 8;

  f32x4 acc[4][4] = {};

  const int nkt = Kc / 32;
  for (int kt = 0; kt < nkt; ++kt){
    const int k0 = kt * 32 + skh;
    {
      float va[16] = {};
      if constexpr (MODE == MODE_PATCH){
        int c   = k0 / 768;
        int rem = k0 - c * 768;
        const float* pc = psrc + ((size_t)c * 384 + (rem >> 1)) * 384;
        #pragma unroll
        for (int m = 0; m < 8; ++m){
          va[m * 2 + 0] = pc[(size_t)m * 384 + 0];
          va[m * 2 + 1] = pc[(size_t)m * 384 + 1];
        }
      } else {
        if (avalid){
          *(float4*)&va[0]  = *(const float4*)(arow + k0);
          *(float4*)&va[4]  = *(const float4*)(arow + k0 + 4);
          *(float4*)&va[8]  = *(const float4*)(arow + k0 + 8);
          *(float4*)&va[12] = *(const float4*)(arow + k0 + 12);
        }
      }
      short hi[16], lo[16];
      #pragma unroll
      for (int j = 0; j < 16; ++j){
        unsigned short hb = f2bf(va[j]);
        hi[j] = (short)hb;
        lo[j] = (short)f2bf(va[j] - bf2f(hb));
      }
      *(bf16x8*)&sAhi[srow][skh]     = *(bf16x8*)&hi[0];
      *(bf16x8*)&sAhi[srow][skh + 8] = *(bf16x8*)&hi[8];
      *(bf16x8*)&sAlo[srow][skh]     = *(bf16x8*)&lo[0];
      *(bf16x8*)&sAlo[srow][skh + 8] = *(bf16x8*)&lo[8];
    }
    {
      float vb[16];
      *(float4*)&vb[0]  = *(const float4*)(brow + k0);
      *(float4*)&vb[4]  = *(const float4*)(brow + k0 + 4);
      *(float4*)&vb[8]  = *(const float4*)(brow + k0 + 8);
      *(float4*)&vb[12] = *(const float4*)(brow + k0 + 12);
      short hi[16], lo[16];
      #pragma unroll
      for (int j = 0; j < 16; ++j){
        unsigned short hb = f2bf(vb[j]);
        hi[j] = (short)hb;
        lo[j] = (short)f2bf(vb[j] - bf2f(hb));
      }
      *(bf16x8*)&sBhi[srow][skh]     = *(bf16x8*)&hi[0];
      *(bf16x8*)&sBhi[srow][skh + 8] = *(bf16x8*)&hi[8];
      *(bf16x8*)&sBlo[srow][skh]     = *(bf16x8*)&lo[0];
      *(bf16x8*)&sBlo[srow][skh + 8] = *(bf16x8*)&lo[8];
    }
    __syncthreads();
    bf16x8 ahi[4], alo[4], bhi[4], blo[4];
    #pragma unroll
    for (int i = 0; i < 4; ++i){
      ahi[i] = *(const bf16x8*)&sAhi[wr + i * 16 + lrow][lkh];
      alo[i] = *(const bf16x8*)&sAlo[wr + i * 16 + lrow][lkh];
    }
    #pragma unroll
    for (int j = 0; j < 4; ++j){
      bhi[j] = *(const bf16x8*)&sBhi[wc + j * 16 + lrow][lkh];
      blo[j] = *(const bf16x8*)&sBlo[wc + j * 16 + lrow][lkh];
    }
    #pragma unroll
    for (int i = 0; i < 4; ++i)
      #pragma unroll
      for (int j = 0; j < 4; ++j){
        acc[i][j] = __builtin_amdgcn_mfma_f32_16x16x32_bf16(ahi[i], bhi[j], acc[i][j], 0, 0, 0);
        acc[i][j] = __builtin_amdgcn_mfma_f32_16x16x32_bf16(ahi[i], blo[j], acc[i][j], 0, 0, 0);
        acc[i][j] = __builtin_amdgcn_mfma_f32_16x16x32_bf16(alo[i], bhi[j], acc[i][j], 0, 0, 0);
      }
    __syncthreads();
  }

  #pragma unroll
  for (int i = 0; i < 4; ++i){
    const int rbase = row0 + wr + i * 16 + (lane >> 4) * 4;
    #pragma unroll
    for (int r = 0; r < 4; ++r){
      const int rg = rbase + r;
      if (rg >= Mloc) continue;
      if constexpr (MODE == MODE_PATCH){
        int bt = rg / 192, n = rg - (rg / 192) * 192;
        size_t orow = ((size_t)bt * N_TOK + n + 1) * C_DIM;
        size_t prow = (size_t)(n + 1) * C_DIM;
        #pragma unroll
        for (int j = 0; j < 4; ++j){
          int cg = col0 + wc + j * 16 + (lane & 15);
          C[orow + cg] = acc[i][j][r] + bp[cg] + pos[prow + cg];
        }
      } else if constexpr (MODE == MODE_PLAIN){
        size_t orow = (size_t)rg * Nc;
        #pragma unroll
        for (int j = 0; j < 4; ++j){
          int cg = col0 + wc + j * 16 + (lane & 15);
          C[orow + cg] = acc[i][j][r] + bp[cg];
        }
      } else if constexpr (MODE == MODE_RESID){
        size_t orow = (size_t)rg * Nc;
        #pragma unroll
        for (int j = 0; j < 4; ++j){
          int cg = col0 + wc + j * 16 + (lane & 15);
          C[orow + cg] += acc[i][j][r] + bp[cg];
        }
      } else {
        int ts = elist[e * MAXPER + rg];
        size_t orow = (size_t)ts * C_DIM;
        #pragma unroll
        for (int j = 0; j < 4; ++j){
          int cg = col0 + wc + j * 16 + (lane & 15);
          C[orow + cg] = acc[i][j][r] + bp[cg];
        }
      }
    }
  }
}

// ============================ attention (flash-style, fp32, 64x64 tiles) ============================
__global__ __launch_bounds__(256) void k_attn(const float* __restrict__ qkv, float* __restrict__ o_out){
  __shared__ float Qs[64][64];   // [d][m]
  __shared__ float KPs[64][64];  // K as [d][n], later P as [m][n]
  __shared__ float Vs[64][64];   // [n][d]
  const int q0 = blockIdx.x * 64;
  const int bh = blockIdx.y;
  const int bt = bh / N_HEAD, hh = bh - bt * N_HEAD;
  const int tid = threadIdx.x;
  const int tx = tid & 15, ty = tid >> 4;
  const size_t base = (size_t)bt * N_TOK * QKV_DIM + (size_t)hh * 64;

  { // stage Q transposed
    int m = tid & 63, g = tid >> 6;
    int q = q0 + m;
    bool valid = q < N_TOK;
    const float* src = qkv + base + (size_t)(valid ? q : 0) * QKV_DIM;
    #pragma unroll
    for (int u = 0; u < 4; ++u){
      int cb = (g * 4 + u) * 4;
      float4 v = valid ? *(const float4*)(src + cb) : make_float4(0.f,0.f,0.f,0.f);
      Qs[cb + 0][m] = v.x; Qs[cb + 1][m] = v.y; Qs[cb + 2][m] = v.z; Qs[cb + 3][m] = v.w;
    }
  }

  float Oa[4][4] = {};
  float mrun[4] = {-1e30f, -1e30f, -1e30f, -1e30f};
  float lrun[4] = {};

  for (int kt = 0; kt < 4; ++kt){
    const int n0 = kt * 64;
    __syncthreads();
    { // stage K transposed
      int m = tid & 63, g = tid >> 6;
      int kk = n0 + m;
      bool valid = kk < N_TOK;
      const float* src = qkv + base + 768 + (size_t)(valid ? kk : 0) * QKV_DIM;
      #pragma unroll
      for (int u = 0; u < 4; ++u){
        int cb = (g * 4 + u) * 4;
        float4 v = valid ? *(const float4*)(src + cb) : make_float4(0.f,0.f,0.f,0.f);
        KPs[cb + 0][m] = v.x; KPs[cb + 1][m] = v.y; KPs[cb + 2][m] = v.z; KPs[cb + 3][m] = v.w;
      }
    }
    { // stage V direct
      int c4 = tid & 15, nr = tid >> 4;
      #pragma unroll
      for (int r = 0; r < 4; ++r){
        int n = nr + r * 16;
        int kk = n0 + n;
        float4 v = (kk < N_TOK) ? *(const float4*)(qkv + base + 1536 + (size_t)kk * QKV_DIM + c4 * 4)
                                : make_float4(0.f,0.f,0.f,0.f);
        *(float4*)&Vs[n][c4 * 4] = v;
      }
    }
    __syncthreads();
    float s[4][4] = {};
    #pragma unroll 8
    for (int d = 0; d < 64; ++d){
      float4 a4 = *(const float4*)&Qs[d][ty * 4];
      float4 b4 = *(const float4*)&KPs[d][tx * 4];
      float av[4] = {a4.x, a4.y, a4.z, a4.w};
      float bv[4] = {b4.x, b4.y, b4.z, b4.w};
      #pragma unroll
      for (int i = 0; i < 4; ++i)
        #pragma unroll
        for (int j = 0; j < 4; ++j)
          s[i][j] = fmaf(av[i], bv[j], s[i][j]);
    }
    #pragma unroll
    for (int i = 0; i < 4; ++i)
      #pragma unroll
      for (int j = 0; j < 4; ++j){
        s[i][j] *= 0.125f;
        if (n0 + tx * 4 + j >= N_TOK) s[i][j] = -1e30f;
      }
    __syncthreads();
    #pragma unroll
    for (int i = 0; i < 4; ++i){
      float rm = fmaxf(fmaxf(s[i][0], s[i][1]), fmaxf(s[i][2], s[i][3]));
      rm = fmaxf(rm, __shfl_xor(rm, 1, 64));
      rm = fmaxf(rm, __shfl_xor(rm, 2, 64));
      rm = fmaxf(rm, __shfl_xor(rm, 4, 64));
      rm = fmaxf(rm, __shfl_xor(rm, 8, 64));
      float mn = fmaxf(mrun[i], rm);
      float fac = expf(mrun[i] - mn);
      mrun[i] = mn;
      lrun[i] *= fac;
      float p[4], rs = 0.f;
      #pragma unroll
      for (int j = 0; j < 4; ++j){ p[j] = expf(s[i][j] - mn); rs += p[j]; }
      rs += __shfl_xor(rs, 1, 64);
      rs += __shfl_xor(rs, 2, 64);
      rs += __shfl_xor(rs, 4, 64);
      rs += __shfl_xor(rs, 8, 64);
      lrun[i] += rs;
      #pragma unroll
      for (int j = 0; j < 4; ++j){ Oa[i][j] *= fac; KPs[ty * 4 + i][tx * 4 + j] = p[j]; }
    }
    __syncthreads();
    #pragma unroll 4
    for (int n = 0; n < 64; ++n){
      float4 v4 = *(const float4*)&Vs[n][tx * 4];
      float vv[4] = {v4.x, v4.y, v4.z, v4.w};
      #pragma unroll
      for (int i = 0; i < 4; ++i){
        float pv = KPs[ty * 4 + i][n];
        #pragma unroll
        for (int j = 0; j < 4; ++j)
          Oa[i][j] = fmaf(pv, vv[j], Oa[i][j]);
      }
    }
  }
  #pragma unroll
  for (int i = 0; i < 4; ++i){
    int q = q0 + ty * 4 + i;
    if (q < N_TOK){
      float inv = 1.0f / lrun[i];
      #pragma unroll
      for (int j = 0; j < 4; ++j)
        o_out[((size_t)bt * N_TOK + q) * C_DIM + hh * 64 + tx * 4 + j] = Oa[i][j] * inv;
    }
  }
}

// ============================ router v2: LDS-staged weights, coalesced y, butterfly logits ============================
// Block = 4 waves = 4 tokens. Stage rw (8x768 = 24 KB) in LDS; lane computes 8 partial dots
// over its 12 y-floats; 64-lane butterfly per expert -> all lanes hold all 8 logits.
// Tail (LN/softmax/noise/top2) identical to the round-5-verified code.
__global__ __launch_bounds__(256) void k_router(
    const float* __restrict__ y, const float* __restrict__ rw, const float* __restrict__ rb,
    const float* __restrict__ rlw, const float* __restrict__ rlb,
    float* __restrict__ topw, int* __restrict__ elist, int* __restrict__ ecnt, int l)
{
  __shared__ float4 sw4[1536];                     // 8*768 floats
  const int tid = threadIdx.x;
  const float4* rw4 = (const float4*)rw;
  #pragma unroll
  for (int u = 0; u < 6; ++u)
    sw4[tid + u * 256] = rw4[tid + u * 256];
  __syncthreads();

  const int wid = tid >> 6, lane = tid & 63;
  const int tok = blockIdx.x * 4 + wid;            // grid 3088 -> 12352 exact
  const float4* y4 = (const float4*)(y + (size_t)tok * C_DIM);
  const float4 a0 = y4[lane], a1 = y4[64 + lane], a2 = y4[128 + lane];

  float part[8];
  #pragma unroll
  for (int e = 0; e < 8; ++e){
    const float4 w0 = sw4[e * 192 + lane];
    const float4 w1 = sw4[e * 192 + 64 + lane];
    const float4 w2 = sw4[e * 192 + 128 + lane];
    float s = a0.x * w0.x;
    s = fmaf(a0.y, w0.y, s); s = fmaf(a0.z, w0.z, s); s = fmaf(a0.w, w0.w, s);
    s = fmaf(a1.x, w1.x, s); s = fmaf(a1.y, w1.y, s); s = fmaf(a1.z, w1.z, s); s = fmaf(a1.w, w1.w, s);
    s = fmaf(a2.x, w2.x, s); s = fmaf(a2.y, w2.y, s); s = fmaf(a2.z, w2.z, s); s = fmaf(a2.w, w2.w, s);
    part[e] = s;
  }
  #pragma unroll
  for (int e = 0; e < 8; ++e)
    #pragma unroll
    for (int off = 32; off; off >>= 1) part[e] += __shfl_xor(part[e], off, 64);

  // ---- verified tail (round 5): lane's expert = lane&7 ----
  const int e = lane & 7;
  float logit = part[e] + rb[e];
  float ssum = logit;
  ssum += __shfl_xor(ssum, 1, 64); ssum += __shfl_xor(ssum, 2, 64); ssum += __shfl_xor(ssum, 4, 64);
  float mean = ssum * 0.125f;
  float d = logit - mean;
  float vs = d * d;
  vs += __shfl_xor(vs, 1, 64); vs += __shfl_xor(vs, 2, 64); vs += __shfl_xor(vs, 4, 64);
  float ln = d * (1.0f / sqrtf(vs * 0.125f + 1e-5f)) * rlw[e] + rlb[e];
  float mx = ln;
  mx = fmaxf(mx, __shfl_xor(mx, 1, 64)); mx = fmaxf(mx, __shfl_xor(mx, 2, 64)); mx = fmaxf(mx, __shfl_xor(mx, 4, 64));
  float ex = expf(ln - mx);
  float es = ex;
  es += __shfl_xor(es, 1, 64); es += __shfl_xor(es, 2, 64); es += __shfl_xor(es, 4, 64);
  float prob = ex / es;
  int t = tok / 6176;
  int rem = tok - t * 6176;
  int b = rem / N_TOK, n = rem - (rem / N_TOK) * N_TOK;
  uint32_t b0, b1, c0, c1;
  tf2x32(0u, 1234u, 0u, (uint32_t)t, b0, b1);
  tf2x32(b0, b1, 0u, (uint32_t)l, c0, c1);
  uint32_t j = (uint32_t)(b * N_TOK + n) * 8u + (uint32_t)e;
  float r = prob + jax_noise(c0, c1, j);
  float v1 = r; int i1 = e;
  #pragma unroll
  for (int off = 1; off <= 4; off <<= 1){
    float ov = __shfl_xor(v1, off, 64); int oi = __shfl_xor(i1, off, 64);
    if (ov > v1 || (ov == v1 && oi < i1)){ v1 = ov; i1 = oi; }
  }
  float rm2 = (e == i1) ? -3.0e38f : r;
  float v2 = rm2; int i2 = e;
  #pragma unroll
  for (int off = 1; off <= 4; off <<= 1){
    float ov = __shfl_xor(v2, off, 64); int oi = __shfl_xor(i2, off, 64);
    if (ov > v2 || (ov == v2 && oi < i2)){ v2 = ov; i2 = oi; }
  }
  float e2 = expf(v2 - v1);
  float sum = 1.0f + e2;
  if (lane == 0){
    topw[tok * 2 + 0] = 1.0f / sum;
    topw[tok * 2 + 1] = e2 / sum;
    int pos = atomicAdd(&ecnt[i1], 1);
    elist[i1 * MAXPER + pos] = tok * 2;
    int pos2 = atomicAdd(&ecnt[i2], 1);
    elist[i2 * MAXPER + pos2] = tok * 2 + 1;
  }
}

__global__ __launch_bounds__(256) void k_combine(float* __restrict__ h, const float* __restrict__ eout,
                                                 const float* __restrict__ topw){
  const int tok = blockIdx.x;
  const float w0 = topw[tok * 2], w1 = topw[tok * 2 + 1];
  const size_t hb = (size_t)tok * C_DIM;
  const size_t e0 = (size_t)(tok * 2) * C_DIM, e1 = e0 + C_DIM;
  #pragma unroll
  for (int u = 0; u < 3; ++u){
    int c = threadIdx.x + u * 256;
    h[hb + c] += w0 * eout[e0 + c] + w1 * eout[e1 + c];
  }
}

// ============================ host launch ============================
extern "C" void kernel_launch(void* const* d_in, const int* in_sizes, int n_in,
                              void* d_out, int out_size, void* d_ws, size_t ws_size,
                              hipStream_t stream){
  float* out = (float*)d_out;

  static const int kExp[22] = {
    14155776, 14155776, 1769472, 768, 768,
    4608, 4608, 10616832, 13824, 3538944, 4608,
    4608, 4608, 36864, 48, 48, 48,
    28311552, 36864, 768, 768, 148224};
  const size_t need_f = (size_t)ROWS * C_DIM * 2 + (size_t)ROWS * QKV_DIM
                      + (size_t)ROWS * 2 + (size_t)N_EXP * MAXPER + 8;
  float bad = 0.f;
  if (n_in != 22) bad = 2.0e6f;
  else {
    for (int i = 0; i < 22; ++i)
      if (in_sizes[i] != kExp[i]){ bad = 4.0e6f + i * 1.0e4f; break; }
  }
  if (bad == 0.f && out_size != 49152) bad = 3.0e6f;
  if (bad == 0.f && ws_size < need_f * 4) bad = 1.0e6f;
  if (bad != 0.f){
    k_sentinel<<<dim3(1), 64, 0, stream>>>(out, bad);
    return;
  }

  const float* x1       = (const float*)d_in[0];
  const float* x2       = (const float*)d_in[1];
  const float* patch_w  = (const float*)d_in[2];
  const float* patch_b  = (const float*)d_in[3];
  const float* cls_tok  = (const float*)d_in[4];
  const float* ln1_w    = (const float*)d_in[5];
  const float* ln1_b    = (const float*)d_in[6];
  const float* qkv_w    = (const float*)d_in[7];
  const float* qkv_b    = (const float*)d_in[8];
  const float* proj_w   = (const float*)d_in[9];
  const float* proj_b   = (const float*)d_in[10];
  const float* ln2_w    = (const float*)d_in[11];
  const float* ln2_b    = (const float*)d_in[12];
  const float* route_w  = (const float*)d_in[13];
  const float* route_b  = (const float*)d_in[14];
  const float* rln_w    = (const float*)d_in[15];
  const float* rln_b    = (const float*)d_in[16];
  const float* expert_w = (const float*)d_in[17];
  const float* expert_b = (const float*)d_in[18];
  const float* norm_w   = (const float*)d_in[19];
  const float* norm_b   = (const float*)d_in[20];
  const float* pos_emb  = (const float*)d_in[21];

  // workspace layout (fp32): h | y | qkv (eout aliases qkv) | topw | elist | ecnt
  float* ws = (float*)d_ws;
  size_t off = 0;
  float* h    = ws + off; off += (size_t)ROWS * C_DIM;
  float* y    = ws + off; off += (size_t)ROWS * C_DIM;
  float* qkv  = ws + off; off += (size_t)ROWS * QKV_DIM;
  float* eout = qkv;
  float* topw = ws + off; off += (size_t)ROWS * 2;
  int*   elist = (int*)(ws + off); off += (size_t)N_EXP * MAXPER;
  int*   ecnt  = (int*)(ws + off); off += 8;

  // patch embed + cls + pos
  k_cls<<<dim3(B_TOT), 256, 0, stream>>>(h, cls_tok, pos_emb);
  k_mgemm<MODE_PATCH><<<dim3(96, 6), 256, 0, stream>>>(
      nullptr, patch_w, patch_b, h, 12288, C_DIM, 2304, x1, x2, pos_emb, nullptr, nullptr);

  for (int l = 0; l < 6; ++l){
    k_layernorm<<<dim3(ROWS), 256, 0, stream>>>(h, y, ln1_w + l * C_DIM, ln1_b + l * C_DIM);
    k_mgemm<MODE_PLAIN><<<dim3(97, 18), 256, 0, stream>>>(
        y, qkv_w + (size_t)l * QKV_DIM * C_DIM, qkv_b + l * QKV_DIM, qkv,
        ROWS, QKV_DIM, C_DIM, nullptr, nullptr, nullptr, nullptr, nullptr);
    k_attn<<<dim3(4, B_TOT * N_HEAD), 256, 0, stream>>>(qkv, y);   // o -> y
    k_mgemm<MODE_RESID><<<dim3(97, 6), 256, 0, stream>>>(
        y, proj_w + (size_t)l * C_DIM * C_DIM, proj_b + l * C_DIM, h,
        ROWS, C_DIM, C_DIM, nullptr, nullptr, nullptr, nullptr, nullptr);
    k_layernorm<<<dim3(ROWS), 256, 0, stream>>>(h, y, ln2_w + l * C_DIM, ln2_b + l * C_DIM);
    k_zero8<<<dim3(1), 64, 0, stream>>>(ecnt);
    k_router<<<dim3(ROWS / 4), 256, 0, stream>>>(
        y, route_w + (size_t)l * N_EXP * C_DIM, route_b + l * N_EXP,
        rln_w + l * N_EXP, rln_b + l * N_EXP, topw, elist, ecnt, l);
    k_mgemm<MODE_EXPERT><<<dim3(97, 6, N_EXP), 256, 0, stream>>>(
        y, expert_w + (size_t)l * N_EXP * C_DIM * C_DIM, expert_b + (size_t)l * N_EXP * C_DIM, eout,
        ROWS, C_DIM, C_DIM, nullptr, nullptr, nullptr, elist, ecnt);
    k_combine<<<dim3(ROWS), 256, 0, stream>>>(h, eout, topw);
  }
  k_final<<<dim3(B_TOT), 256, 0, stream>>>(h, out, norm_w, norm_b);
}

// Round 9
// 4504.702 us; speedup vs baseline: 5.2398x; 1.3189x over previous
//
#include <hip/hip_runtime.h>
#include <stdint.h>

// ============================ problem constants ============================
#define C_DIM   768
#define N_TOK   193
#define B_TOT   64                    // 2 towers x 32 batch
#define ROWS    (B_TOT * N_TOK)       // 12352
#define QKV_DIM 2304
#define N_HEAD  12
#define N_EXP   8
#define MAXPER  ROWS
#define RTOK    64                    // tokens per router block (ROWS = 193*64 exact)

enum { MODE_PATCH = 0, MODE_PLAIN = 1, MODE_RESID = 2, MODE_EXPERT = 3 };

typedef __attribute__((ext_vector_type(8))) short bf16x8;
typedef __attribute__((ext_vector_type(4))) float f32x4;

// ============================ threefry-2x32 (bit-exact vs JAX) ============================
__device__ __forceinline__ uint32_t rotl32(uint32_t x, int n){ return (x << n) | (x >> (32 - n)); }

__device__ __forceinline__ void tf2x32(uint32_t k0, uint32_t k1, uint32_t x0, uint32_t x1,
                                       uint32_t &r0, uint32_t &r1){
  uint32_t k2 = k0 ^ k1 ^ 0x1BD11BDAu;
#define TF4(a,b,c,d) x0+=x1; x1=rotl32(x1,a); x1^=x0; x0+=x1; x1=rotl32(x1,b); x1^=x0; \
                     x0+=x1; x1=rotl32(x1,c); x1^=x0; x0+=x1; x1=rotl32(x1,d); x1^=x0;
  x0 += k0; x1 += k1;
  TF4(13,15,26, 6)  x0 += k1; x1 += k2 + 1u;
  TF4(17,29,16,24)  x0 += k2; x1 += k0 + 2u;
  TF4(13,15,26, 6)  x0 += k0; x1 += k1 + 3u;
  TF4(17,29,16,24)  x0 += k1; x1 += k2 + 4u;
  TF4(13,15,26, 6)  x0 += k2; x1 += k0 + 5u;
#undef TF4
  r0 = x0; r1 = x1;
}

__device__ __forceinline__ float jax_erfinv(float x){
  float w = -log1pf(-x * x);
  float p;
  if (w < 5.0f){
    w -= 2.5f;
    p =              2.81022636e-08f;
    p = fmaf(p, w,   3.43273939e-07f);
    p = fmaf(p, w,  -3.5233877e-06f);
    p = fmaf(p, w,  -4.39150654e-06f);
    p = fmaf(p, w,   0.00021858087f);
    p = fmaf(p, w,  -0.00125372503f);
    p = fmaf(p, w,  -0.00417768164f);
    p = fmaf(p, w,   0.246640727f);
    p = fmaf(p, w,   1.50140941f);
  } else {
    w = sqrtf(w) - 3.0f;
    p =             -0.000200214257f;
    p = fmaf(p, w,   0.000100950558f);
    p = fmaf(p, w,   0.00134934322f);
    p = fmaf(p, w,  -0.00367342844f);
    p = fmaf(p, w,   0.00573950773f);
    p = fmaf(p, w,  -0.0076224613f);
    p = fmaf(p, w,   0.00943887047f);
    p = fmaf(p, w,   1.00167406f);
    p = fmaf(p, w,   2.83297682f);
  }
  return p * x;
}

// PARTITIONABLE threefry random_bits (JAX >= 0.4.36 default) [verified round 5]
__device__ __forceinline__ float jax_noise(uint32_t c0, uint32_t c1, uint32_t j){
  uint32_t o0, o1;
  tf2x32(c0, c1, 0u, j, o0, o1);
  uint32_t bits = o0 ^ o1;
  float f = __uint_as_float(0x3f800000u | (bits >> 9)) - 1.0f;   // [0,1)
  const float lo = -0.99999994f;                                  // nextafter(-1,0)
  float u = fmaxf(lo, f * 2.0f + lo);
  return 1.41421356237f * jax_erfinv(u) * 0.125f;                 // sqrt(2)*erfinv(u)/E
}

// ============================ bf16 split helpers ============================
__device__ __forceinline__ unsigned short f2bf(float x){
  union { float f; uint32_t u; } v; v.f = x;
  uint32_t u = v.u;
  uint32_t r = (u + 0x7FFFu + ((u >> 16) & 1u)) >> 16;   // RNE
  return (unsigned short)r;
}
__device__ __forceinline__ float bf2f(unsigned short h){
  union { uint32_t u; float f; } v; v.u = ((uint32_t)h) << 16;
  return v.f;
}

// ============================ small kernels ============================
__global__ __launch_bounds__(64) void k_zero8(int* __restrict__ p){
  if ((int)threadIdx.x < N_EXP) p[threadIdx.x] = 0;
}

__global__ __launch_bounds__(64) void k_sentinel(float* __restrict__ out, float v){
  if (threadIdx.x == 0) out[0] = v;
}

__global__ __launch_bounds__(256) void k_cls(float* __restrict__ h, const float* __restrict__ cls,
                                             const float* __restrict__ pos){
  const int bt = blockIdx.x;
  #pragma unroll
  for (int u = 0; u < 3; ++u){
    int c = threadIdx.x + u * 256;
    h[(size_t)bt * N_TOK * C_DIM + c] = cls[c] + pos[c];
  }
}

__device__ __forceinline__ float blk_sum(float v, float* sb){
  #pragma unroll
  for (int off = 32; off > 0; off >>= 1) v += __shfl_down(v, off, 64);
  const int lane = threadIdx.x & 63, w = threadIdx.x >> 6;
  if (lane == 0) sb[w] = v;
  __syncthreads();
  if (threadIdx.x == 0) sb[4] = sb[0] + sb[1] + sb[2] + sb[3];
  __syncthreads();
  float r = sb[4];
  __syncthreads();
  return r;
}

__global__ __launch_bounds__(256) void k_layernorm(const float* __restrict__ x, float* __restrict__ y,
                                                   const float* __restrict__ w, const float* __restrict__ b){
  __shared__ float sb[8];
  const float* xr = x + (size_t)blockIdx.x * C_DIM;
  float v0 = xr[threadIdx.x], v1 = xr[threadIdx.x + 256], v2 = xr[threadIdx.x + 512];
  float mean = blk_sum(v0 + v1 + v2, sb) * (1.0f / 768.0f);
  float d0 = v0 - mean, d1 = v1 - mean, d2 = v2 - mean;
  float var = blk_sum(d0 * d0 + d1 * d1 + d2 * d2, sb) * (1.0f / 768.0f);
  float inv = 1.0f / sqrtf(var + 1e-5f);
  float* yr = y + (size_t)blockIdx.x * C_DIM;
  yr[threadIdx.x]       = d0 * inv * w[threadIdx.x]       + b[threadIdx.x];
  yr[threadIdx.x + 256] = d1 * inv * w[threadIdx.x + 256] + b[threadIdx.x + 256];
  yr[threadIdx.x + 512] = d2 * inv * w[threadIdx.x + 512] + b[threadIdx.x + 512];
}

__global__ __launch_bounds__(256) void k_final(const float* __restrict__ h, float* __restrict__ out,
                                               const float* __restrict__ w, const float* __restrict__ b){
  __shared__ float sb[8];
  const int bt = blockIdx.x;
  const float* xr = h + (size_t)bt * N_TOK * C_DIM;
  float v0 = xr[threadIdx.x], v1 = xr[threadIdx.x + 256], v2 = xr[threadIdx.x + 512];
  float mean = blk_sum(v0 + v1 + v2, sb) * (1.0f / 768.0f);
  float d0 = v0 - mean, d1 = v1 - mean, d2 = v2 - mean;
  float var = blk_sum(d0 * d0 + d1 * d1 + d2 * d2, sb) * (1.0f / 768.0f);
  float inv = 1.0f / sqrtf(var + 1e-5f);
  float* orow = out + (size_t)(bt & 31) * 1536 + (size_t)(bt >> 5) * C_DIM;
  orow[threadIdx.x]       = d0 * inv * w[threadIdx.x]       + b[threadIdx.x];
  orow[threadIdx.x + 256] = d1 * inv * w[threadIdx.x + 256] + b[threadIdx.x + 256];
  orow[threadIdx.x + 512] = d2 * inv * w[threadIdx.x + 512] + b[threadIdx.x + 512];
}

// ============================ MFMA GEMM (bf16x2 split): C = A @ W^T (+variants) ============================
template<int MODE>
__global__ __launch_bounds__(256) void k_mgemm(
    const float* __restrict__ A, const float* __restrict__ W,
    const float* __restrict__ bias, float* __restrict__ C,
    int M, int Nc, int Kc,
    const float* __restrict__ xa, const float* __restrict__ xb,
    const float* __restrict__ pos,
    const int* __restrict__ elist, const int* __restrict__ ecnt)
{
  __shared__ short sAhi[128][40];
  __shared__ short sAlo[128][40];
  __shared__ short sBhi[128][40];
  __shared__ short sBlo[128][40];

  const int tid = threadIdx.x;

  int e = 0;
  int Mloc = M;
  const float* Wp = W;
  const float* bp = bias;
  if constexpr (MODE == MODE_EXPERT){
    e = blockIdx.z;
    Mloc = ecnt[e];
    Wp = W + (size_t)e * C_DIM * C_DIM;
    bp = bias + e * C_DIM;
  }
  const int row0 = blockIdx.x * 128;
  const int col0 = blockIdx.y * 128;
  if (row0 >= Mloc) return;

  const int srow = tid >> 1;
  const int skh  = (tid & 1) * 16;

  const float* arow = A;
  bool avalid = false;
  const float* psrc = nullptr;
  if constexpr (MODE == MODE_PLAIN || MODE == MODE_RESID){
    int r = row0 + srow;
    avalid = r < Mloc;
    arow = A + (size_t)(avalid ? r : 0) * Kc;
  } else if constexpr (MODE == MODE_EXPERT){
    int r = row0 + srow;
    avalid = r < Mloc;
    if (avalid) arow = A + (size_t)(elist[e * MAXPER + r] >> 1) * C_DIM;
  } else {
    int r = row0 + srow;
    int bt = r / 192;
    int n  = r - bt * 192;
    const float* xp = (bt < 32) ? xa : xb;
    psrc = xp + (size_t)(bt & 31) * 3 * 384 * 384 + n * 2;
    avalid = true;
  }
  const float* brow = Wp + (size_t)(col0 + srow) * Kc;

  const int wv = tid >> 6;
  const int wr = (wv >> 1) * 64;
  const int wc = (wv & 1) * 64;
  const int lane = tid & 63;
  const int lrow = lane & 15;
  const int lkh  = (lane >> 4) * 8;

  f32x4 acc[4][4] = {};

  const int nkt = Kc / 32;
  for (int kt = 0; kt < nkt; ++kt){
    const int k0 = kt * 32 + skh;
    {
      float va[16] = {};
      if constexpr (MODE == MODE_PATCH){
        int c   = k0 / 768;
        int rem = k0 - c * 768;
        const float* pc = psrc + ((size_t)c * 384 + (rem >> 1)) * 384;
        #pragma unroll
        for (int m = 0; m < 8; ++m){
          va[m * 2 + 0] = pc[(size_t)m * 384 + 0];
          va[m * 2 + 1] = pc[(size_t)m * 384 + 1];
        }
      } else {
        if (avalid){
          *(float4*)&va[0]  = *(const float4*)(arow + k0);
          *(float4*)&va[4]  = *(const float4*)(arow + k0 + 4);
          *(float4*)&va[8]  = *(const float4*)(arow + k0 + 8);
          *(float4*)&va[12] = *(const float4*)(arow + k0 + 12);
        }
      }
      short hi[16], lo[16];
      #pragma unroll
      for (int j = 0; j < 16; ++j){
        unsigned short hb = f2bf(va[j]);
        hi[j] = (short)hb;
        lo[j] = (short)f2bf(va[j] - bf2f(hb));
      }
      *(bf16x8*)&sAhi[srow][skh]     = *(bf16x8*)&hi[0];
      *(bf16x8*)&sAhi[srow][skh + 8] = *(bf16x8*)&hi[8];
      *(bf16x8*)&sAlo[srow][skh]     = *(bf16x8*)&lo[0];
      *(bf16x8*)&sAlo[srow][skh + 8] = *(bf16x8*)&lo[8];
    }
    {
      float vb[16];
      *(float4*)&vb[0]  = *(const float4*)(brow + k0);
      *(float4*)&vb[4]  = *(const float4*)(brow + k0 + 4);
      *(float4*)&vb[8]  = *(const float4*)(brow + k0 + 8);
      *(float4*)&vb[12] = *(const float4*)(brow + k0 + 12);
      short hi[16], lo[16];
      #pragma unroll
      for (int j = 0; j < 16; ++j){
        unsigned short hb = f2bf(vb[j]);
        hi[j] = (short)hb;
        lo[j] = (short)f2bf(vb[j] - bf2f(hb));
      }
      *(bf16x8*)&sBhi[srow][skh]     = *(bf16x8*)&hi[0];
      *(bf16x8*)&sBhi[srow][skh + 8] = *(bf16x8*)&hi[8];
      *(bf16x8*)&sBlo[srow][skh]     = *(bf16x8*)&lo[0];
      *(bf16x8*)&sBlo[srow][skh + 8] = *(bf16x8*)&lo[8];
    }
    __syncthreads();
    bf16x8 ahi[4], alo[4], bhi[4], blo[4];
    #pragma unroll
    for (int i = 0; i < 4; ++i){
      ahi[i] = *(const bf16x8*)&sAhi[wr + i * 16 + lrow][lkh];
      alo[i] = *(const bf16x8*)&sAlo[wr + i * 16 + lrow][lkh];
    }
    #pragma unroll
    for (int j = 0; j < 4; ++j){
      bhi[j] = *(const bf16x8*)&sBhi[wc + j * 16 + lrow][lkh];
      blo[j] = *(const bf16x8*)&sBlo[wc + j * 16 + lrow][lkh];
    }
    #pragma unroll
    for (int i = 0; i < 4; ++i)
      #pragma unroll
      for (int j = 0; j < 4; ++j){
        acc[i][j] = __builtin_amdgcn_mfma_f32_16x16x32_bf16(ahi[i], bhi[j], acc[i][j], 0, 0, 0);
        acc[i][j] = __builtin_amdgcn_mfma_f32_16x16x32_bf16(ahi[i], blo[j], acc[i][j], 0, 0, 0);
        acc[i][j] = __builtin_amdgcn_mfma_f32_16x16x32_bf16(alo[i], bhi[j], acc[i][j], 0, 0, 0);
      }
    __syncthreads();
  }

  #pragma unroll
  for (int i = 0; i < 4; ++i){
    const int rbase = row0 + wr + i * 16 + (lane >> 4) * 4;
    #pragma unroll
    for (int r = 0; r < 4; ++r){
      const int rg = rbase + r;
      if (rg >= Mloc) continue;
      if constexpr (MODE == MODE_PATCH){
        int bt = rg / 192, n = rg - (rg / 192) * 192;
        size_t orow = ((size_t)bt * N_TOK + n + 1) * C_DIM;
        size_t prow = (size_t)(n + 1) * C_DIM;
        #pragma unroll
        for (int j = 0; j < 4; ++j){
          int cg = col0 + wc + j * 16 + (lane & 15);
          C[orow + cg] = acc[i][j][r] + bp[cg] + pos[prow + cg];
        }
      } else if constexpr (MODE == MODE_PLAIN){
        size_t orow = (size_t)rg * Nc;
        #pragma unroll
        for (int j = 0; j < 4; ++j){
          int cg = col0 + wc + j * 16 + (lane & 15);
          C[orow + cg] = acc[i][j][r] + bp[cg];
        }
      } else if constexpr (MODE == MODE_RESID){
        size_t orow = (size_t)rg * Nc;
        #pragma unroll
        for (int j = 0; j < 4; ++j){
          int cg = col0 + wc + j * 16 + (lane & 15);
          C[orow + cg] += acc[i][j][r] + bp[cg];
        }
      } else {
        int ts = elist[e * MAXPER + rg];
        size_t orow = (size_t)ts * C_DIM;
        #pragma unroll
        for (int j = 0; j < 4; ++j){
          int cg = col0 + wc + j * 16 + (lane & 15);
          C[orow + cg] = acc[i][j][r] + bp[cg];
        }
      }
    }
  }
}

// ============================ attention (flash-style, fp32, 64x64 tiles) ============================
__global__ __launch_bounds__(256) void k_attn(const float* __restrict__ qkv, float* __restrict__ o_out){
  __shared__ float Qs[64][64];   // [d][m]
  __shared__ float KPs[64][64];  // K as [d][n], later P as [m][n]
  __shared__ float Vs[64][64];   // [n][d]
  const int q0 = blockIdx.x * 64;
  const int bh = blockIdx.y;
  const int bt = bh / N_HEAD, hh = bh - bt * N_HEAD;
  const int tid = threadIdx.x;
  const int tx = tid & 15, ty = tid >> 4;
  const size_t base = (size_t)bt * N_TOK * QKV_DIM + (size_t)hh * 64;

  { // stage Q transposed
    int m = tid & 63, g = tid >> 6;
    int q = q0 + m;
    bool valid = q < N_TOK;
    const float* src = qkv + base + (size_t)(valid ? q : 0) * QKV_DIM;
    #pragma unroll
    for (int u = 0; u < 4; ++u){
      int cb = (g * 4 + u) * 4;
      float4 v = valid ? *(const float4*)(src + cb) : make_float4(0.f,0.f,0.f,0.f);
      Qs[cb + 0][m] = v.x; Qs[cb + 1][m] = v.y; Qs[cb + 2][m] = v.z; Qs[cb + 3][m] = v.w;
    }
  }

  float Oa[4][4] = {};
  float mrun[4] = {-1e30f, -1e30f, -1e30f, -1e30f};
  float lrun[4] = {};

  for (int kt = 0; kt < 4; ++kt){
    const int n0 = kt * 64;
    __syncthreads();
    { // stage K transposed
      int m = tid & 63, g = tid >> 6;
      int kk = n0 + m;
      bool valid = kk < N_TOK;
      const float* src = qkv + base + 768 + (size_t)(valid ? kk : 0) * QKV_DIM;
      #pragma unroll
      for (int u = 0; u < 4; ++u){
        int cb = (g * 4 + u) * 4;
        float4 v = valid ? *(const float4*)(src + cb) : make_float4(0.f,0.f,0.f,0.f);
        KPs[cb + 0][m] = v.x; KPs[cb + 1][m] = v.y; KPs[cb + 2][m] = v.z; KPs[cb + 3][m] = v.w;
      }
    }
    { // stage V direct
      int c4 = tid & 15, nr = tid >> 4;
      #pragma unroll
      for (int r = 0; r < 4; ++r){
        int n = nr + r * 16;
        int kk = n0 + n;
        float4 v = (kk < N_TOK) ? *(const float4*)(qkv + base + 1536 + (size_t)kk * QKV_DIM + c4 * 4)
                                : make_float4(0.f,0.f,0.f,0.f);
        *(float4*)&Vs[n][c4 * 4] = v;
      }
    }
    __syncthreads();
    float s[4][4] = {};
    #pragma unroll 8
    for (int d = 0; d < 64; ++d){
      float4 a4 = *(const float4*)&Qs[d][ty * 4];
      float4 b4 = *(const float4*)&KPs[d][tx * 4];
      float av[4] = {a4.x, a4.y, a4.z, a4.w};
      float bv[4] = {b4.x, b4.y, b4.z, b4.w};
      #pragma unroll
      for (int i = 0; i < 4; ++i)
        #pragma unroll
        for (int j = 0; j < 4; ++j)
          s[i][j] = fmaf(av[i], bv[j], s[i][j]);
    }
    #pragma unroll
    for (int i = 0; i < 4; ++i)
      #pragma unroll
      for (int j = 0; j < 4; ++j){
        s[i][j] *= 0.125f;
        if (n0 + tx * 4 + j >= N_TOK) s[i][j] = -1e30f;
      }
    __syncthreads();
    #pragma unroll
    for (int i = 0; i < 4; ++i){
      float rm = fmaxf(fmaxf(s[i][0], s[i][1]), fmaxf(s[i][2], s[i][3]));
      rm = fmaxf(rm, __shfl_xor(rm, 1, 64));
      rm = fmaxf(rm, __shfl_xor(rm, 2, 64));
      rm = fmaxf(rm, __shfl_xor(rm, 4, 64));
      rm = fmaxf(rm, __shfl_xor(rm, 8, 64));
      float mn = fmaxf(mrun[i], rm);
      float fac = expf(mrun[i] - mn);
      mrun[i] = mn;
      lrun[i] *= fac;
      float p[4], rs = 0.f;
      #pragma unroll
      for (int j = 0; j < 4; ++j){ p[j] = expf(s[i][j] - mn); rs += p[j]; }
      rs += __shfl_xor(rs, 1, 64);
      rs += __shfl_xor(rs, 2, 64);
      rs += __shfl_xor(rs, 4, 64);
      rs += __shfl_xor(rs, 8, 64);
      lrun[i] += rs;
      #pragma unroll
      for (int j = 0; j < 4; ++j){ Oa[i][j] *= fac; KPs[ty * 4 + i][tx * 4 + j] = p[j]; }
    }
    __syncthreads();
    #pragma unroll 4
    for (int n = 0; n < 64; ++n){
      float4 v4 = *(const float4*)&Vs[n][tx * 4];
      float vv[4] = {v4.x, v4.y, v4.z, v4.w};
      #pragma unroll
      for (int i = 0; i < 4; ++i){
        float pv = KPs[ty * 4 + i][n];
        #pragma unroll
        for (int j = 0; j < 4; ++j)
          Oa[i][j] = fmaf(pv, vv[j], Oa[i][j]);
      }
    }
  }
  #pragma unroll
  for (int i = 0; i < 4; ++i){
    int q = q0 + ty * 4 + i;
    if (q < N_TOK){
      float inv = 1.0f / lrun[i];
      #pragma unroll
      for (int j = 0; j < 4; ++j)
        o_out[((size_t)bt * N_TOK + q) * C_DIM + hh * 64 + tx * 4 + j] = Oa[i][j] * inv;
    }
  }
}

// ============================ router v3: 64 tokens/block, LDS-aggregated expert lists ============================
// Per-token compute bit-identical to round 8 (LDS weights, float4 dot, butterfly, verified tail).
// Global atomics: 8 per block (was 2 per token) -> 1544 total vs 24704. Lists built in LDS.
__global__ __launch_bounds__(256) void k_router(
    const float* __restrict__ y, const float* __restrict__ rw, const float* __restrict__ rb,
    const float* __restrict__ rlw, const float* __restrict__ rlb,
    float* __restrict__ topw, int* __restrict__ elist, int* __restrict__ ecnt, int l)
{
  __shared__ float4 sw4[1536];                     // 8*768 floats = 24 KB
  __shared__ int lcnt[8];
  __shared__ int lbase[8];
  __shared__ int llist[8][RTOK];                   // max RTOK entries/expert (top-2 distinct)
  const int tid = threadIdx.x;
  const float4* rw4 = (const float4*)rw;
  #pragma unroll
  for (int u = 0; u < 6; ++u)
    sw4[tid + u * 256] = rw4[tid + u * 256];
  if (tid < 8) lcnt[tid] = 0;
  __syncthreads();

  const int wid = tid >> 6, lane = tid & 63;
  const int e = lane & 7;

  for (int t16 = 0; t16 < RTOK / 4; ++t16){
    const int tok = blockIdx.x * RTOK + wid * (RTOK / 4) + t16;
    const float4* y4 = (const float4*)(y + (size_t)tok * C_DIM);
    const float4 a0 = y4[lane], a1 = y4[64 + lane], a2 = y4[128 + lane];

    float part[8];
    #pragma unroll
    for (int ee = 0; ee < 8; ++ee){
      const float4 w0 = sw4[ee * 192 + lane];
      const float4 w1 = sw4[ee * 192 + 64 + lane];
      const float4 w2 = sw4[ee * 192 + 128 + lane];
      float s = a0.x * w0.x;
      s = fmaf(a0.y, w0.y, s); s = fmaf(a0.z, w0.z, s); s = fmaf(a0.w, w0.w, s);
      s = fmaf(a1.x, w1.x, s); s = fmaf(a1.y, w1.y, s); s = fmaf(a1.z, w1.z, s); s = fmaf(a1.w, w1.w, s);
      s = fmaf(a2.x, w2.x, s); s = fmaf(a2.y, w2.y, s); s = fmaf(a2.z, w2.z, s); s = fmaf(a2.w, w2.w, s);
      part[ee] = s;
    }
    #pragma unroll
    for (int ee = 0; ee < 8; ++ee)
      #pragma unroll
      for (int off = 32; off; off >>= 1) part[ee] += __shfl_xor(part[ee], off, 64);

    // ---- verified tail (round 5): lane's expert = lane&7 ----
    float logit = part[e] + rb[e];
    float ssum = logit;
    ssum += __shfl_xor(ssum, 1, 64); ssum += __shfl_xor(ssum, 2, 64); ssum += __shfl_xor(ssum, 4, 64);
    float mean = ssum * 0.125f;
    float d = logit - mean;
    float vs = d * d;
    vs += __shfl_xor(vs, 1, 64); vs += __shfl_xor(vs, 2, 64); vs += __shfl_xor(vs, 4, 64);
    float ln = d * (1.0f / sqrtf(vs * 0.125f + 1e-5f)) * rlw[e] + rlb[e];
    float mx = ln;
    mx = fmaxf(mx, __shfl_xor(mx, 1, 64)); mx = fmaxf(mx, __shfl_xor(mx, 2, 64)); mx = fmaxf(mx, __shfl_xor(mx, 4, 64));
    float ex = expf(ln - mx);
    float es = ex;
    es += __shfl_xor(es, 1, 64); es += __shfl_xor(es, 2, 64); es += __shfl_xor(es, 4, 64);
    float prob = ex / es;
    int t = tok / 6176;
    int rem = tok - t * 6176;
    int b = rem / N_TOK, n = rem - (rem / N_TOK) * N_TOK;
    uint32_t b0, b1, c0, c1;
    tf2x32(0u, 1234u, 0u, (uint32_t)t, b0, b1);
    tf2x32(b0, b1, 0u, (uint32_t)l, c0, c1);
    uint32_t j = (uint32_t)(b * N_TOK + n) * 8u + (uint32_t)e;
    float r = prob + jax_noise(c0, c1, j);
    float v1 = r; int i1 = e;
    #pragma unroll
    for (int off = 1; off <= 4; off <<= 1){
      float ov = __shfl_xor(v1, off, 64); int oi = __shfl_xor(i1, off, 64);
      if (ov > v1 || (ov == v1 && oi < i1)){ v1 = ov; i1 = oi; }
    }
    float rm2 = (e == i1) ? -3.0e38f : r;
    float v2 = rm2; int i2 = e;
    #pragma unroll
    for (int off = 1; off <= 4; off <<= 1){
      float ov = __shfl_xor(v2, off, 64); int oi = __shfl_xor(i2, off, 64);
      if (ov > v2 || (ov == v2 && oi < i2)){ v2 = ov; i2 = oi; }
    }
    float e2 = expf(v2 - v1);
    float sum = 1.0f + e2;
    if (lane == 0){
      topw[tok * 2 + 0] = 1.0f / sum;
      topw[tok * 2 + 1] = e2 / sum;
      int p = atomicAdd(&lcnt[i1], 1);
      llist[i1][p] = tok * 2;
      int p2 = atomicAdd(&lcnt[i2], 1);
      llist[i2][p2] = tok * 2 + 1;
    }
  }
  __syncthreads();
  if (tid < 8) lbase[tid] = atomicAdd(&ecnt[tid], lcnt[tid]);
  __syncthreads();
  #pragma unroll
  for (int ee = 0; ee < 8; ++ee){
    const int cnt = lcnt[ee];
    const int bse = lbase[ee];
    for (int i = tid; i < cnt; i += 256)
      elist[ee * MAXPER + bse + i] = llist[ee][i];
  }
}

__global__ __launch_bounds__(256) void k_combine(float* __restrict__ h, const float* __restrict__ eout,
                                                 const float* __restrict__ topw){
  const int tok = blockIdx.x;
  const float w0 = topw[tok * 2], w1 = topw[tok * 2 + 1];
  const size_t hb = (size_t)tok * C_DIM;
  const size_t e0 = (size_t)(tok * 2) * C_DIM, e1 = e0 + C_DIM;
  #pragma unroll
  for (int u = 0; u < 3; ++u){
    int c = threadIdx.x + u * 256;
    h[hb + c] += w0 * eout[e0 + c] + w1 * eout[e1 + c];
  }
}

// ============================ host launch ============================
extern "C" void kernel_launch(void* const* d_in, const int* in_sizes, int n_in,
                              void* d_out, int out_size, void* d_ws, size_t ws_size,
                              hipStream_t stream){
  float* out = (float*)d_out;

  static const int kExp[22] = {
    14155776, 14155776, 1769472, 768, 768,
    4608, 4608, 10616832, 13824, 3538944, 4608,
    4608, 4608, 36864, 48, 48, 48,
    28311552, 36864, 768, 768, 148224};
  const size_t need_f = (size_t)ROWS * C_DIM * 2 + (size_t)ROWS * QKV_DIM
                      + (size_t)ROWS * 2 + (size_t)N_EXP * MAXPER + 8;
  float bad = 0.f;
  if (n_in != 22) bad = 2.0e6f;
  else {
    for (int i = 0; i < 22; ++i)
      if (in_sizes[i] != kExp[i]){ bad = 4.0e6f + i * 1.0e4f; break; }
  }
  if (bad == 0.f && out_size != 49152) bad = 3.0e6f;
  if (bad == 0.f && ws_size < need_f * 4) bad = 1.0e6f;
  if (bad != 0.f){
    k_sentinel<<<dim3(1), 64, 0, stream>>>(out, bad);
    return;
  }

  const float* x1       = (const float*)d_in[0];
  const float* x2       = (const float*)d_in[1];
  const float* patch_w  = (const float*)d_in[2];
  const float* patch_b  = (const float*)d_in[3];
  const float* cls_tok  = (const float*)d_in[4];
  const float* ln1_w    = (const float*)d_in[5];
  const float* ln1_b    = (const float*)d_in[6];
  const float* qkv_w    = (const float*)d_in[7];
  const float* qkv_b    = (const float*)d_in[8];
  const float* proj_w   = (const float*)d_in[9];
  const float* proj_b   = (const float*)d_in[10];
  const float* ln2_w    = (const float*)d_in[11];
  const float* ln2_b    = (const float*)d_in[12];
  const float* route_w  = (const float*)d_in[13];
  const float* route_b  = (const float*)d_in[14];
  const float* rln_w    = (const float*)d_in[15];
  const float* rln_b    = (const float*)d_in[16];
  const float* expert_w = (const float*)d_in[17];
  const float* expert_b = (const float*)d_in[18];
  const float* norm_w   = (const float*)d_in[19];
  const float* norm_b   = (const float*)d_in[20];
  const float* pos_emb  = (const float*)d_in[21];

  // workspace layout (fp32): h | y | qkv (eout aliases qkv) | topw | elist | ecnt
  float* ws = (float*)d_ws;
  size_t off = 0;
  float* h    = ws + off; off += (size_t)ROWS * C_DIM;
  float* y    = ws + off; off += (size_t)ROWS * C_DIM;
  float* qkv  = ws + off; off += (size_t)ROWS * QKV_DIM;
  float* eout = qkv;
  float* topw = ws + off; off += (size_t)ROWS * 2;
  int*   elist = (int*)(ws + off); off += (size_t)N_EXP * MAXPER;
  int*   ecnt  = (int*)(ws + off); off += 8;

  // patch embed + cls + pos
  k_cls<<<dim3(B_TOT), 256, 0, stream>>>(h, cls_tok, pos_emb);
  k_mgemm<MODE_PATCH><<<dim3(96, 6), 256, 0, stream>>>(
      nullptr, patch_w, patch_b, h, 12288, C_DIM, 2304, x1, x2, pos_emb, nullptr, nullptr);

  for (int l = 0; l < 6; ++l){
    k_layernorm<<<dim3(ROWS), 256, 0, stream>>>(h, y, ln1_w + l * C_DIM, ln1_b + l * C_DIM);
    k_mgemm<MODE_PLAIN><<<dim3(97, 18), 256, 0, stream>>>(
        y, qkv_w + (size_t)l * QKV_DIM * C_DIM, qkv_b + l * QKV_DIM, qkv,
        ROWS, QKV_DIM, C_DIM, nullptr, nullptr, nullptr, nullptr, nullptr);
    k_attn<<<dim3(4, B_TOT * N_HEAD), 256, 0, stream>>>(qkv, y);   // o -> y
    k_mgemm<MODE_RESID><<<dim3(97, 6), 256, 0, stream>>>(
        y, proj_w + (size_t)l * C_DIM * C_DIM, proj_b + l * C_DIM, h,
        ROWS, C_DIM, C_DIM, nullptr, nullptr, nullptr, nullptr, nullptr);
    k_layernorm<<<dim3(ROWS), 256, 0, stream>>>(h, y, ln2_w + l * C_DIM, ln2_b + l * C_DIM);
    k_zero8<<<dim3(1), 64, 0, stream>>>(ecnt);
    k_router<<<dim3(ROWS / RTOK), 256, 0, stream>>>(
        y, route_w + (size_t)l * N_EXP * C_DIM, route_b + l * N_EXP,
        rln_w + l * N_EXP, rln_b + l * N_EXP, topw, elist, ecnt, l);
    k_mgemm<MODE_EXPERT><<<dim3(97, 6, N_EXP), 256, 0, stream>>>(
        y, expert_w + (size_t)l * N_EXP * C_DIM * C_DIM, expert_b + (size_t)l * N_EXP * C_DIM, eout,
        ROWS, C_DIM, C_DIM, nullptr, nullptr, nullptr, elist, ecnt);
    k_combine<<<dim3(ROWS), 256, 0, stream>>>(h, eout, topw);
  }
  k_final<<<dim3(B_TOT), 256, 0, stream>>>(h, out, norm_w, norm_b);
}

// Round 10
// 4071.669 us; speedup vs baseline: 5.7971x; 1.1064x over previous
//
#include <hip/hip_runtime.h>
#include <stdint.h>

// ============================ problem constants ============================
#define C_DIM   768
#define N_TOK   193
#define B_TOT   64                    // 2 towers x 32 batch
#define ROWS    (B_TOT * N_TOK)       // 12352
#define QKV_DIM 2304
#define N_HEAD  12
#define N_EXP   8
#define MAXPER  ROWS
#define RTOK    64                    // tokens per router block

enum { MODE_PATCH = 0, MODE_PLAIN = 1, MODE_RESID = 2, MODE_EXPERT = 3 };

typedef __attribute__((ext_vector_type(8))) short bf16x8;
typedef __attribute__((ext_vector_type(4))) float f32x4;

// ============================ threefry-2x32 (bit-exact vs JAX) ============================
__device__ __forceinline__ uint32_t rotl32(uint32_t x, int n){ return (x << n) | (x >> (32 - n)); }

__device__ __forceinline__ void tf2x32(uint32_t k0, uint32_t k1, uint32_t x0, uint32_t x1,
                                       uint32_t &r0, uint32_t &r1){
  uint32_t k2 = k0 ^ k1 ^ 0x1BD11BDAu;
#define TF4(a,b,c,d) x0+=x1; x1=rotl32(x1,a); x1^=x0; x0+=x1; x1=rotl32(x1,b); x1^=x0; \
                     x0+=x1; x1=rotl32(x1,c); x1^=x0; x0+=x1; x1=rotl32(x1,d); x1^=x0;
  x0 += k0; x1 += k1;
  TF4(13,15,26, 6)  x0 += k1; x1 += k2 + 1u;
  TF4(17,29,16,24)  x0 += k2; x1 += k0 + 2u;
  TF4(13,15,26, 6)  x0 += k0; x1 += k1 + 3u;
  TF4(17,29,16,24)  x0 += k1; x1 += k2 + 4u;
  TF4(13,15,26, 6)  x0 += k2; x1 += k0 + 5u;
#undef TF4
  r0 = x0; r1 = x1;
}

__device__ __forceinline__ float jax_erfinv(float x){
  float w = -log1pf(-x * x);
  float p;
  if (w < 5.0f){
    w -= 2.5f;
    p =              2.81022636e-08f;
    p = fmaf(p, w,   3.43273939e-07f);
    p = fmaf(p, w,  -3.5233877e-06f);
    p = fmaf(p, w,  -4.39150654e-06f);
    p = fmaf(p, w,   0.00021858087f);
    p = fmaf(p, w,  -0.00125372503f);
    p = fmaf(p, w,  -0.00417768164f);
    p = fmaf(p, w,   0.246640727f);
    p = fmaf(p, w,   1.50140941f);
  } else {
    w = sqrtf(w) - 3.0f;
    p =             -0.000200214257f;
    p = fmaf(p, w,   0.000100950558f);
    p = fmaf(p, w,   0.00134934322f);
    p = fmaf(p, w,  -0.00367342844f);
    p = fmaf(p, w,   0.00573950773f);
    p = fmaf(p, w,  -0.0076224613f);
    p = fmaf(p, w,   0.00943887047f);
    p = fmaf(p, w,   1.00167406f);
    p = fmaf(p, w,   2.83297682f);
  }
  return p * x;
}

// PARTITIONABLE threefry random_bits (JAX >= 0.4.36 default) [verified round 5]
__device__ __forceinline__ float jax_noise(uint32_t c0, uint32_t c1, uint32_t j){
  uint32_t o0, o1;
  tf2x32(c0, c1, 0u, j, o0, o1);
  uint32_t bits = o0 ^ o1;
  float f = __uint_as_float(0x3f800000u | (bits >> 9)) - 1.0f;   // [0,1)
  const float lo = -0.99999994f;                                  // nextafter(-1,0)
  float u = fmaxf(lo, f * 2.0f + lo);
  return 1.41421356237f * jax_erfinv(u) * 0.125f;                 // sqrt(2)*erfinv(u)/E
}

// ============================ bf16 split helpers ============================
__device__ __forceinline__ unsigned short f2bf(float x){
  union { float f; uint32_t u; } v; v.f = x;
  uint32_t u = v.u;
  uint32_t r = (u + 0x7FFFu + ((u >> 16) & 1u)) >> 16;   // RNE
  return (unsigned short)r;
}
__device__ __forceinline__ float bf2f(unsigned short h){
  union { uint32_t u; float f; } v; v.u = ((uint32_t)h) << 16;
  return v.f;
}

// ============================ small kernels ============================
__global__ __launch_bounds__(64) void k_zero8(int* __restrict__ p){
  if ((int)threadIdx.x < N_EXP) p[threadIdx.x] = 0;
}

__global__ __launch_bounds__(64) void k_sentinel(float* __restrict__ out, float v){
  if (threadIdx.x == 0) out[0] = v;
}

__global__ __launch_bounds__(256) void k_cls(float* __restrict__ h, const float* __restrict__ cls,
                                             const float* __restrict__ pos){
  const int bt = blockIdx.x;
  #pragma unroll
  for (int u = 0; u < 3; ++u){
    int c = threadIdx.x + u * 256;
    h[(size_t)bt * N_TOK * C_DIM + c] = cls[c] + pos[c];
  }
}

__device__ __forceinline__ float blk_sum(float v, float* sb){
  #pragma unroll
  for (int off = 32; off > 0; off >>= 1) v += __shfl_down(v, off, 64);
  const int lane = threadIdx.x & 63, w = threadIdx.x >> 6;
  if (lane == 0) sb[w] = v;
  __syncthreads();
  if (threadIdx.x == 0) sb[4] = sb[0] + sb[1] + sb[2] + sb[3];
  __syncthreads();
  float r = sb[4];
  __syncthreads();
  return r;
}

__global__ __launch_bounds__(256) void k_layernorm(const float* __restrict__ x, float* __restrict__ y,
                                                   const float* __restrict__ w, const float* __restrict__ b){
  __shared__ float sb[8];
  const float* xr = x + (size_t)blockIdx.x * C_DIM;
  float v0 = xr[threadIdx.x], v1 = xr[threadIdx.x + 256], v2 = xr[threadIdx.x + 512];
  float mean = blk_sum(v0 + v1 + v2, sb) * (1.0f / 768.0f);
  float d0 = v0 - mean, d1 = v1 - mean, d2 = v2 - mean;
  float var = blk_sum(d0 * d0 + d1 * d1 + d2 * d2, sb) * (1.0f / 768.0f);
  float inv = 1.0f / sqrtf(var + 1e-5f);
  float* yr = y + (size_t)blockIdx.x * C_DIM;
  yr[threadIdx.x]       = d0 * inv * w[threadIdx.x]       + b[threadIdx.x];
  yr[threadIdx.x + 256] = d1 * inv * w[threadIdx.x + 256] + b[threadIdx.x + 256];
  yr[threadIdx.x + 512] = d2 * inv * w[threadIdx.x + 512] + b[threadIdx.x + 512];
}

__global__ __launch_bounds__(256) void k_final(const float* __restrict__ h, float* __restrict__ out,
                                               const float* __restrict__ w, const float* __restrict__ b){
  __shared__ float sb[8];
  const int bt = blockIdx.x;
  const float* xr = h + (size_t)bt * N_TOK * C_DIM;
  float v0 = xr[threadIdx.x], v1 = xr[threadIdx.x + 256], v2 = xr[threadIdx.x + 512];
  float mean = blk_sum(v0 + v1 + v2, sb) * (1.0f / 768.0f);
  float d0 = v0 - mean, d1 = v1 - mean, d2 = v2 - mean;
  float var = blk_sum(d0 * d0 + d1 * d1 + d2 * d2, sb) * (1.0f / 768.0f);
  float inv = 1.0f / sqrtf(var + 1e-5f);
  float* orow = out + (size_t)(bt & 31) * 1536 + (size_t)(bt >> 5) * C_DIM;
  orow[threadIdx.x]       = d0 * inv * w[threadIdx.x]       + b[threadIdx.x];
  orow[threadIdx.x + 256] = d1 * inv * w[threadIdx.x + 256] + b[threadIdx.x + 256];
  orow[threadIdx.x + 512] = d2 * inv * w[threadIdx.x + 512] + b[threadIdx.x + 512];
}

// ============================ MFMA GEMM (bf16x2 split): C = A @ W^T (+variants) ============================
template<int MODE>
__global__ __launch_bounds__(256) void k_mgemm(
    const float* __restrict__ A, const float* __restrict__ W,
    const float* __restrict__ bias, float* __restrict__ C,
    int M, int Nc, int Kc,
    const float* __restrict__ xa, const float* __restrict__ xb,
    const float* __restrict__ pos,
    const int* __restrict__ elist, const int* __restrict__ ecnt)
{
  __shared__ short sAhi[128][40];
  __shared__ short sAlo[128][40];
  __shared__ short sBhi[128][40];
  __shared__ short sBlo[128][40];

  const int tid = threadIdx.x;

  int e = 0;
  int Mloc = M;
  const float* Wp = W;
  const float* bp = bias;
  if constexpr (MODE == MODE_EXPERT){
    e = blockIdx.z;
    Mloc = ecnt[e];
    Wp = W + (size_t)e * C_DIM * C_DIM;
    bp = bias + e * C_DIM;
  }
  const int row0 = blockIdx.x * 128;
  const int col0 = blockIdx.y * 128;
  if (row0 >= Mloc) return;

  const int srow = tid >> 1;
  const int skh  = (tid & 1) * 16;

  const float* arow = A;
  bool avalid = false;
  const float* psrc = nullptr;
  if constexpr (MODE == MODE_PLAIN || MODE == MODE_RESID){
    int r = row0 + srow;
    avalid = r < Mloc;
    arow = A + (size_t)(avalid ? r : 0) * Kc;
  } else if constexpr (MODE == MODE_EXPERT){
    int r = row0 + srow;
    avalid = r < Mloc;
    if (avalid) arow = A + (size_t)(elist[e * MAXPER + r] >> 1) * C_DIM;
  } else {
    int r = row0 + srow;
    int bt = r / 192;
    int n  = r - bt * 192;
    const float* xp = (bt < 32) ? xa : xb;
    psrc = xp + (size_t)(bt & 31) * 3 * 384 * 384 + n * 2;
    avalid = true;
  }
  const float* brow = Wp + (size_t)(col0 + srow) * Kc;

  const int wv = tid >> 6;
  const int wr = (wv >> 1) * 64;
  const int wc = (wv & 1) * 64;
  const int lane = tid & 63;
  const int lrow = lane & 15;
  const int lkh  = (lane >> 4) * 8;

  f32x4 acc[4][4] = {};

  const int nkt = Kc / 32;
  for (int kt = 0; kt < nkt; ++kt){
    const int k0 = kt * 32 + skh;
    {
      float va[16] = {};
      if constexpr (MODE == MODE_PATCH){
        int c   = k0 / 768;
        int rem = k0 - c * 768;
        const float* pc = psrc + ((size_t)c * 384 + (rem >> 1)) * 384;
        #pragma unroll
        for (int m = 0; m < 8; ++m){
          va[m * 2 + 0] = pc[(size_t)m * 384 + 0];
          va[m * 2 + 1] = pc[(size_t)m * 384 + 1];
        }
      } else {
        if (avalid){
          *(float4*)&va[0]  = *(const float4*)(arow + k0);
          *(float4*)&va[4]  = *(const float4*)(arow + k0 + 4);
          *(float4*)&va[8]  = *(const float4*)(arow + k0 + 8);
          *(float4*)&va[12] = *(const float4*)(arow + k0 + 12);
        }
      }
      short hi[16], lo[16];
      #pragma unroll
      for (int j = 0; j < 16; ++j){
        unsigned short hb = f2bf(va[j]);
        hi[j] = (short)hb;
        lo[j] = (short)f2bf(va[j] - bf2f(hb));
      }
      *(bf16x8*)&sAhi[srow][skh]     = *(bf16x8*)&hi[0];
      *(bf16x8*)&sAhi[srow][skh + 8] = *(bf16x8*)&hi[8];
      *(bf16x8*)&sAlo[srow][skh]     = *(bf16x8*)&lo[0];
      *(bf16x8*)&sAlo[srow][skh + 8] = *(bf16x8*)&lo[8];
    }
    {
      float vb[16];
      *(float4*)&vb[0]  = *(const float4*)(brow + k0);
      *(float4*)&vb[4]  = *(const float4*)(brow + k0 + 4);
      *(float4*)&vb[8]  = *(const float4*)(brow + k0 + 8);
      *(float4*)&vb[12] = *(const float4*)(brow + k0 + 12);
      short hi[16], lo[16];
      #pragma unroll
      for (int j = 0; j < 16; ++j){
        unsigned short hb = f2bf(vb[j]);
        hi[j] = (short)hb;
        lo[j] = (short)f2bf(vb[j] - bf2f(hb));
      }
      *(bf16x8*)&sBhi[srow][skh]     = *(bf16x8*)&hi[0];
      *(bf16x8*)&sBhi[srow][skh + 8] = *(bf16x8*)&hi[8];
      *(bf16x8*)&sBlo[srow][skh]     = *(bf16x8*)&lo[0];
      *(bf16x8*)&sBlo[srow][skh + 8] = *(bf16x8*)&lo[8];
    }
    __syncthreads();
    bf16x8 ahi[4], alo[4], bhi[4], blo[4];
    #pragma unroll
    for (int i = 0; i < 4; ++i){
      ahi[i] = *(const bf16x8*)&sAhi[wr + i * 16 + lrow][lkh];
      alo[i] = *(const bf16x8*)&sAlo[wr + i * 16 + lrow][lkh];
    }
    #pragma unroll
    for (int j = 0; j < 4; ++j){
      bhi[j] = *(const bf16x8*)&sBhi[wc + j * 16 + lrow][lkh];
      blo[j] = *(const bf16x8*)&sBlo[wc + j * 16 + lrow][lkh];
    }
    #pragma unroll
    for (int i = 0; i < 4; ++i)
      #pragma unroll
      for (int j = 0; j < 4; ++j){
        acc[i][j] = __builtin_amdgcn_mfma_f32_16x16x32_bf16(ahi[i], bhi[j], acc[i][j], 0, 0, 0);
        acc[i][j] = __builtin_amdgcn_mfma_f32_16x16x32_bf16(ahi[i], blo[j], acc[i][j], 0, 0, 0);
        acc[i][j] = __builtin_amdgcn_mfma_f32_16x16x32_bf16(alo[i], bhi[j], acc[i][j], 0, 0, 0);
      }
    __syncthreads();
  }

  #pragma unroll
  for (int i = 0; i < 4; ++i){
    const int rbase = row0 + wr + i * 16 + (lane >> 4) * 4;
    #pragma unroll
    for (int r = 0; r < 4; ++r){
      const int rg = rbase + r;
      if (rg >= Mloc) continue;
      if constexpr (MODE == MODE_PATCH){
        int bt = rg / 192, n = rg - (rg / 192) * 192;
        size_t orow = ((size_t)bt * N_TOK + n + 1) * C_DIM;
        size_t prow = (size_t)(n + 1) * C_DIM;
        #pragma unroll
        for (int j = 0; j < 4; ++j){
          int cg = col0 + wc + j * 16 + (lane & 15);
          C[orow + cg] = acc[i][j][r] + bp[cg] + pos[prow + cg];
        }
      } else if constexpr (MODE == MODE_PLAIN){
        size_t orow = (size_t)rg * Nc;
        #pragma unroll
        for (int j = 0; j < 4; ++j){
          int cg = col0 + wc + j * 16 + (lane & 15);
          C[orow + cg] = acc[i][j][r] + bp[cg];
        }
      } else if constexpr (MODE == MODE_RESID){
        size_t orow = (size_t)rg * Nc;
        #pragma unroll
        for (int j = 0; j < 4; ++j){
          int cg = col0 + wc + j * 16 + (lane & 15);
          C[orow + cg] += acc[i][j][r] + bp[cg];
        }
      } else {
        int ts = elist[e * MAXPER + rg];
        size_t orow = (size_t)ts * C_DIM;
        #pragma unroll
        for (int j = 0; j < 4; ++j){
          int cg = col0 + wc + j * 16 + (lane & 15);
          C[orow + cg] = acc[i][j][r] + bp[cg];
        }
      }
    }
  }
}

// ============================ attention (flash-style, MFMA bf16x2 split) ============================
// Block = (64-row q-tile, bt*h). 4 waves; wave w owns S/O rows [w*16, w*16+16).
// LDS: Q (hi/lo), K/P shared buffer (hi/lo), V-transposed (hi/lo), all [64][72] bf16.
// Fragment access patterns identical to k_mgemm (verified). Softmax in MFMA C-layout:
// each 16-lane group owns rows (l>>4)*4+reg; row-reduce via shfl_xor 1,2,4,8.
__global__ __launch_bounds__(256) void k_attn(const float* __restrict__ qkv, float* __restrict__ o_out){
  __shared__ short sQhi[64][72],  sQlo[64][72];
  __shared__ short sKPhi[64][72], sKPlo[64][72];   // K tile, then P tile (barrier-separated)
  __shared__ short sVThi[64][72], sVTlo[64][72];   // V transposed: [d][n]

  const int q0 = blockIdx.x * 64;
  const int bh = blockIdx.y;
  const int bt = bh / N_HEAD, hh = bh - bt * N_HEAD;
  const int tid = threadIdx.x;
  const size_t base = (size_t)bt * N_TOK * QKV_DIM + (size_t)hh * 64;

  const int srow = tid >> 2;              // staging: 4 threads/row, 16 d's each
  const int sk   = (tid & 3) * 16;

  { // stage Q (once): rows q0+srow, d = sk..sk+15
    float v[16] = {};
    int q = q0 + srow;
    if (q < N_TOK){
      const float* src = qkv + base + (size_t)q * QKV_DIM + sk;
      *(float4*)&v[0]  = *(const float4*)(src);
      *(float4*)&v[4]  = *(const float4*)(src + 4);
      *(float4*)&v[8]  = *(const float4*)(src + 8);
      *(float4*)&v[12] = *(const float4*)(src + 12);
    }
    short hi[16], lo[16];
    #pragma unroll
    for (int j = 0; j < 16; ++j){
      unsigned short hb = f2bf(v[j]);
      hi[j] = (short)hb;
      lo[j] = (short)f2bf(v[j] - bf2f(hb));
    }
    *(bf16x8*)&sQhi[srow][sk]     = *(bf16x8*)&hi[0];
    *(bf16x8*)&sQhi[srow][sk + 8] = *(bf16x8*)&hi[8];
    *(bf16x8*)&sQlo[srow][sk]     = *(bf16x8*)&lo[0];
    *(bf16x8*)&sQlo[srow][sk + 8] = *(bf16x8*)&lo[8];
  }

  const int wv   = tid >> 6;
  const int lane = tid & 63;
  const int lrow = lane & 15;
  const int lkh  = (lane >> 4) * 8;

  f32x4 Oacc[4] = {};                     // O row-block wv*16; 4 d-frags
  float mrun[4] = {-1e30f, -1e30f, -1e30f, -1e30f};
  float lrun[4] = {};

  for (int kt = 0; kt < 4; ++kt){
    const int n0 = kt * 64;
    __syncthreads();                      // prev iter done with sKP(P)/sVT; covers Q staging
    { // stage K rows n0+srow -> sKP; V rows -> sVT transposed
      float v[16] = {};
      int kk = n0 + srow;
      bool valid = kk < N_TOK;
      if (valid){
        const float* src = qkv + base + 768 + (size_t)kk * QKV_DIM + sk;
        *(float4*)&v[0]  = *(const float4*)(src);
        *(float4*)&v[4]  = *(const float4*)(src + 4);
        *(float4*)&v[8]  = *(const float4*)(src + 8);
        *(float4*)&v[12] = *(const float4*)(src + 12);
      }
      short hi[16], lo[16];
      #pragma unroll
      for (int j = 0; j < 16; ++j){
        unsigned short hb = f2bf(v[j]);
        hi[j] = (short)hb;
        lo[j] = (short)f2bf(v[j] - bf2f(hb));
      }
      *(bf16x8*)&sKPhi[srow][sk]     = *(bf16x8*)&hi[0];
      *(bf16x8*)&sKPhi[srow][sk + 8] = *(bf16x8*)&hi[8];
      *(bf16x8*)&sKPlo[srow][sk]     = *(bf16x8*)&lo[0];
      *(bf16x8*)&sKPlo[srow][sk + 8] = *(bf16x8*)&lo[8];
      // V transposed
      float vv[16] = {};
      if (valid){
        const float* src = qkv + base + 1536 + (size_t)kk * QKV_DIM + sk;
        *(float4*)&vv[0]  = *(const float4*)(src);
        *(float4*)&vv[4]  = *(const float4*)(src + 4);
        *(float4*)&vv[8]  = *(const float4*)(src + 8);
        *(float4*)&vv[12] = *(const float4*)(src + 12);
      }
      #pragma unroll
      for (int j = 0; j < 16; ++j){
        unsigned short hb = f2bf(vv[j]);
        sVThi[sk + j][srow] = (short)hb;
        sVTlo[sk + j][srow] = (short)f2bf(vv[j] - bf2f(hb));
      }
    }
    __syncthreads();

    // ---- S = Q K^T (MFMA, bf16x2 split); wave w rows [wv*16, +16) ----
    f32x4 s[4] = {};
    {
      bf16x8 ahi0 = *(const bf16x8*)&sQhi[wv * 16 + lrow][lkh];
      bf16x8 alo0 = *(const bf16x8*)&sQlo[wv * 16 + lrow][lkh];
      bf16x8 ahi1 = *(const bf16x8*)&sQhi[wv * 16 + lrow][32 + lkh];
      bf16x8 alo1 = *(const bf16x8*)&sQlo[wv * 16 + lrow][32 + lkh];
      #pragma unroll
      for (int j = 0; j < 4; ++j){
        bf16x8 bhi0 = *(const bf16x8*)&sKPhi[j * 16 + lrow][lkh];
        bf16x8 blo0 = *(const bf16x8*)&sKPlo[j * 16 + lrow][lkh];
        bf16x8 bhi1 = *(const bf16x8*)&sKPhi[j * 16 + lrow][32 + lkh];
        bf16x8 blo1 = *(const bf16x8*)&sKPlo[j * 16 + lrow][32 + lkh];
        s[j] = __builtin_amdgcn_mfma_f32_16x16x32_bf16(ahi0, bhi0, s[j], 0, 0, 0);
        s[j] = __builtin_amdgcn_mfma_f32_16x16x32_bf16(ahi0, blo0, s[j], 0, 0, 0);
        s[j] = __builtin_amdgcn_mfma_f32_16x16x32_bf16(alo0, bhi0, s[j], 0, 0, 0);
        s[j] = __builtin_amdgcn_mfma_f32_16x16x32_bf16(ahi1, bhi1, s[j], 0, 0, 0);
        s[j] = __builtin_amdgcn_mfma_f32_16x16x32_bf16(ahi1, blo1, s[j], 0, 0, 0);
        s[j] = __builtin_amdgcn_mfma_f32_16x16x32_bf16(alo1, bhi1, s[j], 0, 0, 0);
      }
    }
    // scale + mask (col = n0 + j*16 + (l&15))
    #pragma unroll
    for (int j = 0; j < 4; ++j){
      bool masked = (n0 + j * 16 + lrow) >= N_TOK;
      #pragma unroll
      for (int r = 0; r < 4; ++r){
        s[j][r] *= 0.125f;
        if (masked) s[j][r] = -1e30f;
      }
    }

    // ---- online softmax in C-layout (rows (l>>4)*4+r, 16-lane row groups) ----
    float p[4][4], fac[4];
    #pragma unroll
    for (int r = 0; r < 4; ++r){
      float rm = fmaxf(fmaxf(s[0][r], s[1][r]), fmaxf(s[2][r], s[3][r]));
      rm = fmaxf(rm, __shfl_xor(rm, 1, 64));
      rm = fmaxf(rm, __shfl_xor(rm, 2, 64));
      rm = fmaxf(rm, __shfl_xor(rm, 4, 64));
      rm = fmaxf(rm, __shfl_xor(rm, 8, 64));
      float mn = fmaxf(mrun[r], rm);
      fac[r] = expf(mrun[r] - mn);
      mrun[r] = mn;
      lrun[r] *= fac[r];
      float rs = 0.f;
      #pragma unroll
      for (int j = 0; j < 4; ++j){ p[j][r] = expf(s[j][r] - mn); rs += p[j][r]; }
      rs += __shfl_xor(rs, 1, 64);
      rs += __shfl_xor(rs, 2, 64);
      rs += __shfl_xor(rs, 4, 64);
      rs += __shfl_xor(rs, 8, 64);
      lrun[r] += rs;
      #pragma unroll
      for (int j = 0; j < 4; ++j) Oacc[j][r] *= fac[r];
    }

    __syncthreads();                      // all waves done reading sKP as K
    // write P (bf16 split) into sKP; wave-local rows
    #pragma unroll
    for (int r = 0; r < 4; ++r){
      const int prow = wv * 16 + (lane >> 4) * 4 + r;
      #pragma unroll
      for (int j = 0; j < 4; ++j){
        unsigned short hb = f2bf(p[j][r]);
        sKPhi[prow][j * 16 + lrow] = (short)hb;
        sKPlo[prow][j * 16 + lrow] = (short)f2bf(p[j][r] - bf2f(hb));
      }
    }

    // ---- O += P V (MFMA; A = P rows [wv*16,+16), B = VT rows = d-cols) ----
    {
      bf16x8 phi0 = *(const bf16x8*)&sKPhi[wv * 16 + lrow][lkh];
      bf16x8 plo0 = *(const bf16x8*)&sKPlo[wv * 16 + lrow][lkh];
      bf16x8 phi1 = *(const bf16x8*)&sKPhi[wv * 16 + lrow][32 + lkh];
      bf16x8 plo1 = *(const bf16x8*)&sKPlo[wv * 16 + lrow][32 + lkh];
      #pragma unroll
      for (int j = 0; j < 4; ++j){
        bf16x8 vhi0 = *(const bf16x8*)&sVThi[j * 16 + lrow][lkh];
        bf16x8 vlo0 = *(const bf16x8*)&sVTlo[j * 16 + lrow][lkh];
        bf16x8 vhi1 = *(const bf16x8*)&sVThi[j * 16 + lrow][32 + lkh];
        bf16x8 vlo1 = *(const bf16x8*)&sVTlo[j * 16 + lrow][32 + lkh];
        Oacc[j] = __builtin_amdgcn_mfma_f32_16x16x32_bf16(phi0, vhi0, Oacc[j], 0, 0, 0);
        Oacc[j] = __builtin_amdgcn_mfma_f32_16x16x32_bf16(phi0, vlo0, Oacc[j], 0, 0, 0);
        Oacc[j] = __builtin_amdgcn_mfma_f32_16x16x32_bf16(plo0, vhi0, Oacc[j], 0, 0, 0);
        Oacc[j] = __builtin_amdgcn_mfma_f32_16x16x32_bf16(phi1, vhi1, Oacc[j], 0, 0, 0);
        Oacc[j] = __builtin_amdgcn_mfma_f32_16x16x32_bf16(phi1, vlo1, Oacc[j], 0, 0, 0);
        Oacc[j] = __builtin_amdgcn_mfma_f32_16x16x32_bf16(plo1, vhi1, Oacc[j], 0, 0, 0);
      }
    }
  }

  // ---- write O: row = q0 + wv*16 + (l>>4)*4 + r, col = h*64 + j*16 + (l&15) ----
  #pragma unroll
  for (int r = 0; r < 4; ++r){
    int q = q0 + wv * 16 + (lane >> 4) * 4 + r;
    if (q < N_TOK){
      float inv = 1.0f / lrun[r];
      #pragma unroll
      for (int j = 0; j < 4; ++j)
        o_out[((size_t)bt * N_TOK + q) * C_DIM + hh * 64 + j * 16 + lrow] = Oacc[j][r] * inv;
    }
  }
}

// ============================ router v3: 64 tokens/block, LDS-aggregated expert lists ============================
__global__ __launch_bounds__(256) void k_router(
    const float* __restrict__ y, const float* __restrict__ rw, const float* __restrict__ rb,
    const float* __restrict__ rlw, const float* __restrict__ rlb,
    float* __restrict__ topw, int* __restrict__ elist, int* __restrict__ ecnt, int l)
{
  __shared__ float4 sw4[1536];                     // 8*768 floats = 24 KB
  __shared__ int lcnt[8];
  __shared__ int lbase[8];
  __shared__ int llist[8][RTOK];
  const int tid = threadIdx.x;
  const float4* rw4 = (const float4*)rw;
  #pragma unroll
  for (int u = 0; u < 6; ++u)
    sw4[tid + u * 256] = rw4[tid + u * 256];
  if (tid < 8) lcnt[tid] = 0;
  __syncthreads();

  const int wid = tid >> 6, lane = tid & 63;
  const int e = lane & 7;

  for (int t16 = 0; t16 < RTOK / 4; ++t16){
    const int tok = blockIdx.x * RTOK + wid * (RTOK / 4) + t16;
    const float4* y4 = (const float4*)(y + (size_t)tok * C_DIM);
    const float4 a0 = y4[lane], a1 = y4[64 + lane], a2 = y4[128 + lane];

    float part[8];
    #pragma unroll
    for (int ee = 0; ee < 8; ++ee){
      const float4 w0 = sw4[ee * 192 + lane];
      const float4 w1 = sw4[ee * 192 + 64 + lane];
      const float4 w2 = sw4[ee * 192 + 128 + lane];
      float s = a0.x * w0.x;
      s = fmaf(a0.y, w0.y, s); s = fmaf(a0.z, w0.z, s); s = fmaf(a0.w, w0.w, s);
      s = fmaf(a1.x, w1.x, s); s = fmaf(a1.y, w1.y, s); s = fmaf(a1.z, w1.z, s); s = fmaf(a1.w, w1.w, s);
      s = fmaf(a2.x, w2.x, s); s = fmaf(a2.y, w2.y, s); s = fmaf(a2.z, w2.z, s); s = fmaf(a2.w, w2.w, s);
      part[ee] = s;
    }
    #pragma unroll
    for (int ee = 0; ee < 8; ++ee)
      #pragma unroll
      for (int off = 32; off; off >>= 1) part[ee] += __shfl_xor(part[ee], off, 64);

    float logit = part[e] + rb[e];
    float ssum = logit;
    ssum += __shfl_xor(ssum, 1, 64); ssum += __shfl_xor(ssum, 2, 64); ssum += __shfl_xor(ssum, 4, 64);
    float mean = ssum * 0.125f;
    float d = logit - mean;
    float vs = d * d;
    vs += __shfl_xor(vs, 1, 64); vs += __shfl_xor(vs, 2, 64); vs += __shfl_xor(vs, 4, 64);
    float ln = d * (1.0f / sqrtf(vs * 0.125f + 1e-5f)) * rlw[e] + rlb[e];
    float mx = ln;
    mx = fmaxf(mx, __shfl_xor(mx, 1, 64)); mx = fmaxf(mx, __shfl_xor(mx, 2, 64)); mx = fmaxf(mx, __shfl_xor(mx, 4, 64));
    float ex = expf(ln - mx);
    float es = ex;
    es += __shfl_xor(es, 1, 64); es += __shfl_xor(es, 2, 64); es += __shfl_xor(es, 4, 64);
    float prob = ex / es;
    int t = tok / 6176;
    int rem = tok - t * 6176;
    int b = rem / N_TOK, n = rem - (rem / N_TOK) * N_TOK;
    uint32_t b0, b1, c0, c1;
    tf2x32(0u, 1234u, 0u, (uint32_t)t, b0, b1);
    tf2x32(b0, b1, 0u, (uint32_t)l, c0, c1);
    uint32_t j = (uint32_t)(b * N_TOK + n) * 8u + (uint32_t)e;
    float r = prob + jax_noise(c0, c1, j);
    float v1 = r; int i1 = e;
    #pragma unroll
    for (int off = 1; off <= 4; off <<= 1){
      float ov = __shfl_xor(v1, off, 64); int oi = __shfl_xor(i1, off, 64);
      if (ov > v1 || (ov == v1 && oi < i1)){ v1 = ov; i1 = oi; }
    }
    float rm2 = (e == i1) ? -3.0e38f : r;
    float v2 = rm2; int i2 = e;
    #pragma unroll
    for (int off = 1; off <= 4; off <<= 1){
      float ov = __shfl_xor(v2, off, 64); int oi = __shfl_xor(i2, off, 64);
      if (ov > v2 || (ov == v2 && oi < i2)){ v2 = ov; i2 = oi; }
    }
    float e2 = expf(v2 - v1);
    float sum = 1.0f + e2;
    if (lane == 0){
      topw[tok * 2 + 0] = 1.0f / sum;
      topw[tok * 2 + 1] = e2 / sum;
      int p = atomicAdd(&lcnt[i1], 1);
      llist[i1][p] = tok * 2;
      int p2 = atomicAdd(&lcnt[i2], 1);
      llist[i2][p2] = tok * 2 + 1;
    }
  }
  __syncthreads();
  if (tid < 8) lbase[tid] = atomicAdd(&ecnt[tid], lcnt[tid]);
  __syncthreads();
  #pragma unroll
  for (int ee = 0; ee < 8; ++ee){
    const int cnt = lcnt[ee];
    const int bse = lbase[ee];
    for (int i = tid; i < cnt; i += 256)
      elist[ee * MAXPER + bse + i] = llist[ee][i];
  }
}

__global__ __launch_bounds__(256) void k_combine(float* __restrict__ h, const float* __restrict__ eout,
                                                 const float* __restrict__ topw){
  const int tok = blockIdx.x;
  const float w0 = topw[tok * 2], w1 = topw[tok * 2 + 1];
  const size_t hb = (size_t)tok * C_DIM;
  const size_t e0 = (size_t)(tok * 2) * C_DIM, e1 = e0 + C_DIM;
  #pragma unroll
  for (int u = 0; u < 3; ++u){
    int c = threadIdx.x + u * 256;
    h[hb + c] += w0 * eout[e0 + c] + w1 * eout[e1 + c];
  }
}

// ============================ host launch ============================
extern "C" void kernel_launch(void* const* d_in, const int* in_sizes, int n_in,
                              void* d_out, int out_size, void* d_ws, size_t ws_size,
                              hipStream_t stream){
  float* out = (float*)d_out;

  static const int kExp[22] = {
    14155776, 14155776, 1769472, 768, 768,
    4608, 4608, 10616832, 13824, 3538944, 4608,
    4608, 4608, 36864, 48, 48, 48,
    28311552, 36864, 768, 768, 148224};
  const size_t need_f = (size_t)ROWS * C_DIM * 2 + (size_t)ROWS * QKV_DIM
                      + (size_t)ROWS * 2 + (size_t)N_EXP * MAXPER + 8;
  float bad = 0.f;
  if (n_in != 22) bad = 2.0e6f;
  else {
    for (int i = 0; i < 22; ++i)
      if (in_sizes[i] != kExp[i]){ bad = 4.0e6f + i * 1.0e4f; break; }
  }
  if (bad == 0.f && out_size != 49152) bad = 3.0e6f;
  if (bad == 0.f && ws_size < need_f * 4) bad = 1.0e6f;
  if (bad != 0.f){
    k_sentinel<<<dim3(1), 64, 0, stream>>>(out, bad);
    return;
  }

  const float* x1       = (const float*)d_in[0];
  const float* x2       = (const float*)d_in[1];
  const float* patch_w  = (const float*)d_in[2];
  const float* patch_b  = (const float*)d_in[3];
  const float* cls_tok  = (const float*)d_in[4];
  const float* ln1_w    = (const float*)d_in[5];
  const float* ln1_b    = (const float*)d_in[6];
  const float* qkv_w    = (const float*)d_in[7];
  const float* qkv_b    = (const float*)d_in[8];
  const float* proj_w   = (const float*)d_in[9];
  const float* proj_b   = (const float*)d_in[10];
  const float* ln2_w    = (const float*)d_in[11];
  const float* ln2_b    = (const float*)d_in[12];
  const float* route_w  = (const float*)d_in[13];
  const float* route_b  = (const float*)d_in[14];
  const float* rln_w    = (const float*)d_in[15];
  const float* rln_b    = (const float*)d_in[16];
  const float* expert_w = (const float*)d_in[17];
  const float* expert_b = (const float*)d_in[18];
  const float* norm_w   = (const float*)d_in[19];
  const float* norm_b   = (const float*)d_in[20];
  const float* pos_emb  = (const float*)d_in[21];

  // workspace layout (fp32): h | y | qkv (eout aliases qkv) | topw | elist | ecnt
  float* ws = (float*)d_ws;
  size_t off = 0;
  float* h    = ws + off; off += (size_t)ROWS * C_DIM;
  float* y    = ws + off; off += (size_t)ROWS * C_DIM;
  float* qkv  = ws + off; off += (size_t)ROWS * QKV_DIM;
  float* eout = qkv;
  float* topw = ws + off; off += (size_t)ROWS * 2;
  int*   elist = (int*)(ws + off); off += (size_t)N_EXP * MAXPER;
  int*   ecnt  = (int*)(ws + off); off += 8;

  // patch embed + cls + pos
  k_cls<<<dim3(B_TOT), 256, 0, stream>>>(h, cls_tok, pos_emb);
  k_mgemm<MODE_PATCH><<<dim3(96, 6), 256, 0, stream>>>(
      nullptr, patch_w, patch_b, h, 12288, C_DIM, 2304, x1, x2, pos_emb, nullptr, nullptr);

  for (int l = 0; l < 6; ++l){
    k_layernorm<<<dim3(ROWS), 256, 0, stream>>>(h, y, ln1_w + l * C_DIM, ln1_b + l * C_DIM);
    k_mgemm<MODE_PLAIN><<<dim3(97, 18), 256, 0, stream>>>(
        y, qkv_w + (size_t)l * QKV_DIM * C_DIM, qkv_b + l * QKV_DIM, qkv,
        ROWS, QKV_DIM, C_DIM, nullptr, nullptr, nullptr, nullptr, nullptr);
    k_attn<<<dim3(4, B_TOT * N_HEAD), 256, 0, stream>>>(qkv, y);   // o -> y
    k_mgemm<MODE_RESID><<<dim3(97, 6), 256, 0, stream>>>(
        y, proj_w + (size_t)l * C_DIM * C_DIM, proj_b + l * C_DIM, h,
        ROWS, C_DIM, C_DIM, nullptr, nullptr, nullptr, nullptr, nullptr);
    k_layernorm<<<dim3(ROWS), 256, 0, stream>>>(h, y, ln2_w + l * C_DIM, ln2_b + l * C_DIM);
    k_zero8<<<dim3(1), 64, 0, stream>>>(ecnt);
    k_router<<<dim3(ROWS / RTOK), 256, 0, stream>>>(
        y, route_w + (size_t)l * N_EXP * C_DIM, route_b + l * N_EXP,
        rln_w + l * N_EXP, rln_b + l * N_EXP, topw, elist, ecnt, l);
    k_mgemm<MODE_EXPERT><<<dim3(97, 6, N_EXP), 256, 0, stream>>>(
        y, expert_w + (size_t)l * N_EXP * C_DIM * C_DIM, expert_b + (size_t)l * N_EXP * C_DIM, eout,
        ROWS, C_DIM, C_DIM, nullptr, nullptr, nullptr, elist, ecnt);
    k_combine<<<dim3(ROWS), 256, 0, stream>>>(h, eout, topw);
  }
  k_final<<<dim3(B_TOT), 256, 0, stream>>>(h, out, norm_w, norm_b);
}